// Round 13
// baseline (1227.582 us; speedup 1.0000x reference)
//
#include <hip/hip_runtime.h>
#include <math.h>

typedef _Float16 half_t;
typedef unsigned int u32;
typedef unsigned short u16;
typedef float f32x4 __attribute__((ext_vector_type(4)));
typedef _Float16 f16x8 __attribute__((ext_vector_type(8)));
typedef _Float16 f16x4 __attribute__((ext_vector_type(4)));

#define T_DIM 4096
#define S_DIM 4096
#define D_DIM 512
#define F_DIM 2048
#define NLAYER 4
#define KVS ((size_t)4096 * 512)

__device__ __forceinline__ void gload16(const void* g, void* l) {
    __builtin_amdgcn_global_load_lds(
        (const __attribute__((address_space(1))) u32*)g,
        (__attribute__((address_space(3))) u32*)l, 16, 0, 0);
}

template<int N> __device__ __forceinline__ void wait_vm() {
    if constexpr (N == 0) asm volatile("s_waitcnt vmcnt(0)" ::: "memory");
    else if constexpr (N == 3) asm volatile("s_waitcnt vmcnt(3)" ::: "memory");
    else if constexpr (N == 4) asm volatile("s_waitcnt vmcnt(4)" ::: "memory");
    else if constexpr (N == 6) asm volatile("s_waitcnt vmcnt(6)" ::: "memory");
    else if constexpr (N == 8) asm volatile("s_waitcnt vmcnt(8)" ::: "memory");
}
__device__ __forceinline__ void wait_lgkm0() {
    asm volatile("s_waitcnt lgkmcnt(0)" ::: "memory");
}

// ---------------------------------------------------------------------------
// Workhorse: 512 thr, BM=128, BK=64, wave tile 32xBN/2.
// EPI: 2 fp16 [M,N] (ldd) | 5 QKV split row-major | 7 batched cross-KV.
// ---------------------------------------------------------------------------
template<int BN, int EPI>
__global__ __launch_bounds__(512)
void gemm_nt(const half_t* __restrict__ A, int lda,
             const half_t* __restrict__ B, int ldb,
             int N, int K, int gx,
             half_t* __restrict__ D1, half_t* __restrict__ D2,
             half_t* __restrict__ D3, int ldd)
{
    constexpr int BM = 128, BK = 64;
    constexpr int NF = BN / 32;
    constexpr int LPT = 2 + BN / 64;
    constexpr int NSLOT = (BN == 64) ? 3 : 2;
    __shared__ half_t As[NSLOT][BM * BK];
    __shared__ half_t Bs[NSLOT][BN * BK];

    const int tid  = threadIdx.x;
    const int wave = tid >> 6;
    const int lane = tid & 63;

    const int nb  = gridDim.x;
    const int bid = blockIdx.x;
    const int nid = (bid & 7) * (nb >> 3) + (bid >> 3);
    const int bx  = nid % gx;
    const int by  = nid / gx;
    const int bm = by * BM, bn = bx * BN;

    const int wm = (wave >> 1) * 32;
    const int wn = (wave & 1) * (BN / 2);
    const int kq = lane >> 4;
    const int rr = lane & 15;
    const int scol = (((lane & 7) ^ (lane >> 3)) << 3);

    f32x4 acc[2][NF];
#pragma unroll
    for (int m = 0; m < 2; ++m)
#pragma unroll
        for (int n = 0; n < NF; ++n)
            acc[m][n] = f32x4{0.f, 0.f, 0.f, 0.f};

    auto stage = [&](int buf, int k0) {
#pragma unroll
        for (int c = 0; c < 2; ++c) {
            const int row = wave * 16 + c * 8 + (lane >> 3);
            gload16(A + (size_t)(bm + row) * lda + k0 + scol,
                    (char*)&As[buf][0] + (wave * 2 + c) * 1024 + lane * 16);
        }
        if constexpr (BN == 64) {
            const int row = wave * 8 + (lane >> 3);
            gload16(B + (size_t)(bn + row) * ldb + k0 + scol,
                    (char*)&Bs[buf][0] + wave * 1024 + lane * 16);
        } else {
#pragma unroll
            for (int c = 0; c < 2; ++c) {
                const int row = wave * 16 + c * 8 + (lane >> 3);
                gload16(B + (size_t)(bn + row) * ldb + k0 + scol,
                        (char*)&Bs[buf][0] + (wave * 2 + c) * 1024 + lane * 16);
            }
        }
    };

    const int nt = K / BK;
    stage(0, 0);
    if constexpr (NSLOT == 3) stage(1, BK);
    int cur = 0, pf = NSLOT - 1;
    for (int t = 0; t < nt; ++t) {
        if (t + 1 < nt) wait_vm<(NSLOT - 2) * LPT>(); else wait_vm<0>();
        __builtin_amdgcn_s_barrier();
        if (t + NSLOT - 1 < nt) stage(pf, (t + NSLOT - 1) * BK);
#pragma unroll
        for (int ks = 0; ks < 2; ++ks) {
            f16x8 af[2], bf[NF];
#pragma unroll
            for (int m = 0; m < 2; ++m) {
                const int r = wm + m * 16 + rr;
                af[m] = *(const f16x8*)&As[cur][r * BK + (((ks * 4 + kq) ^ (r & 7)) << 3)];
            }
#pragma unroll
            for (int n = 0; n < NF; ++n) {
                const int r = wn + n * 16 + rr;
                bf[n] = *(const f16x8*)&Bs[cur][r * BK + (((ks * 4 + kq) ^ (r & 7)) << 3)];
            }
#pragma unroll
            for (int m = 0; m < 2; ++m)
#pragma unroll
                for (int n = 0; n < NF; ++n)
                    acc[m][n] = __builtin_amdgcn_mfma_f32_16x16x32_f16(af[m], bf[n], acc[m][n], 0, 0, 0);
        }
        cur = (cur + 1 == NSLOT) ? 0 : cur + 1;
        pf  = (pf  + 1 == NSLOT) ? 0 : pf  + 1;
    }

    const int r0 = bm + wm + (lane >> 4) * 4;
#pragma unroll
    for (int m = 0; m < 2; ++m)
#pragma unroll
        for (int n = 0; n < NF; ++n) {
            const int c = bn + wn + n * 16 + rr;
            if (EPI == 2) {
#pragma unroll
                for (int i = 0; i < 4; ++i)
                    D1[(size_t)(r0 + m * 16 + i) * ldd + c] = (half_t)acc[m][n][i];
            } else if (EPI == 5) {
                half_t* Dst = (bn < 512) ? D1 : (bn < 1024) ? D2 : D3;
                const int sub = c & 511;
#pragma unroll
                for (int i = 0; i < 4; ++i)
                    Dst[(size_t)(r0 + m * 16 + i) * 512 + sub] = (half_t)acc[m][n][i];
            } else { // EPI == 7 batched cross-KV (row-major K and v)
                const int l = c >> 10;
                const int sub = c & 1023;
                half_t* Dst = (sub < 512) ? (D2 + l * KVS) : (D3 + l * KVS);
                const int d = sub & 511;
#pragma unroll
                for (int i = 0; i < 4; ++i)
                    Dst[(size_t)(r0 + m * 16 + i) * 512 + d] = (half_t)acc[m][n][i];
            }
        }
}

// ---------------------------------------------------------------------------
// V-fold GEMM (z-batched): Out[z][d',s] = sum_d Wt[z][d',d] * V[z][s,d].
// ---------------------------------------------------------------------------
__global__ __launch_bounds__(512)
void gemm_fold(const half_t* __restrict__ Wt, const half_t* __restrict__ V,
               half_t* __restrict__ Out, int zSA, long zSB, long zSD)
{
    constexpr int BM = 128, BK = 64, BN = 64, NSLOT = 3, LPT = 3;
    __shared__ half_t As[NSLOT][BM * BK];
    __shared__ half_t Bs[NSLOT][BN * BK];

    const half_t* A = Wt + (size_t)blockIdx.z * zSA;
    const half_t* B = V  + (size_t)blockIdx.z * zSB;
    half_t* D = Out + (size_t)blockIdx.z * zSD;

    const int tid  = threadIdx.x;
    const int wave = tid >> 6;
    const int lane = tid & 63;

    const int nb  = gridDim.x;   // 256
    const int bid = blockIdx.x;
    const int nid = (bid & 7) * (nb >> 3) + (bid >> 3);
    const int bx = nid & 63, by = nid >> 6;
    const int bm = by * BM, bn = bx * BN;

    const int wm = (wave >> 1) * 32;
    const int wn = (wave & 1) * 32;
    const int kq = lane >> 4;
    const int rr = lane & 15;
    const int scol = (((lane & 7) ^ (lane >> 3)) << 3);

    f32x4 acc[2][2];
#pragma unroll
    for (int m = 0; m < 2; ++m)
#pragma unroll
        for (int n = 0; n < 2; ++n)
            acc[m][n] = f32x4{0.f, 0.f, 0.f, 0.f};

    auto stage = [&](int buf, int k0) {
#pragma unroll
        for (int c = 0; c < 2; ++c) {
            const int row = wave * 16 + c * 8 + (lane >> 3);
            gload16(A + (size_t)(bm + row) * 512 + k0 + scol,
                    (char*)&As[buf][0] + (wave * 2 + c) * 1024 + lane * 16);
        }
        const int row = wave * 8 + (lane >> 3);
        gload16(B + (size_t)(bn + row) * 512 + k0 + scol,
                (char*)&Bs[buf][0] + wave * 1024 + lane * 16);
    };

    const int nt = 512 / BK;   // 8
    stage(0, 0);
    stage(1, BK);
    int cur = 0, pf = 2;
    for (int t = 0; t < nt; ++t) {
        if (t + 1 < nt) wait_vm<LPT>(); else wait_vm<0>();
        __builtin_amdgcn_s_barrier();
        if (t + 2 < nt) stage(pf, (t + 2) * BK);
#pragma unroll
        for (int ks = 0; ks < 2; ++ks) {
            f16x8 af[2], bf[2];
#pragma unroll
            for (int m = 0; m < 2; ++m) {
                const int r = wm + m * 16 + rr;
                af[m] = *(const f16x8*)&As[cur][r * BK + (((ks * 4 + kq) ^ (r & 7)) << 3)];
            }
#pragma unroll
            for (int n = 0; n < 2; ++n) {
                const int r = wn + n * 16 + rr;
                bf[n] = *(const f16x8*)&Bs[cur][r * BK + (((ks * 4 + kq) ^ (r & 7)) << 3)];
            }
#pragma unroll
            for (int m = 0; m < 2; ++m)
#pragma unroll
                for (int n = 0; n < 2; ++n)
                    acc[m][n] = __builtin_amdgcn_mfma_f32_16x16x32_f16(af[m], bf[n], acc[m][n], 0, 0, 0);
        }
        cur = (cur + 1 == NSLOT) ? 0 : cur + 1;
        pf  = (pf  + 1 == NSLOT) ? 0 : pf  + 1;
    }

    const int r0 = bm + wm + (lane >> 4) * 4;
#pragma unroll
    for (int m = 0; m < 2; ++m)
#pragma unroll
        for (int n = 0; n < 2; ++n) {
            const int c = bn + wn + n * 16 + rr;
#pragma unroll
            for (int i = 0; i < 4; ++i)
                D[(size_t)(r0 + m * 16 + i) * 4096 + c] = (half_t)acc[m][n][i];
        }
}

// ---------------------------------------------------------------------------
// m97 geometry: used for W1 (EPI 4) and W2 split-K fp32.
// ---------------------------------------------------------------------------
template<int EPI, int SPLITK = 1, int P16 = 1>
__global__ __launch_bounds__(256)
void gemm97(const half_t* __restrict__ A, int lda,
            const half_t* __restrict__ B, int ldb,
            int K, int gx, half_t* __restrict__ D,
            float* __restrict__ Fout, int ldd)
{
    constexpr int BK = 32, NSLOT = 3, LPT = 4;
    __shared__ half_t As[NSLOT][128 * BK];
    __shared__ half_t Bs[NSLOT][128 * BK];

    const int tid  = threadIdx.x;
    const int wave = tid >> 6;
    const int lane = tid & 63;

    const int nb  = gridDim.x;
    const int bid = blockIdx.x;
    const int nid = (bid & 7) * (nb >> 3) + (bid >> 3);
    const int gy  = nb / (gx * SPLITK);
    const int bx  = nid % gx;
    const int tmp = nid / gx;
    const int by  = tmp % gy;
    const int kz  = tmp / gy;
    const int bm = by * 128, bn = bx * 128;

    const int Keff = K / SPLITK;
    A += (size_t)kz * Keff;
    B += (size_t)kz * Keff;

    const int wm = (wave >> 1) * 64;
    const int wn = (wave & 1) * 64;
    const int kq = lane >> 4;
    const int rr = lane & 15;
    const int srow = lane >> 2;
    const int scol = (((lane & 3) ^ ((lane >> 3) & 3)) << 3);
    const int kqa  = kq ^ ((rr >> 1) & 3);

    const half_t* Abase = A + (size_t)(bm + wave * 16 + srow) * lda + scol;
    const half_t* Bbase = B + (size_t)(bn + wave * 16 + srow) * ldb + scol;

    f32x4 acc[4][4];
#pragma unroll
    for (int m = 0; m < 4; ++m)
#pragma unroll
        for (int n = 0; n < 4; ++n)
            acc[m][n] = f32x4{0.f, 0.f, 0.f, 0.f};

    auto stage = [&](int buf, int k0) {
#pragma unroll
        for (int c = 0; c < 2; ++c)
            gload16(Abase + (size_t)c * 64 * lda + k0,
                    (char*)&As[buf][0] + c * 4096 + wave * 1024 + lane * 16);
#pragma unroll
        for (int c = 0; c < 2; ++c)
            gload16(Bbase + (size_t)c * 64 * ldb + k0,
                    (char*)&Bs[buf][0] + c * 4096 + wave * 1024 + lane * 16);
    };

    const int nt = Keff / BK;
    stage(0, 0);
    stage(1, BK);
    int cur = 0, pf = 2;
    for (int t = 0; t < nt; ++t) {
        if (t + 1 < nt) wait_vm<LPT>(); else wait_vm<0>();
        __builtin_amdgcn_s_barrier();
        if (t + 2 < nt) stage(pf, (t + 2) * BK);
        f16x8 af[4], bf[4];
#pragma unroll
        for (int m = 0; m < 4; ++m)
            af[m] = *(const f16x8*)&As[cur][(wm + m * 16 + rr) * BK + kqa * 8];
#pragma unroll
        for (int n = 0; n < 4; ++n)
            bf[n] = *(const f16x8*)&Bs[cur][(wn + n * 16 + rr) * BK + kqa * 8];
#pragma unroll
        for (int m = 0; m < 4; ++m)
#pragma unroll
            for (int n = 0; n < 4; ++n)
                acc[m][n] = __builtin_amdgcn_mfma_f32_16x16x32_f16(af[m], bf[n], acc[m][n], 0, 0, 0);
        cur = (cur == 2) ? 0 : cur + 1;
        pf  = (pf  == 2) ? 0 : pf + 1;
    }

    const int r0 = bm + wm + (lane >> 4) * 4;
    const int soff = kz * gx * 128;
#pragma unroll
    for (int m = 0; m < 4; ++m)
#pragma unroll
        for (int n = 0; n < 4; ++n) {
            const int c = bn + wn + n * 16 + rr;
#pragma unroll
            for (int i = 0; i < 4; ++i) {
                float v = acc[m][n][i];
                const size_t r = r0 + m * 16 + i;
                if constexpr (SPLITK > 1) {
                    if constexpr (P16) D[r * ldd + soff + c] = (half_t)v;
                    else               Fout[r * ldd + soff + c] = v;
                } else {
                    if (EPI == 4) v = fmaxf(v, 0.f);
                    D[r * ldd + c] = (half_t)v;
                }
            }
        }
}

// ---------------------------------------------------------------------------
// Logits GEMM + fused MASK ONLY (no stats: round-12's in-epilogue shfl-reduce
// chains cost ~28 us at low occupancy). Masked z stored fp16 (-1e9 -> -inf,
// exp -> 0 downstream). Stats computed by row_stats kernel.
// ---------------------------------------------------------------------------
__global__ __launch_bounds__(256)
void gemm_logits(const half_t* __restrict__ A, const half_t* __restrict__ B,
                 const u32* __restrict__ bits, half_t* __restrict__ D)
{
    constexpr int BK = 32, NSLOT = 3, LPT = 4, nt = 16;  // K=512
    __shared__ half_t As[NSLOT][128 * BK];
    __shared__ half_t Bs[NSLOT][128 * BK];

    const int tid  = threadIdx.x;
    const int wave = tid >> 6;
    const int lane = tid & 63;

    const int nb  = gridDim.x;   // 1024
    const int bid = blockIdx.x;
    const int nid = (bid & 7) * (nb >> 3) + (bid >> 3);
    const int bx = nid & 31, by = nid >> 5;
    const int bm = by * 128, bn = bx * 128;

    const int wm = (wave >> 1) * 64;
    const int wn = (wave & 1) * 64;
    const int kq = lane >> 4;
    const int rr = lane & 15;
    const int srow = lane >> 2;
    const int scol = (((lane & 3) ^ ((lane >> 3) & 3)) << 3);
    const int kqa  = kq ^ ((rr >> 1) & 3);

    const half_t* Abase = A + (size_t)(bm + wave * 16 + srow) * 512 + scol;
    const half_t* Bbase = B + (size_t)(bn + wave * 16 + srow) * 512 + scol;

    f32x4 acc[4][4];
#pragma unroll
    for (int m = 0; m < 4; ++m)
#pragma unroll
        for (int n = 0; n < 4; ++n)
            acc[m][n] = f32x4{0.f, 0.f, 0.f, 0.f};

    auto stage = [&](int buf, int k0) {
#pragma unroll
        for (int c = 0; c < 2; ++c)
            gload16(Abase + (size_t)c * 64 * 512 + k0,
                    (char*)&As[buf][0] + c * 4096 + wave * 1024 + lane * 16);
#pragma unroll
        for (int c = 0; c < 2; ++c)
            gload16(Bbase + (size_t)c * 64 * 512 + k0,
                    (char*)&Bs[buf][0] + c * 4096 + wave * 1024 + lane * 16);
    };

    stage(0, 0);
    stage(1, BK);
    int cur = 0, pf = 2;
    for (int t = 0; t < nt; ++t) {
        if (t + 1 < nt) wait_vm<LPT>(); else wait_vm<0>();
        __builtin_amdgcn_s_barrier();
        if (t + 2 < nt) stage(pf, (t + 2) * BK);
        f16x8 af[4], bf[4];
#pragma unroll
        for (int m = 0; m < 4; ++m)
            af[m] = *(const f16x8*)&As[cur][(wm + m * 16 + rr) * BK + kqa * 8];
#pragma unroll
        for (int n = 0; n < 4; ++n)
            bf[n] = *(const f16x8*)&Bs[cur][(wn + n * 16 + rr) * BK + kqa * 8];
#pragma unroll
        for (int m = 0; m < 4; ++m)
#pragma unroll
            for (int n = 0; n < 4; ++n)
                acc[m][n] = __builtin_amdgcn_mfma_f32_16x16x32_f16(af[m], bf[n], acc[m][n], 0, 0, 0);
        cur = (cur == 2) ? 0 : cur + 1;
        pf  = (pf  == 2) ? 0 : pf + 1;
    }

    // ---- epilogue: mask (broadcast bit loads, no cross-lane) + fp16 store ----
    const int g4 = (lane >> 4) * 4;
    const int r0 = bm + wm + g4;
    const int wordbase = (bn + wn) >> 5;
#pragma unroll
    for (int m = 0; m < 4; ++m)
#pragma unroll
        for (int i = 0; i < 4; ++i) {
            const int r = r0 + m * 16 + i;
            const u32 w01 = bits[(size_t)r * 128 + wordbase];
            const u32 w23 = bits[(size_t)r * 128 + wordbase + 1];
            acc[m][0][i] += (((w01 >> rr) & 1u) ? 0.f : -1e9f);
            acc[m][1][i] += (((w01 >> (16 + rr)) & 1u) ? 0.f : -1e9f);
            acc[m][2][i] += (((w23 >> rr) & 1u) ? 0.f : -1e9f);
            acc[m][3][i] += (((w23 >> (16 + rr)) & 1u) ? 0.f : -1e9f);
        }
#pragma unroll
    for (int m = 0; m < 4; ++m)
#pragma unroll
        for (int n = 0; n < 4; ++n) {
            const int c = bn + wn + n * 16 + rr;
#pragma unroll
            for (int i = 0; i < 4; ++i)
                D[(size_t)(r0 + m * 16 + i) * 4096 + c] = (half_t)acc[m][n][i];
        }
}

// ---------------------------------------------------------------------------
// row_stats: per-row {M, 1/S} from masked fp16 z (read-only, one block/row).
// Masked entries are fp16 -inf -> exp contributes 0.
// ---------------------------------------------------------------------------
__global__ __launch_bounds__(256)
void row_stats(const half_t* __restrict__ logits, float2* __restrict__ rowstat)
{
    const int t = blockIdx.x;
    const half_t* row = logits + (size_t)t * S_DIM;
    __shared__ float red[8];
    const int tid = threadIdx.x, wave = tid >> 6, lane = tid & 63;
    const int s0 = tid * 16;
    f16x8 h0 = *(const f16x8*)&row[s0];
    f16x8 h1 = *(const f16x8*)&row[s0 + 8];
    float z[16];
    float lmax = -3.0e38f;
#pragma unroll
    for (int q = 0; q < 16; ++q) {
        z[q] = (float)((q < 8) ? h0[q & 7] : h1[q & 7]);
        lmax = fmaxf(lmax, z[q]);
    }
#pragma unroll
    for (int off = 32; off; off >>= 1) lmax = fmaxf(lmax, __shfl_xor(lmax, off));
    if (lane == 0) red[wave] = lmax;
    __syncthreads();
    const float mx = fmaxf(fmaxf(red[0], red[1]), fmaxf(red[2], red[3]));
    float lsum = 0.f;
#pragma unroll
    for (int q = 0; q < 16; ++q) lsum += __expf(z[q] - mx);
#pragma unroll
    for (int off = 32; off; off >>= 1) lsum += __shfl_xor(lsum, off);
    if (lane == 0) red[4 + wave] = lsum;
    __syncthreads();
    if (tid == 0)
        rowstat[t] = float2{mx, 1.f / (red[4] + red[5] + red[6] + red[7])};
}

// ---------------------------------------------------------------------------
// PV GEMM with on-the-fly P = exp(z - M) * inv (round-12, proven).
// ---------------------------------------------------------------------------
__global__ __launch_bounds__(256)
void gemm_pv(const half_t* __restrict__ A, const half_t* __restrict__ B,
             const float2* __restrict__ rowstat, half_t* __restrict__ D)
{
    constexpr int BK = 32, NSLOT = 3, Keff = 1024, nt = 32;
    __shared__ half_t As[NSLOT][128 * BK];
    __shared__ half_t Bs[NSLOT][128 * BK];

    const int tid = threadIdx.x, wave = tid >> 6, lane = tid & 63;
    const int nb = gridDim.x, bid = blockIdx.x;
    const int nid = (bid & 7) * (nb >> 3) + (bid >> 3);
    const int bx = nid & 3;
    const int tmp = nid >> 2;
    const int by = tmp & 31, kz = tmp >> 5;
    const int bm = by * 128, bn = bx * 128;

    const int wm = (wave >> 1) * 64, wn = (wave & 1) * 64;
    const int kq = lane >> 4, rr = lane & 15, srow = lane >> 2;
    const int scol = (((lane & 3) ^ ((lane >> 3) & 3)) << 3);
    const int kqa = kq ^ ((rr >> 1) & 3);

    const int arow = bm + wave * 16 + srow;
    const half_t* Abase = A + (size_t)arow * 4096 + kz * Keff + scol;
    const half_t* Bbase = B + (size_t)(bn + wave * 16 + srow) * 4096 + kz * Keff + scol;

    const float2 rs0 = rowstat[arow];
    const float2 rs1 = rowstat[arow + 64];
    asm volatile("s_waitcnt vmcnt(0)" ::: "memory");
    const float M0 = rs0.x, I0 = rs0.y, M1 = rs1.x, I1 = rs1.y;

    f32x4 acc[4][4];
#pragma unroll
    for (int m = 0; m < 4; ++m)
#pragma unroll
        for (int n = 0; n < 4; ++n)
            acc[m][n] = f32x4{0.f, 0.f, 0.f, 0.f};

    auto loadA = [&](int k0, f16x8& a0, f16x8& a1) {
        a0 = *(const f16x8*)(Abase + k0);
        a1 = *(const f16x8*)(Abase + (size_t)64 * 4096 + k0);
    };
    auto gloadB = [&](int buf, int k0) {
        gload16(Bbase + k0, (char*)&Bs[buf][0] + wave * 1024 + lane * 16);
        gload16(Bbase + (size_t)64 * 4096 + k0,
                (char*)&Bs[buf][0] + 4096 + wave * 1024 + lane * 16);
    };
    auto writeA = [&](int buf, const f16x8& a0, const f16x8& a1) {
        f16x8 p0, p1;
#pragma unroll
        for (int e = 0; e < 8; ++e) {
            p0[e] = (half_t)(__expf((float)a0[e] - M0) * I0);
            p1[e] = (half_t)(__expf((float)a1[e] - M1) * I1);
        }
        *(f16x8*)((char*)&As[buf][0] + wave * 1024 + lane * 16) = p0;
        *(f16x8*)((char*)&As[buf][0] + 4096 + wave * 1024 + lane * 16) = p1;
    };
    auto compute = [&](int s) {
        f16x8 af[4], bf[4];
#pragma unroll
        for (int m = 0; m < 4; ++m)
            af[m] = *(const f16x8*)&As[s][(wm + m * 16 + rr) * BK + kqa * 8];
#pragma unroll
        for (int n = 0; n < 4; ++n)
            bf[n] = *(const f16x8*)&Bs[s][(wn + n * 16 + rr) * BK + kqa * 8];
#pragma unroll
        for (int m = 0; m < 4; ++m)
#pragma unroll
            for (int n = 0; n < 4; ++n)
                acc[m][n] = __builtin_amdgcn_mfma_f32_16x16x32_f16(af[m], bf[n], acc[m][n], 0, 0, 0);
    };

    f16x8 a0A, a1A, a0B, a1B;
    loadA(0, a0A, a1A);  gloadB(0, 0);
    loadA(BK, a0B, a1B); gloadB(1, BK);
    wait_vm<4>();
    writeA(0, a0A, a1A);
    wait_lgkm0();
    __builtin_amdgcn_s_barrier();

    int cur = 0, pf = 2;
    for (int t = 0; t < nt; t += 2) {
        {
            const bool hasPF = (t + 2 < nt);
            if (hasPF) { loadA((t + 2) * BK, a0A, a1A); gloadB(pf, (t + 2) * BK); }
            compute(cur);
            if (t + 1 < nt) {
                if (hasPF) wait_vm<4>(); else wait_vm<0>();
                writeA((cur + 1 == NSLOT) ? 0 : cur + 1, a0B, a1B);
                wait_lgkm0();
            }
            __builtin_amdgcn_s_barrier();
            cur = (cur + 1 == NSLOT) ? 0 : cur + 1;
            pf  = (pf  + 1 == NSLOT) ? 0 : pf + 1;
        }
        {
            const int u = t + 1;
            const bool hasPF = (u + 2 < nt);
            if (hasPF) { loadA((u + 2) * BK, a0B, a1B); gloadB(pf, (u + 2) * BK); }
            compute(cur);
            if (u + 1 < nt) {
                if (hasPF) wait_vm<4>(); else wait_vm<0>();
                writeA((cur + 1 == NSLOT) ? 0 : cur + 1, a0A, a1A);
                wait_lgkm0();
            }
            __builtin_amdgcn_s_barrier();
            cur = (cur + 1 == NSLOT) ? 0 : cur + 1;
            pf  = (pf  + 1 == NSLOT) ? 0 : pf + 1;
        }
    }

    const int r0 = bm + wm + (lane >> 4) * 4;
    const int soff = kz * 512;
#pragma unroll
    for (int m = 0; m < 4; ++m)
#pragma unroll
        for (int n = 0; n < 4; ++n) {
            const int c = bn + wn + n * 16 + rr;
#pragma unroll
            for (int i = 0; i < 4; ++i)
                D[(size_t)(r0 + m * 16 + i) * 2048 + soff + c] = (half_t)acc[m][n][i];
        }
}

// ---------------------------------------------------------------------------
// attn_tail: xbuf = xin + sum of 4 fp16 PV slices; hh = LayerNorm(xbuf).
// ---------------------------------------------------------------------------
__global__ __launch_bounds__(256)
void attn_tail(const float* __restrict__ xin, const half_t* __restrict__ P,
               float* __restrict__ xbuf, half_t* __restrict__ hh)
{
    const int row  = blockIdx.x * 4 + (threadIdx.x >> 6);
    const int lane = threadIdx.x & 63;
    const int d0 = lane * 8;
    float v[8];
    {
        const float* xr = xin + (size_t)row * D_DIM + d0;
        float4 a = *(const float4*)xr;
        float4 b = *(const float4*)(xr + 4);
        v[0]=a.x; v[1]=a.y; v[2]=a.z; v[3]=a.w; v[4]=b.x; v[5]=b.y; v[6]=b.z; v[7]=b.w;
    }
    const half_t* pr = P + (size_t)row * 2048 + d0;
#pragma unroll
    for (int j = 0; j < 4; ++j) {
        f16x8 pv = *(const f16x8*)(pr + j * 512);
#pragma unroll
        for (int e = 0; e < 8; ++e) v[e] += (float)pv[e];
    }
    float* xo = xbuf + (size_t)row * D_DIM + d0;
    *(float4*)xo       = float4{v[0], v[1], v[2], v[3]};
    *(float4*)(xo + 4) = float4{v[4], v[5], v[6], v[7]};

    float s = 0.f;
#pragma unroll
    for (int j = 0; j < 8; ++j) s += v[j];
#pragma unroll
    for (int off = 32; off; off >>= 1) s += __shfl_xor(s, off);
    const float mean = s * (1.f / 512.f);
    float ss = 0.f;
#pragma unroll
    for (int j = 0; j < 8; ++j) { float d = v[j] - mean; ss += d * d; }
#pragma unroll
    for (int off = 32; off; off >>= 1) ss += __shfl_xor(ss, off);
    const float inv = 1.f / (sqrtf(ss * (1.f / 511.f)) + 1e-6f);
    f16x8 hv;
#pragma unroll
    for (int j = 0; j < 8; ++j) hv[j] = (half_t)((v[j] - mean) * inv);
    *(f16x8*)&hh[(size_t)row * D_DIM + d0] = hv;
}

// ---------------------------------------------------------------------------
// norm_red: x = xin + sum of 4 fp32 W2 partial slices [4096][2048].
// ---------------------------------------------------------------------------
template<int FINAL>
__global__ __launch_bounds__(256)
void norm_red(const float* __restrict__ xin, const float* __restrict__ P,
              float* __restrict__ xbuf, half_t* __restrict__ hh,
              float* __restrict__ outF, const float* __restrict__ alphaP,
              const float* __restrict__ gammaP)
{
    const int row  = blockIdx.x * 4 + (threadIdx.x >> 6);
    const int lane = threadIdx.x & 63;
    const int d0 = lane * 8;
    const float* xr = xin + (size_t)row * D_DIM + d0;
    float v[8];
    {
        float4 a = *(const float4*)xr;
        float4 b = *(const float4*)(xr + 4);
        v[0]=a.x; v[1]=a.y; v[2]=a.z; v[3]=a.w; v[4]=b.x; v[5]=b.y; v[6]=b.z; v[7]=b.w;
    }
    const float* pr = P + (size_t)row * 2048 + d0;
#pragma unroll
    for (int j = 0; j < 4; ++j) {
        float4 a = *(const float4*)(pr + j * 512);
        float4 b = *(const float4*)(pr + j * 512 + 4);
        v[0]+=a.x; v[1]+=a.y; v[2]+=a.z; v[3]+=a.w; v[4]+=b.x; v[5]+=b.y; v[6]+=b.z; v[7]+=b.w;
    }
    if (!FINAL) {
        float* xo = xbuf + (size_t)row * D_DIM + d0;
        *(float4*)xo       = float4{v[0], v[1], v[2], v[3]};
        *(float4*)(xo + 4) = float4{v[4], v[5], v[6], v[7]};
    }
    float s = 0.f;
#pragma unroll
    for (int j = 0; j < 8; ++j) s += v[j];
#pragma unroll
    for (int off = 32; off; off >>= 1) s += __shfl_xor(s, off);
    const float mean = s * (1.f / 512.f);
    float ss = 0.f;
#pragma unroll
    for (int j = 0; j < 8; ++j) { float d = v[j] - mean; ss += d * d; }
#pragma unroll
    for (int off = 32; off; off >>= 1) ss += __shfl_xor(ss, off);
    const float inv = 1.f / (sqrtf(ss * (1.f / 511.f)) + 1e-6f);
    if (FINAL) {
        const float alp = alphaP[0], gam = gammaP[0];
        float o[8];
#pragma unroll
        for (int j = 0; j < 8; ++j) o[j] = alp * ((v[j] - mean) * inv) + gam;
        float* op = outF + (size_t)row * D_DIM + d0;
        *(float4*)op       = float4{o[0], o[1], o[2], o[3]};
        *(float4*)(op + 4) = float4{o[4], o[5], o[6], o[7]};
    } else {
        f16x8 hv;
#pragma unroll
        for (int j = 0; j < 8; ++j) hv[j] = (half_t)((v[j] - mean) * inv);
        *(f16x8*)&hh[(size_t)row * D_DIM + d0] = hv;
    }
}

template<int FINAL>
__global__ __launch_bounds__(256)
void norm_rows(const float* __restrict__ x, half_t* __restrict__ hh,
               float* __restrict__ outF, const float* __restrict__ alphaP,
               const float* __restrict__ gammaP)
{
    const int row  = blockIdx.x * 4 + (threadIdx.x >> 6);
    const int lane = threadIdx.x & 63;
    const float* xr = x + (size_t)row * D_DIM + lane * 8;
    float4 a = *(const float4*)xr;
    float4 b = *(const float4*)(xr + 4);
    float v[8] = {a.x, a.y, a.z, a.w, b.x, b.y, b.z, b.w};
    float s = 0.f;
#pragma unroll
    for (int j = 0; j < 8; ++j) s += v[j];
#pragma unroll
    for (int off = 32; off; off >>= 1) s += __shfl_xor(s, off);
    const float mean = s * (1.f / 512.f);
    float ss = 0.f;
#pragma unroll
    for (int j = 0; j < 8; ++j) { float d = v[j] - mean; ss += d * d; }
#pragma unroll
    for (int off = 32; off; off >>= 1) ss += __shfl_xor(ss, off);
    const float inv = 1.f / (sqrtf(ss * (1.f / 511.f)) + 1e-6f);
    if (FINAL) {
        const float alp = alphaP[0], gam = gammaP[0];
        float o[8];
#pragma unroll
        for (int j = 0; j < 8; ++j) o[j] = alp * ((v[j] - mean) * inv) + gam;
        float* op = outF + (size_t)row * D_DIM + lane * 8;
        *(float4*)op       = float4{o[0], o[1], o[2], o[3]};
        *(float4*)(op + 4) = float4{o[4], o[5], o[6], o[7]};
    } else {
        f16x8 hv;
#pragma unroll
        for (int j = 0; j < 8; ++j) hv[j] = (half_t)((v[j] - mean) * inv);
        *(f16x8*)&hh[(size_t)row * D_DIM + lane * 8] = hv;
    }
}

__global__ __launch_bounds__(256)
void cast_f16(const float* __restrict__ in, half_t* __restrict__ out)
{
    size_t i = ((size_t)blockIdx.x * 256 + threadIdx.x) * 8;
    float4 a = *(const float4*)&in[i];
    float4 b = *(const float4*)&in[i + 4];
    float v[8] = {a.x, a.y, a.z, a.w, b.x, b.y, b.z, b.w};
    f16x8 o;
#pragma unroll
    for (int j = 0; j < 8; ++j) o[j] = (half_t)v[j];
    *(f16x8*)&out[i] = o;
}

// batched square-weight transpose: z = t*4 + layer; 8 weights in one launch
__global__ __launch_bounds__(256)
void transpose_cast8(const float* __restrict__ i0, const float* __restrict__ i1,
                     const float* __restrict__ i2, const float* __restrict__ i3,
                     const float* __restrict__ i4, const float* __restrict__ i5,
                     const float* __restrict__ i6, const float* __restrict__ i7,
                     half_t* __restrict__ o0, half_t* __restrict__ o1,
                     half_t* __restrict__ o2, half_t* __restrict__ o3,
                     half_t* __restrict__ o4, half_t* __restrict__ o5,
                     half_t* __restrict__ o6, half_t* __restrict__ o7,
                     float qscale)
{
    const int SQ = 512 * 512, QKVZ = 1536 * 512, KVZ = 1024 * 512;
    const int z = blockIdx.z, t = z >> 2, l = z & 3;
    const float* in; half_t* out; float sc = 1.f; int outZ;
    switch (t) {
        case 0: in = i0; out = o0; sc = qscale; outZ = QKVZ; break;
        case 1: in = i1; out = o1; outZ = QKVZ; break;
        case 2: in = i2; out = o2; outZ = QKVZ; break;
        case 3: in = i3; out = o3; outZ = SQ; break;
        case 4: in = i4; out = o4; sc = qscale; outZ = SQ; break;
        case 5: in = i5; out = o5; outZ = KVZ; break;
        case 6: in = i6; out = o6; outZ = KVZ; break;
        default: in = i7; out = o7; outZ = SQ; break;
    }
    in  += (size_t)l * SQ;
    out += (size_t)l * outZ;
    __shared__ float tile[32][33];
    const int tx = threadIdx.x & 31, ty = threadIdx.x >> 5;
    const int r0 = blockIdx.y * 32, c0 = blockIdx.x * 32;
#pragma unroll
    for (int i = 0; i < 4; ++i)
        tile[ty + i * 8][tx] = in[(size_t)(r0 + ty + i * 8) * 512 + c0 + tx];
    __syncthreads();
#pragma unroll
    for (int i = 0; i < 4; ++i)
        out[(size_t)(c0 + ty + i * 8) * 512 + r0 + tx] = (half_t)(tile[tx][ty + i * 8] * sc);
}

__global__ __launch_bounds__(256)
void transpose_cast(const float* __restrict__ in, half_t* __restrict__ out,
                    int R, int C, float scale, int inZ, int outZ)
{
    in  += (size_t)blockIdx.z * inZ;
    out += (size_t)blockIdx.z * outZ;
    __shared__ float tile[32][33];
    const int tx = threadIdx.x & 31, ty = threadIdx.x >> 5;
    const int r0 = blockIdx.y * 32, c0 = blockIdx.x * 32;
#pragma unroll
    for (int i = 0; i < 4; ++i)
        tile[ty + i * 8][tx] = in[(size_t)(r0 + ty + i * 8) * C + c0 + tx];
    __syncthreads();
#pragma unroll
    for (int i = 0; i < 4; ++i)
        out[(size_t)(c0 + ty + i * 8) * R + r0 + tx] = (half_t)(tile[tx][ty + i * 8] * scale);
}

__global__ __launch_bounds__(256)
void pack_masks(const float* __restrict__ cm, const int* __restrict__ ids,
                u32* __restrict__ crossb, u32* __restrict__ selfb)
{
    const int t = blockIdx.x;
    const float* row = cm + (size_t)t * S_DIM;
    __shared__ u32 cb[S_DIM / 32];
    __shared__ u16 sh16[256];
    const int tid = threadIdx.x;
    u32 bits = 0;
#pragma unroll
    for (int q = 0; q < 4; ++q) {
        float4 v = *(const float4*)&row[tid * 16 + q * 4];
        bits |= (v.x > 0.5f ? 1u : 0u) << (q * 4 + 0);
        bits |= (v.y > 0.5f ? 1u : 0u) << (q * 4 + 1);
        bits |= (v.z > 0.5f ? 1u : 0u) << (q * 4 + 2);
        bits |= (v.w > 0.5f ? 1u : 0u) << (q * 4 + 3);
    }
    ((u16*)cb)[tid] = (u16)bits;
    __syncthreads();
    u32 sb = 0;
#pragma unroll
    for (int q = 0; q < 4; ++q) {
        int4 id4 = *(const int4*)&ids[tid * 16 + q * 4];
        sb |= ((cb[id4.x >> 5] >> (id4.x & 31)) & 1u) << (q * 4 + 0);
        sb |= ((cb[id4.y >> 5] >> (id4.y & 31)) & 1u) << (q * 4 + 1);
        sb |= ((cb[id4.z >> 5] >> (id4.z & 31)) & 1u) << (q * 4 + 2);
        sb |= ((cb[id4.w >> 5] >> (id4.w & 31)) & 1u) << (q * 4 + 3);
    }
    sh16[tid] = (u16)sb;
    __syncthreads();
    if (tid < 128) {
        crossb[(size_t)t * 128 + tid] = cb[tid];
        selfb[(size_t)t * 128 + tid]  = (u32)sh16[2 * tid] | ((u32)sh16[2 * tid + 1] << 16);
    }
}

// ---------------------------------------------------------------------------
extern "C" void kernel_launch(void* const* d_in, const int* in_sizes, int n_in,
                              void* d_out, int out_size, void* d_ws, size_t ws_size,
                              hipStream_t stream)
{
    (void)in_sizes; (void)n_in; (void)out_size; (void)ws_size;

    const float* x0p  = (const float*)d_in[0];
    const float* encp = (const float*)d_in[1];
    const float* cmp  = (const float*)d_in[2];
    const float* Wq = (const float*)d_in[3], *Wk = (const float*)d_in[4];
    const float* Wv = (const float*)d_in[5], *Wo = (const float*)d_in[6];
    const float* Cq = (const float*)d_in[7], *Ck = (const float*)d_in[8];
    const float* Cv = (const float*)d_in[9], *Co = (const float*)d_in[10];
    const float* W1p = (const float*)d_in[11];
    const float* W2p = (const float*)d_in[12];
    const float* alphap = (const float*)d_in[13];
    const float* gammap = (const float*)d_in[14];
    const int*   idsp   = (const int*)d_in[15];
    float* outp = (float*)d_out;

    char* wp = (char*)d_ws;
    auto take = [&](size_t nelem, int esz) -> void* {
        void* p = (void*)wp;
        wp += (nelem * (size_t)esz + 255) & ~(size_t)255;
        return p;
    };
    half_t* wqkvT = (half_t*)take((size_t)NLAYER * 1536 * 512, 2);
    half_t* ckvT  = (half_t*)take((size_t)NLAYER * 1024 * 512, 2);
    half_t* cqT   = (half_t*)take((size_t)NLAYER * 512 * 512, 2);
    half_t* woT   = (half_t*)take((size_t)NLAYER * 512 * 512, 2);
    half_t* coT   = (half_t*)take((size_t)NLAYER * 512 * 512, 2);
    half_t* w1T   = (half_t*)take((size_t)NLAYER * D_DIM * F_DIM, 2);
    half_t* w2T   = (half_t*)take((size_t)NLAYER * D_DIM * F_DIM, 2);
    half_t* hh    = (half_t*)take((size_t)T_DIM * D_DIM, 2);
    half_t* qb    = (half_t*)take((size_t)T_DIM * D_DIM, 2);
    half_t* kb    = (half_t*)take((size_t)S_DIM * D_DIM, 2);
    half_t* vb    = (half_t*)take((size_t)S_DIM * D_DIM, 2);
    half_t* vTp   = (half_t*)take((size_t)S_DIM * D_DIM, 2);
    half_t* mid   = (half_t*)take((size_t)T_DIM * F_DIM, 2);
    half_t* enc16 = (half_t*)take((size_t)S_DIM * D_DIM, 2);
    half_t* kbC   = (half_t*)take((size_t)NLAYER * S_DIM * D_DIM, 2);
    half_t* vC    = (half_t*)take((size_t)NLAYER * S_DIM * D_DIM, 2);
    half_t* vTCp  = (half_t*)take((size_t)NLAYER * S_DIM * D_DIM, 2);
    float* xbuf   = (float*)take((size_t)T_DIM * D_DIM, 4);
    half_t* logit16 = (half_t*)take((size_t)T_DIM * S_DIM, 2);
    half_t* p16   = (half_t*)take((size_t)T_DIM * 2048, 2);
    float* pbuf   = (float*)take((size_t)T_DIM * 2048, 4);
    float2* rowstat = (float2*)take((size_t)T_DIM, 8);
    u32* crossb = (u32*)take((size_t)T_DIM * (S_DIM / 32), 4);
    u32* selfb  = (u32*)take((size_t)T_DIM * (S_DIM / 32), 4);

    const dim3 B(256), B512(512);
    const float qscale = 0.04419417382415922f; // 1/sqrt(512), folded into Wq/Cq

    // ---- one-time prep ----
    const int SQ = 512 * 512, FZ = 512 * 2048;
    transpose_cast8<<<dim3(16, 16, 32), B, 0, stream>>>(
        Wq, Wk, Wv, Wo, Cq, Ck, Cv, Co,
        wqkvT, wqkvT + SQ, wqkvT + 2 * SQ, woT, cqT, ckvT, ckvT + SQ, coT, qscale);
    transpose_cast<<<dim3(64,16,4), B, 0, stream>>>(W1p, w1T, 512, 2048, 1.f, FZ, FZ);
    transpose_cast<<<dim3(16,64,4), B, 0, stream>>>(W2p, w2T, 2048, 512, 1.f, FZ, FZ);
    cast_f16<<<dim3((S_DIM * D_DIM / 8) / 256), B, 0, stream>>>(encp, enc16);
    pack_masks<<<dim3(T_DIM), B, 0, stream>>>(cmp, idsp, crossb, selfb);
    gemm_nt<64, 7><<<dim3(2048), B512, 0, stream>>>(enc16, 512, ckvT, 512,
        4096, 512, 64, nullptr, kbC, vC, 0);
    gemm_fold<<<dim3(256, 1, NLAYER), B512, 0, stream>>>(coT, vC, vTCp,
        SQ, (long)KVS, (long)KVS);

    for (int l = 0; l < NLAYER; ++l) {
        // ---- head: residual fold of prev W2 + norm ----
        if (l == 0)
            norm_rows<0><<<T_DIM / 4, B, 0, stream>>>(x0p, hh, nullptr, nullptr, nullptr);
        else
            norm_red<0><<<T_DIM / 4, B, 0, stream>>>(xbuf, pbuf, xbuf, hh, nullptr, nullptr, nullptr);

        // ---- self attention ----
        gemm_nt<64, 5><<<dim3(768), B512, 0, stream>>>(hh, 512, wqkvT + (size_t)l * 1536 * 512, 512,
            1536, 512, 24, qb, kb, vb, 0);
        gemm_fold<<<dim3(256, 1, 1), B512, 0, stream>>>(woT + (size_t)l * SQ, vb, vTp, 0, 0, 0);
        gemm_logits<<<dim3(1024), B, 0, stream>>>(qb, kb, selfb, logit16);
        row_stats<<<dim3(T_DIM), B, 0, stream>>>(logit16, rowstat);
        gemm_pv<<<dim3(512), B, 0, stream>>>(logit16, vTp, rowstat, p16);
        attn_tail<<<dim3(T_DIM / 4), B, 0, stream>>>((l == 0) ? x0p : xbuf, p16, xbuf, hh);

        // ---- cross attention ----
        gemm_nt<64, 2><<<dim3(256), B512, 0, stream>>>(hh, 512, cqT + (size_t)l * SQ, 512,
            512, 512, 8, qb, nullptr, nullptr, 512);
        gemm_logits<<<dim3(1024), B, 0, stream>>>(qb, kbC + (size_t)l * KVS, crossb, logit16);
        row_stats<<<dim3(T_DIM), B, 0, stream>>>(logit16, rowstat);
        gemm_pv<<<dim3(512), B, 0, stream>>>(logit16, vTCp + (size_t)l * KVS, rowstat, p16);
        attn_tail<<<dim3(T_DIM / 4), B, 0, stream>>>(xbuf, p16, xbuf, hh);

        // ---- FFN ----
        gemm97<4><<<dim3(512), B, 0, stream>>>(hh, 512, w1T + (size_t)l * FZ, 512,
            512, 16, mid, nullptr, 2048);
        gemm97<0, 4, 0><<<dim3(512), B, 0, stream>>>(mid, 2048, w2T + (size_t)l * FZ, 2048,
            2048, 4, nullptr, pbuf, 2048);
    }

    norm_red<1><<<T_DIM / 4, B, 0, stream>>>(xbuf, pbuf, xbuf, nullptr, outp, alphap, gammap);
}

// Round 14
// 1218.166 us; speedup vs baseline: 1.0077x; 1.0077x over previous
//
#include <hip/hip_runtime.h>
#include <math.h>

typedef _Float16 half_t;
typedef unsigned int u32;
typedef unsigned short u16;
typedef float f32x4 __attribute__((ext_vector_type(4)));
typedef _Float16 f16x8 __attribute__((ext_vector_type(8)));
typedef _Float16 f16x4 __attribute__((ext_vector_type(4)));

#define T_DIM 4096
#define S_DIM 4096
#define D_DIM 512
#define F_DIM 2048
#define NLAYER 4
#define KVS ((size_t)4096 * 512)

__device__ __forceinline__ void gload16(const void* g, void* l) {
    __builtin_amdgcn_global_load_lds(
        (const __attribute__((address_space(1))) u32*)g,
        (__attribute__((address_space(3))) u32*)l, 16, 0, 0);
}

template<int N> __device__ __forceinline__ void wait_vm() {
    if constexpr (N == 0) asm volatile("s_waitcnt vmcnt(0)" ::: "memory");
    else if constexpr (N == 3) asm volatile("s_waitcnt vmcnt(3)" ::: "memory");
    else if constexpr (N == 4) asm volatile("s_waitcnt vmcnt(4)" ::: "memory");
    else if constexpr (N == 6) asm volatile("s_waitcnt vmcnt(6)" ::: "memory");
    else if constexpr (N == 8) asm volatile("s_waitcnt vmcnt(8)" ::: "memory");
}
__device__ __forceinline__ void wait_lgkm0() {
    asm volatile("s_waitcnt lgkmcnt(0)" ::: "memory");
}

// ---------------------------------------------------------------------------
// Workhorse: 512 thr, BM=128, BK=64, wave tile 32xBN/2.
// EPI: 2 fp16 [M,N] (ldd) | 5 QKV split row-major | 7 batched cross-KV.
// ---------------------------------------------------------------------------
template<int BN, int EPI>
__global__ __launch_bounds__(512)
void gemm_nt(const half_t* __restrict__ A, int lda,
             const half_t* __restrict__ B, int ldb,
             int N, int K, int gx,
             half_t* __restrict__ D1, half_t* __restrict__ D2,
             half_t* __restrict__ D3, int ldd)
{
    constexpr int BM = 128, BK = 64;
    constexpr int NF = BN / 32;
    constexpr int LPT = 2 + BN / 64;
    constexpr int NSLOT = (BN == 64) ? 3 : 2;
    __shared__ half_t As[NSLOT][BM * BK];
    __shared__ half_t Bs[NSLOT][BN * BK];

    const int tid  = threadIdx.x;
    const int wave = tid >> 6;
    const int lane = tid & 63;

    const int nb  = gridDim.x;
    const int bid = blockIdx.x;
    const int nid = (bid & 7) * (nb >> 3) + (bid >> 3);
    const int bx  = nid % gx;
    const int by  = nid / gx;
    const int bm = by * BM, bn = bx * BN;

    const int wm = (wave >> 1) * 32;
    const int wn = (wave & 1) * (BN / 2);
    const int kq = lane >> 4;
    const int rr = lane & 15;
    const int scol = (((lane & 7) ^ (lane >> 3)) << 3);

    f32x4 acc[2][NF];
#pragma unroll
    for (int m = 0; m < 2; ++m)
#pragma unroll
        for (int n = 0; n < NF; ++n)
            acc[m][n] = f32x4{0.f, 0.f, 0.f, 0.f};

    auto stage = [&](int buf, int k0) {
#pragma unroll
        for (int c = 0; c < 2; ++c) {
            const int row = wave * 16 + c * 8 + (lane >> 3);
            gload16(A + (size_t)(bm + row) * lda + k0 + scol,
                    (char*)&As[buf][0] + (wave * 2 + c) * 1024 + lane * 16);
        }
        if constexpr (BN == 64) {
            const int row = wave * 8 + (lane >> 3);
            gload16(B + (size_t)(bn + row) * ldb + k0 + scol,
                    (char*)&Bs[buf][0] + wave * 1024 + lane * 16);
        } else {
#pragma unroll
            for (int c = 0; c < 2; ++c) {
                const int row = wave * 16 + c * 8 + (lane >> 3);
                gload16(B + (size_t)(bn + row) * ldb + k0 + scol,
                        (char*)&Bs[buf][0] + (wave * 2 + c) * 1024 + lane * 16);
            }
        }
    };

    const int nt = K / BK;
    stage(0, 0);
    if constexpr (NSLOT == 3) stage(1, BK);
    int cur = 0, pf = NSLOT - 1;
    for (int t = 0; t < nt; ++t) {
        if (t + 1 < nt) wait_vm<(NSLOT - 2) * LPT>(); else wait_vm<0>();
        __builtin_amdgcn_s_barrier();
        if (t + NSLOT - 1 < nt) stage(pf, (t + NSLOT - 1) * BK);
#pragma unroll
        for (int ks = 0; ks < 2; ++ks) {
            f16x8 af[2], bf[NF];
#pragma unroll
            for (int m = 0; m < 2; ++m) {
                const int r = wm + m * 16 + rr;
                af[m] = *(const f16x8*)&As[cur][r * BK + (((ks * 4 + kq) ^ (r & 7)) << 3)];
            }
#pragma unroll
            for (int n = 0; n < NF; ++n) {
                const int r = wn + n * 16 + rr;
                bf[n] = *(const f16x8*)&Bs[cur][r * BK + (((ks * 4 + kq) ^ (r & 7)) << 3)];
            }
#pragma unroll
            for (int m = 0; m < 2; ++m)
#pragma unroll
                for (int n = 0; n < NF; ++n)
                    acc[m][n] = __builtin_amdgcn_mfma_f32_16x16x32_f16(af[m], bf[n], acc[m][n], 0, 0, 0);
        }
        cur = (cur + 1 == NSLOT) ? 0 : cur + 1;
        pf  = (pf  + 1 == NSLOT) ? 0 : pf  + 1;
    }

    const int r0 = bm + wm + (lane >> 4) * 4;
#pragma unroll
    for (int m = 0; m < 2; ++m)
#pragma unroll
        for (int n = 0; n < NF; ++n) {
            const int c = bn + wn + n * 16 + rr;
            if (EPI == 2) {
#pragma unroll
                for (int i = 0; i < 4; ++i)
                    D1[(size_t)(r0 + m * 16 + i) * ldd + c] = (half_t)acc[m][n][i];
            } else if (EPI == 5) {
                half_t* Dst = (bn < 512) ? D1 : (bn < 1024) ? D2 : D3;
                const int sub = c & 511;
#pragma unroll
                for (int i = 0; i < 4; ++i)
                    Dst[(size_t)(r0 + m * 16 + i) * 512 + sub] = (half_t)acc[m][n][i];
            } else { // EPI == 7 batched cross-KV (row-major K and v)
                const int l = c >> 10;
                const int sub = c & 1023;
                half_t* Dst = (sub < 512) ? (D2 + l * KVS) : (D3 + l * KVS);
                const int d = sub & 511;
#pragma unroll
                for (int i = 0; i < 4; ++i)
                    Dst[(size_t)(r0 + m * 16 + i) * 512 + d] = (half_t)acc[m][n][i];
            }
        }
}

// ---------------------------------------------------------------------------
// V-fold GEMM (z-batched): Out[z][d',s] = sum_d Wt[z][d',d] * V[z][s,d].
// ---------------------------------------------------------------------------
__global__ __launch_bounds__(512)
void gemm_fold(const half_t* __restrict__ Wt, const half_t* __restrict__ V,
               half_t* __restrict__ Out, int zSA, long zSB, long zSD)
{
    constexpr int BM = 128, BK = 64, BN = 64, NSLOT = 3, LPT = 3;
    __shared__ half_t As[NSLOT][BM * BK];
    __shared__ half_t Bs[NSLOT][BN * BK];

    const half_t* A = Wt + (size_t)blockIdx.z * zSA;
    const half_t* B = V  + (size_t)blockIdx.z * zSB;
    half_t* D = Out + (size_t)blockIdx.z * zSD;

    const int tid  = threadIdx.x;
    const int wave = tid >> 6;
    const int lane = tid & 63;

    const int nb  = gridDim.x;   // 256
    const int bid = blockIdx.x;
    const int nid = (bid & 7) * (nb >> 3) + (bid >> 3);
    const int bx = nid & 63, by = nid >> 6;
    const int bm = by * BM, bn = bx * BN;

    const int wm = (wave >> 1) * 32;
    const int wn = (wave & 1) * 32;
    const int kq = lane >> 4;
    const int rr = lane & 15;
    const int scol = (((lane & 7) ^ (lane >> 3)) << 3);

    f32x4 acc[2][2];
#pragma unroll
    for (int m = 0; m < 2; ++m)
#pragma unroll
        for (int n = 0; n < 2; ++n)
            acc[m][n] = f32x4{0.f, 0.f, 0.f, 0.f};

    auto stage = [&](int buf, int k0) {
#pragma unroll
        for (int c = 0; c < 2; ++c) {
            const int row = wave * 16 + c * 8 + (lane >> 3);
            gload16(A + (size_t)(bm + row) * 512 + k0 + scol,
                    (char*)&As[buf][0] + (wave * 2 + c) * 1024 + lane * 16);
        }
        const int row = wave * 8 + (lane >> 3);
        gload16(B + (size_t)(bn + row) * 512 + k0 + scol,
                (char*)&Bs[buf][0] + wave * 1024 + lane * 16);
    };

    const int nt = 512 / BK;   // 8
    stage(0, 0);
    stage(1, BK);
    int cur = 0, pf = 2;
    for (int t = 0; t < nt; ++t) {
        if (t + 1 < nt) wait_vm<LPT>(); else wait_vm<0>();
        __builtin_amdgcn_s_barrier();
        if (t + 2 < nt) stage(pf, (t + 2) * BK);
#pragma unroll
        for (int ks = 0; ks < 2; ++ks) {
            f16x8 af[2], bf[2];
#pragma unroll
            for (int m = 0; m < 2; ++m) {
                const int r = wm + m * 16 + rr;
                af[m] = *(const f16x8*)&As[cur][r * BK + (((ks * 4 + kq) ^ (r & 7)) << 3)];
            }
#pragma unroll
            for (int n = 0; n < 2; ++n) {
                const int r = wn + n * 16 + rr;
                bf[n] = *(const f16x8*)&Bs[cur][r * BK + (((ks * 4 + kq) ^ (r & 7)) << 3)];
            }
#pragma unroll
            for (int m = 0; m < 2; ++m)
#pragma unroll
                for (int n = 0; n < 2; ++n)
                    acc[m][n] = __builtin_amdgcn_mfma_f32_16x16x32_f16(af[m], bf[n], acc[m][n], 0, 0, 0);
        }
        cur = (cur + 1 == NSLOT) ? 0 : cur + 1;
        pf  = (pf  + 1 == NSLOT) ? 0 : pf  + 1;
    }

    const int r0 = bm + wm + (lane >> 4) * 4;
#pragma unroll
    for (int m = 0; m < 2; ++m)
#pragma unroll
        for (int n = 0; n < 2; ++n) {
            const int c = bn + wn + n * 16 + rr;
#pragma unroll
            for (int i = 0; i < 4; ++i)
                D[(size_t)(r0 + m * 16 + i) * 4096 + c] = (half_t)acc[m][n][i];
        }
}

// ---------------------------------------------------------------------------
// m97 geometry: used for W1 (EPI 4) and W2 split-K fp32.
// ---------------------------------------------------------------------------
template<int EPI, int SPLITK = 1, int P16 = 1>
__global__ __launch_bounds__(256)
void gemm97(const half_t* __restrict__ A, int lda,
            const half_t* __restrict__ B, int ldb,
            int K, int gx, half_t* __restrict__ D,
            float* __restrict__ Fout, int ldd)
{
    constexpr int BK = 32, NSLOT = 3, LPT = 4;
    __shared__ half_t As[NSLOT][128 * BK];
    __shared__ half_t Bs[NSLOT][128 * BK];

    const int tid  = threadIdx.x;
    const int wave = tid >> 6;
    const int lane = tid & 63;

    const int nb  = gridDim.x;
    const int bid = blockIdx.x;
    const int nid = (bid & 7) * (nb >> 3) + (bid >> 3);
    const int gy  = nb / (gx * SPLITK);
    const int bx  = nid % gx;
    const int tmp = nid / gx;
    const int by  = tmp % gy;
    const int kz  = tmp / gy;
    const int bm = by * 128, bn = bx * 128;

    const int Keff = K / SPLITK;
    A += (size_t)kz * Keff;
    B += (size_t)kz * Keff;

    const int wm = (wave >> 1) * 64;
    const int wn = (wave & 1) * 64;
    const int kq = lane >> 4;
    const int rr = lane & 15;
    const int srow = lane >> 2;
    const int scol = (((lane & 3) ^ ((lane >> 3) & 3)) << 3);
    const int kqa  = kq ^ ((rr >> 1) & 3);

    const half_t* Abase = A + (size_t)(bm + wave * 16 + srow) * lda + scol;
    const half_t* Bbase = B + (size_t)(bn + wave * 16 + srow) * ldb + scol;

    f32x4 acc[4][4];
#pragma unroll
    for (int m = 0; m < 4; ++m)
#pragma unroll
        for (int n = 0; n < 4; ++n)
            acc[m][n] = f32x4{0.f, 0.f, 0.f, 0.f};

    auto stage = [&](int buf, int k0) {
#pragma unroll
        for (int c = 0; c < 2; ++c)
            gload16(Abase + (size_t)c * 64 * lda + k0,
                    (char*)&As[buf][0] + c * 4096 + wave * 1024 + lane * 16);
#pragma unroll
        for (int c = 0; c < 2; ++c)
            gload16(Bbase + (size_t)c * 64 * ldb + k0,
                    (char*)&Bs[buf][0] + c * 4096 + wave * 1024 + lane * 16);
    };

    const int nt = Keff / BK;
    stage(0, 0);
    stage(1, BK);
    int cur = 0, pf = 2;
    for (int t = 0; t < nt; ++t) {
        if (t + 1 < nt) wait_vm<LPT>(); else wait_vm<0>();
        __builtin_amdgcn_s_barrier();
        if (t + 2 < nt) stage(pf, (t + 2) * BK);
        f16x8 af[4], bf[4];
#pragma unroll
        for (int m = 0; m < 4; ++m)
            af[m] = *(const f16x8*)&As[cur][(wm + m * 16 + rr) * BK + kqa * 8];
#pragma unroll
        for (int n = 0; n < 4; ++n)
            bf[n] = *(const f16x8*)&Bs[cur][(wn + n * 16 + rr) * BK + kqa * 8];
#pragma unroll
        for (int m = 0; m < 4; ++m)
#pragma unroll
            for (int n = 0; n < 4; ++n)
                acc[m][n] = __builtin_amdgcn_mfma_f32_16x16x32_f16(af[m], bf[n], acc[m][n], 0, 0, 0);
        cur = (cur == 2) ? 0 : cur + 1;
        pf  = (pf  == 2) ? 0 : pf + 1;
    }

    const int r0 = bm + wm + (lane >> 4) * 4;
    const int soff = kz * gx * 128;
#pragma unroll
    for (int m = 0; m < 4; ++m)
#pragma unroll
        for (int n = 0; n < 4; ++n) {
            const int c = bn + wn + n * 16 + rr;
#pragma unroll
            for (int i = 0; i < 4; ++i) {
                float v = acc[m][n][i];
                const size_t r = r0 + m * 16 + i;
                if constexpr (SPLITK > 1) {
                    if constexpr (P16) D[r * ldd + soff + c] = (half_t)v;
                    else               Fout[r * ldd + soff + c] = v;
                } else {
                    if (EPI == 4) v = fmaxf(v, 0.f);
                    D[r * ldd + c] = (half_t)v;
                }
            }
        }
}

// ---------------------------------------------------------------------------
// Logits GEMM + fused MASK epilogue. __launch_bounds__(256,4) caps VGPR at
// 128 (round 13 without it: 132 VGPR -> occupancy halved -> 48us; round 12
// with it: 100 VGPR). Masked z stored fp16 (-1e9 -> -inf, exp -> 0).
// ---------------------------------------------------------------------------
__global__ __launch_bounds__(256, 4)
void gemm_logits(const half_t* __restrict__ A, const half_t* __restrict__ B,
                 const u32* __restrict__ bits, half_t* __restrict__ D)
{
    constexpr int BK = 32, NSLOT = 3, LPT = 4, nt = 16;  // K=512
    __shared__ half_t As[NSLOT][128 * BK];
    __shared__ half_t Bs[NSLOT][128 * BK];

    const int tid  = threadIdx.x;
    const int wave = tid >> 6;
    const int lane = tid & 63;

    const int nb  = gridDim.x;   // 1024
    const int bid = blockIdx.x;
    const int nid = (bid & 7) * (nb >> 3) + (bid >> 3);
    const int bx = nid & 31, by = nid >> 5;
    const int bm = by * 128, bn = bx * 128;

    const int wm = (wave >> 1) * 64;
    const int wn = (wave & 1) * 64;
    const int kq = lane >> 4;
    const int rr = lane & 15;
    const int srow = lane >> 2;
    const int scol = (((lane & 3) ^ ((lane >> 3) & 3)) << 3);
    const int kqa  = kq ^ ((rr >> 1) & 3);

    const half_t* Abase = A + (size_t)(bm + wave * 16 + srow) * 512 + scol;
    const half_t* Bbase = B + (size_t)(bn + wave * 16 + srow) * 512 + scol;

    f32x4 acc[4][4];
#pragma unroll
    for (int m = 0; m < 4; ++m)
#pragma unroll
        for (int n = 0; n < 4; ++n)
            acc[m][n] = f32x4{0.f, 0.f, 0.f, 0.f};

    auto stage = [&](int buf, int k0) {
#pragma unroll
        for (int c = 0; c < 2; ++c)
            gload16(Abase + (size_t)c * 64 * 512 + k0,
                    (char*)&As[buf][0] + c * 4096 + wave * 1024 + lane * 16);
#pragma unroll
        for (int c = 0; c < 2; ++c)
            gload16(Bbase + (size_t)c * 64 * 512 + k0,
                    (char*)&Bs[buf][0] + c * 4096 + wave * 1024 + lane * 16);
    };

    stage(0, 0);
    stage(1, BK);
    int cur = 0, pf = 2;
    for (int t = 0; t < nt; ++t) {
        if (t + 1 < nt) wait_vm<LPT>(); else wait_vm<0>();
        __builtin_amdgcn_s_barrier();
        if (t + 2 < nt) stage(pf, (t + 2) * BK);
        f16x8 af[4], bf[4];
#pragma unroll
        for (int m = 0; m < 4; ++m)
            af[m] = *(const f16x8*)&As[cur][(wm + m * 16 + rr) * BK + kqa * 8];
#pragma unroll
        for (int n = 0; n < 4; ++n)
            bf[n] = *(const f16x8*)&Bs[cur][(wn + n * 16 + rr) * BK + kqa * 8];
#pragma unroll
        for (int m = 0; m < 4; ++m)
#pragma unroll
            for (int n = 0; n < 4; ++n)
                acc[m][n] = __builtin_amdgcn_mfma_f32_16x16x32_f16(af[m], bf[n], acc[m][n], 0, 0, 0);
        cur = (cur == 2) ? 0 : cur + 1;
        pf  = (pf  == 2) ? 0 : pf + 1;
    }

    // ---- epilogue: mask (broadcast bit loads, no cross-lane) + fp16 store ----
    const int g4 = (lane >> 4) * 4;
    const int r0 = bm + wm + g4;
    const int wordbase = (bn + wn) >> 5;
#pragma unroll
    for (int m = 0; m < 4; ++m)
#pragma unroll
        for (int i = 0; i < 4; ++i) {
            const int r = r0 + m * 16 + i;
            const u32 w01 = bits[(size_t)r * 128 + wordbase];
            const u32 w23 = bits[(size_t)r * 128 + wordbase + 1];
            acc[m][0][i] += (((w01 >> rr) & 1u) ? 0.f : -1e9f);
            acc[m][1][i] += (((w01 >> (16 + rr)) & 1u) ? 0.f : -1e9f);
            acc[m][2][i] += (((w23 >> rr) & 1u) ? 0.f : -1e9f);
            acc[m][3][i] += (((w23 >> (16 + rr)) & 1u) ? 0.f : -1e9f);
        }
#pragma unroll
    for (int m = 0; m < 4; ++m)
#pragma unroll
        for (int n = 0; n < 4; ++n) {
            const int c = bn + wn + n * 16 + rr;
#pragma unroll
            for (int i = 0; i < 4; ++i)
                D[(size_t)(r0 + m * 16 + i) * 4096 + c] = (half_t)acc[m][n][i];
        }
}

// ---------------------------------------------------------------------------
// row_stats: per-row {M, 1/S} from masked fp16 z (read-only, one block/row).
// ---------------------------------------------------------------------------
__global__ __launch_bounds__(256)
void row_stats(const half_t* __restrict__ logits, float2* __restrict__ rowstat)
{
    const int t = blockIdx.x;
    const half_t* row = logits + (size_t)t * S_DIM;
    __shared__ float red[8];
    const int tid = threadIdx.x, wave = tid >> 6, lane = tid & 63;
    const int s0 = tid * 16;
    f16x8 h0 = *(const f16x8*)&row[s0];
    f16x8 h1 = *(const f16x8*)&row[s0 + 8];
    float z[16];
    float lmax = -3.0e38f;
#pragma unroll
    for (int q = 0; q < 16; ++q) {
        z[q] = (float)((q < 8) ? h0[q & 7] : h1[q & 7]);
        lmax = fmaxf(lmax, z[q]);
    }
#pragma unroll
    for (int off = 32; off; off >>= 1) lmax = fmaxf(lmax, __shfl_xor(lmax, off));
    if (lane == 0) red[wave] = lmax;
    __syncthreads();
    const float mx = fmaxf(fmaxf(red[0], red[1]), fmaxf(red[2], red[3]));
    float lsum = 0.f;
#pragma unroll
    for (int q = 0; q < 16; ++q) lsum += __expf(z[q] - mx);
#pragma unroll
    for (int off = 32; off; off >>= 1) lsum += __shfl_xor(lsum, off);
    if (lane == 0) red[4 + wave] = lsum;
    __syncthreads();
    if (tid == 0)
        rowstat[t] = float2{mx, 1.f / (red[4] + red[5] + red[6] + red[7])};
}

// ---------------------------------------------------------------------------
// PV GEMM with on-the-fly P = exp(z - M) * inv (round-12, proven).
// ---------------------------------------------------------------------------
__global__ __launch_bounds__(256)
void gemm_pv(const half_t* __restrict__ A, const half_t* __restrict__ B,
             const float2* __restrict__ rowstat, half_t* __restrict__ D)
{
    constexpr int BK = 32, NSLOT = 3, Keff = 1024, nt = 32;
    __shared__ half_t As[NSLOT][128 * BK];
    __shared__ half_t Bs[NSLOT][128 * BK];

    const int tid = threadIdx.x, wave = tid >> 6, lane = tid & 63;
    const int nb = gridDim.x, bid = blockIdx.x;
    const int nid = (bid & 7) * (nb >> 3) + (bid >> 3);
    const int bx = nid & 3;
    const int tmp = nid >> 2;
    const int by = tmp & 31, kz = tmp >> 5;
    const int bm = by * 128, bn = bx * 128;

    const int wm = (wave >> 1) * 64, wn = (wave & 1) * 64;
    const int kq = lane >> 4, rr = lane & 15, srow = lane >> 2;
    const int scol = (((lane & 3) ^ ((lane >> 3) & 3)) << 3);
    const int kqa = kq ^ ((rr >> 1) & 3);

    const int arow = bm + wave * 16 + srow;
    const half_t* Abase = A + (size_t)arow * 4096 + kz * Keff + scol;
    const half_t* Bbase = B + (size_t)(bn + wave * 16 + srow) * 4096 + kz * Keff + scol;

    const float2 rs0 = rowstat[arow];
    const float2 rs1 = rowstat[arow + 64];
    asm volatile("s_waitcnt vmcnt(0)" ::: "memory");
    const float M0 = rs0.x, I0 = rs0.y, M1 = rs1.x, I1 = rs1.y;

    f32x4 acc[4][4];
#pragma unroll
    for (int m = 0; m < 4; ++m)
#pragma unroll
        for (int n = 0; n < 4; ++n)
            acc[m][n] = f32x4{0.f, 0.f, 0.f, 0.f};

    auto loadA = [&](int k0, f16x8& a0, f16x8& a1) {
        a0 = *(const f16x8*)(Abase + k0);
        a1 = *(const f16x8*)(Abase + (size_t)64 * 4096 + k0);
    };
    auto gloadB = [&](int buf, int k0) {
        gload16(Bbase + k0, (char*)&Bs[buf][0] + wave * 1024 + lane * 16);
        gload16(Bbase + (size_t)64 * 4096 + k0,
                (char*)&Bs[buf][0] + 4096 + wave * 1024 + lane * 16);
    };
    auto writeA = [&](int buf, const f16x8& a0, const f16x8& a1) {
        f16x8 p0, p1;
#pragma unroll
        for (int e = 0; e < 8; ++e) {
            p0[e] = (half_t)(__expf((float)a0[e] - M0) * I0);
            p1[e] = (half_t)(__expf((float)a1[e] - M1) * I1);
        }
        *(f16x8*)((char*)&As[buf][0] + wave * 1024 + lane * 16) = p0;
        *(f16x8*)((char*)&As[buf][0] + 4096 + wave * 1024 + lane * 16) = p1;
    };
    auto compute = [&](int s) {
        f16x8 af[4], bf[4];
#pragma unroll
        for (int m = 0; m < 4; ++m)
            af[m] = *(const f16x8*)&As[s][(wm + m * 16 + rr) * BK + kqa * 8];
#pragma unroll
        for (int n = 0; n < 4; ++n)
            bf[n] = *(const f16x8*)&Bs[s][(wn + n * 16 + rr) * BK + kqa * 8];
#pragma unroll
        for (int m = 0; m < 4; ++m)
#pragma unroll
            for (int n = 0; n < 4; ++n)
                acc[m][n] = __builtin_amdgcn_mfma_f32_16x16x32_f16(af[m], bf[n], acc[m][n], 0, 0, 0);
    };

    f16x8 a0A, a1A, a0B, a1B;
    loadA(0, a0A, a1A);  gloadB(0, 0);
    loadA(BK, a0B, a1B); gloadB(1, BK);
    wait_vm<4>();
    writeA(0, a0A, a1A);
    wait_lgkm0();
    __builtin_amdgcn_s_barrier();

    int cur = 0, pf = 2;
    for (int t = 0; t < nt; t += 2) {
        {
            const bool hasPF = (t + 2 < nt);
            if (hasPF) { loadA((t + 2) * BK, a0A, a1A); gloadB(pf, (t + 2) * BK); }
            compute(cur);
            if (t + 1 < nt) {
                if (hasPF) wait_vm<4>(); else wait_vm<0>();
                writeA((cur + 1 == NSLOT) ? 0 : cur + 1, a0B, a1B);
                wait_lgkm0();
            }
            __builtin_amdgcn_s_barrier();
            cur = (cur + 1 == NSLOT) ? 0 : cur + 1;
            pf  = (pf  + 1 == NSLOT) ? 0 : pf + 1;
        }
        {
            const int u = t + 1;
            const bool hasPF = (u + 2 < nt);
            if (hasPF) { loadA((u + 2) * BK, a0B, a1B); gloadB(pf, (u + 2) * BK); }
            compute(cur);
            if (u + 1 < nt) {
                if (hasPF) wait_vm<4>(); else wait_vm<0>();
                writeA((cur + 1 == NSLOT) ? 0 : cur + 1, a0A, a1A);
                wait_lgkm0();
            }
            __builtin_amdgcn_s_barrier();
            cur = (cur + 1 == NSLOT) ? 0 : cur + 1;
            pf  = (pf  + 1 == NSLOT) ? 0 : pf + 1;
        }
    }

    const int r0 = bm + wm + (lane >> 4) * 4;
    const int soff = kz * 512;
#pragma unroll
    for (int m = 0; m < 4; ++m)
#pragma unroll
        for (int n = 0; n < 4; ++n) {
            const int c = bn + wn + n * 16 + rr;
#pragma unroll
            for (int i = 0; i < 4; ++i)
                D[(size_t)(r0 + m * 16 + i) * 2048 + soff + c] = (half_t)acc[m][n][i];
        }
}

// ---------------------------------------------------------------------------
// attn_tail: xbuf = xin + sum of 4 fp16 PV slices; hh = LayerNorm(xbuf).
// ---------------------------------------------------------------------------
__global__ __launch_bounds__(256)
void attn_tail(const float* __restrict__ xin, const half_t* __restrict__ P,
               float* __restrict__ xbuf, half_t* __restrict__ hh)
{
    const int row  = blockIdx.x * 4 + (threadIdx.x >> 6);
    const int lane = threadIdx.x & 63;
    const int d0 = lane * 8;
    float v[8];
    {
        const float* xr = xin + (size_t)row * D_DIM + d0;
        float4 a = *(const float4*)xr;
        float4 b = *(const float4*)(xr + 4);
        v[0]=a.x; v[1]=a.y; v[2]=a.z; v[3]=a.w; v[4]=b.x; v[5]=b.y; v[6]=b.z; v[7]=b.w;
    }
    const half_t* pr = P + (size_t)row * 2048 + d0;
#pragma unroll
    for (int j = 0; j < 4; ++j) {
        f16x8 pv = *(const f16x8*)(pr + j * 512);
#pragma unroll
        for (int e = 0; e < 8; ++e) v[e] += (float)pv[e];
    }
    float* xo = xbuf + (size_t)row * D_DIM + d0;
    *(float4*)xo       = float4{v[0], v[1], v[2], v[3]};
    *(float4*)(xo + 4) = float4{v[4], v[5], v[6], v[7]};

    float s = 0.f;
#pragma unroll
    for (int j = 0; j < 8; ++j) s += v[j];
#pragma unroll
    for (int off = 32; off; off >>= 1) s += __shfl_xor(s, off);
    const float mean = s * (1.f / 512.f);
    float ss = 0.f;
#pragma unroll
    for (int j = 0; j < 8; ++j) { float d = v[j] - mean; ss += d * d; }
#pragma unroll
    for (int off = 32; off; off >>= 1) ss += __shfl_xor(ss, off);
    const float inv = 1.f / (sqrtf(ss * (1.f / 511.f)) + 1e-6f);
    f16x8 hv;
#pragma unroll
    for (int j = 0; j < 8; ++j) hv[j] = (half_t)((v[j] - mean) * inv);
    *(f16x8*)&hh[(size_t)row * D_DIM + d0] = hv;
}

// ---------------------------------------------------------------------------
// norm_red: x = xin + sum of 4 fp32 W2 partial slices [4096][2048].
// ---------------------------------------------------------------------------
template<int FINAL>
__global__ __launch_bounds__(256)
void norm_red(const float* __restrict__ xin, const float* __restrict__ P,
              float* __restrict__ xbuf, half_t* __restrict__ hh,
              float* __restrict__ outF, const float* __restrict__ alphaP,
              const float* __restrict__ gammaP)
{
    const int row  = blockIdx.x * 4 + (threadIdx.x >> 6);
    const int lane = threadIdx.x & 63;
    const int d0 = lane * 8;
    const float* xr = xin + (size_t)row * D_DIM + d0;
    float v[8];
    {
        float4 a = *(const float4*)xr;
        float4 b = *(const float4*)(xr + 4);
        v[0]=a.x; v[1]=a.y; v[2]=a.z; v[3]=a.w; v[4]=b.x; v[5]=b.y; v[6]=b.z; v[7]=b.w;
    }
    const float* pr = P + (size_t)row * 2048 + d0;
#pragma unroll
    for (int j = 0; j < 4; ++j) {
        float4 a = *(const float4*)(pr + j * 512);
        float4 b = *(const float4*)(pr + j * 512 + 4);
        v[0]+=a.x; v[1]+=a.y; v[2]+=a.z; v[3]+=a.w; v[4]+=b.x; v[5]+=b.y; v[6]+=b.z; v[7]+=b.w;
    }
    if (!FINAL) {
        float* xo = xbuf + (size_t)row * D_DIM + d0;
        *(float4*)xo       = float4{v[0], v[1], v[2], v[3]};
        *(float4*)(xo + 4) = float4{v[4], v[5], v[6], v[7]};
    }
    float s = 0.f;
#pragma unroll
    for (int j = 0; j < 8; ++j) s += v[j];
#pragma unroll
    for (int off = 32; off; off >>= 1) s += __shfl_xor(s, off);
    const float mean = s * (1.f / 512.f);
    float ss = 0.f;
#pragma unroll
    for (int j = 0; j < 8; ++j) { float d = v[j] - mean; ss += d * d; }
#pragma unroll
    for (int off = 32; off; off >>= 1) ss += __shfl_xor(ss, off);
    const float inv = 1.f / (sqrtf(ss * (1.f / 511.f)) + 1e-6f);
    if (FINAL) {
        const float alp = alphaP[0], gam = gammaP[0];
        float o[8];
#pragma unroll
        for (int j = 0; j < 8; ++j) o[j] = alp * ((v[j] - mean) * inv) + gam;
        float* op = outF + (size_t)row * D_DIM + d0;
        *(float4*)op       = float4{o[0], o[1], o[2], o[3]};
        *(float4*)(op + 4) = float4{o[4], o[5], o[6], o[7]};
    } else {
        f16x8 hv;
#pragma unroll
        for (int j = 0; j < 8; ++j) hv[j] = (half_t)((v[j] - mean) * inv);
        *(f16x8*)&hh[(size_t)row * D_DIM + d0] = hv;
    }
}

template<int FINAL>
__global__ __launch_bounds__(256)
void norm_rows(const float* __restrict__ x, half_t* __restrict__ hh,
               float* __restrict__ outF, const float* __restrict__ alphaP,
               const float* __restrict__ gammaP)
{
    const int row  = blockIdx.x * 4 + (threadIdx.x >> 6);
    const int lane = threadIdx.x & 63;
    const float* xr = x + (size_t)row * D_DIM + lane * 8;
    float4 a = *(const float4*)xr;
    float4 b = *(const float4*)(xr + 4);
    float v[8] = {a.x, a.y, a.z, a.w, b.x, b.y, b.z, b.w};
    float s = 0.f;
#pragma unroll
    for (int j = 0; j < 8; ++j) s += v[j];
#pragma unroll
    for (int off = 32; off; off >>= 1) s += __shfl_xor(s, off);
    const float mean = s * (1.f / 512.f);
    float ss = 0.f;
#pragma unroll
    for (int j = 0; j < 8; ++j) { float d = v[j] - mean; ss += d * d; }
#pragma unroll
    for (int off = 32; off; off >>= 1) ss += __shfl_xor(ss, off);
    const float inv = 1.f / (sqrtf(ss * (1.f / 511.f)) + 1e-6f);
    if (FINAL) {
        const float alp = alphaP[0], gam = gammaP[0];
        float o[8];
#pragma unroll
        for (int j = 0; j < 8; ++j) o[j] = alp * ((v[j] - mean) * inv) + gam;
        float* op = outF + (size_t)row * D_DIM + lane * 8;
        *(float4*)op       = float4{o[0], o[1], o[2], o[3]};
        *(float4*)(op + 4) = float4{o[4], o[5], o[6], o[7]};
    } else {
        f16x8 hv;
#pragma unroll
        for (int j = 0; j < 8; ++j) hv[j] = (half_t)((v[j] - mean) * inv);
        *(f16x8*)&hh[(size_t)row * D_DIM + lane * 8] = hv;
    }
}

__global__ __launch_bounds__(256)
void cast_f16(const float* __restrict__ in, half_t* __restrict__ out)
{
    size_t i = ((size_t)blockIdx.x * 256 + threadIdx.x) * 8;
    float4 a = *(const float4*)&in[i];
    float4 b = *(const float4*)&in[i + 4];
    float v[8] = {a.x, a.y, a.z, a.w, b.x, b.y, b.z, b.w};
    f16x8 o;
#pragma unroll
    for (int j = 0; j < 8; ++j) o[j] = (half_t)v[j];
    *(f16x8*)&out[i] = o;
}

// batched square-weight transpose: z = t*4 + layer; 8 weights in one launch
__global__ __launch_bounds__(256)
void transpose_cast8(const float* __restrict__ i0, const float* __restrict__ i1,
                     const float* __restrict__ i2, const float* __restrict__ i3,
                     const float* __restrict__ i4, const float* __restrict__ i5,
                     const float* __restrict__ i6, const float* __restrict__ i7,
                     half_t* __restrict__ o0, half_t* __restrict__ o1,
                     half_t* __restrict__ o2, half_t* __restrict__ o3,
                     half_t* __restrict__ o4, half_t* __restrict__ o5,
                     half_t* __restrict__ o6, half_t* __restrict__ o7,
                     float qscale)
{
    const int SQ = 512 * 512, QKVZ = 1536 * 512, KVZ = 1024 * 512;
    const int z = blockIdx.z, t = z >> 2, l = z & 3;
    const float* in; half_t* out; float sc = 1.f; int outZ;
    switch (t) {
        case 0: in = i0; out = o0; sc = qscale; outZ = QKVZ; break;
        case 1: in = i1; out = o1; outZ = QKVZ; break;
        case 2: in = i2; out = o2; outZ = QKVZ; break;
        case 3: in = i3; out = o3; outZ = SQ; break;
        case 4: in = i4; out = o4; sc = qscale; outZ = SQ; break;
        case 5: in = i5; out = o5; outZ = KVZ; break;
        case 6: in = i6; out = o6; outZ = KVZ; break;
        default: in = i7; out = o7; outZ = SQ; break;
    }
    in  += (size_t)l * SQ;
    out += (size_t)l * outZ;
    __shared__ float tile[32][33];
    const int tx = threadIdx.x & 31, ty = threadIdx.x >> 5;
    const int r0 = blockIdx.y * 32, c0 = blockIdx.x * 32;
#pragma unroll
    for (int i = 0; i < 4; ++i)
        tile[ty + i * 8][tx] = in[(size_t)(r0 + ty + i * 8) * 512 + c0 + tx];
    __syncthreads();
#pragma unroll
    for (int i = 0; i < 4; ++i)
        out[(size_t)(c0 + ty + i * 8) * 512 + r0 + tx] = (half_t)(tile[tx][ty + i * 8] * sc);
}

__global__ __launch_bounds__(256)
void transpose_cast(const float* __restrict__ in, half_t* __restrict__ out,
                    int R, int C, float scale, int inZ, int outZ)
{
    in  += (size_t)blockIdx.z * inZ;
    out += (size_t)blockIdx.z * outZ;
    __shared__ float tile[32][33];
    const int tx = threadIdx.x & 31, ty = threadIdx.x >> 5;
    const int r0 = blockIdx.y * 32, c0 = blockIdx.x * 32;
#pragma unroll
    for (int i = 0; i < 4; ++i)
        tile[ty + i * 8][tx] = in[(size_t)(r0 + ty + i * 8) * C + c0 + tx];
    __syncthreads();
#pragma unroll
    for (int i = 0; i < 4; ++i)
        out[(size_t)(c0 + ty + i * 8) * R + r0 + tx] = (half_t)(tile[tx][ty + i * 8] * scale);
}

__global__ __launch_bounds__(256)
void pack_masks(const float* __restrict__ cm, const int* __restrict__ ids,
                u32* __restrict__ crossb, u32* __restrict__ selfb)
{
    const int t = blockIdx.x;
    const float* row = cm + (size_t)t * S_DIM;
    __shared__ u32 cb[S_DIM / 32];
    __shared__ u16 sh16[256];
    const int tid = threadIdx.x;
    u32 bits = 0;
#pragma unroll
    for (int q = 0; q < 4; ++q) {
        float4 v = *(const float4*)&row[tid * 16 + q * 4];
        bits |= (v.x > 0.5f ? 1u : 0u) << (q * 4 + 0);
        bits |= (v.y > 0.5f ? 1u : 0u) << (q * 4 + 1);
        bits |= (v.z > 0.5f ? 1u : 0u) << (q * 4 + 2);
        bits |= (v.w > 0.5f ? 1u : 0u) << (q * 4 + 3);
    }
    ((u16*)cb)[tid] = (u16)bits;
    __syncthreads();
    u32 sb = 0;
#pragma unroll
    for (int q = 0; q < 4; ++q) {
        int4 id4 = *(const int4*)&ids[tid * 16 + q * 4];
        sb |= ((cb[id4.x >> 5] >> (id4.x & 31)) & 1u) << (q * 4 + 0);
        sb |= ((cb[id4.y >> 5] >> (id4.y & 31)) & 1u) << (q * 4 + 1);
        sb |= ((cb[id4.z >> 5] >> (id4.z & 31)) & 1u) << (q * 4 + 2);
        sb |= ((cb[id4.w >> 5] >> (id4.w & 31)) & 1u) << (q * 4 + 3);
    }
    sh16[tid] = (u16)sb;
    __syncthreads();
    if (tid < 128) {
        crossb[(size_t)t * 128 + tid] = cb[tid];
        selfb[(size_t)t * 128 + tid]  = (u32)sh16[2 * tid] | ((u32)sh16[2 * tid + 1] << 16);
    }
}

// ---------------------------------------------------------------------------
extern "C" void kernel_launch(void* const* d_in, const int* in_sizes, int n_in,
                              void* d_out, int out_size, void* d_ws, size_t ws_size,
                              hipStream_t stream)
{
    (void)in_sizes; (void)n_in; (void)out_size; (void)ws_size;

    const float* x0p  = (const float*)d_in[0];
    const float* encp = (const float*)d_in[1];
    const float* cmp  = (const float*)d_in[2];
    const float* Wq = (const float*)d_in[3], *Wk = (const float*)d_in[4];
    const float* Wv = (const float*)d_in[5], *Wo = (const float*)d_in[6];
    const float* Cq = (const float*)d_in[7], *Ck = (const float*)d_in[8];
    const float* Cv = (const float*)d_in[9], *Co = (const float*)d_in[10];
    const float* W1p = (const float*)d_in[11];
    const float* W2p = (const float*)d_in[12];
    const float* alphap = (const float*)d_in[13];
    const float* gammap = (const float*)d_in[14];
    const int*   idsp   = (const int*)d_in[15];
    float* outp = (float*)d_out;

    char* wp = (char*)d_ws;
    auto take = [&](size_t nelem, int esz) -> void* {
        void* p = (void*)wp;
        wp += (nelem * (size_t)esz + 255) & ~(size_t)255;
        return p;
    };
    half_t* wqkvT = (half_t*)take((size_t)NLAYER * 1536 * 512, 2);
    half_t* ckvT  = (half_t*)take((size_t)NLAYER * 1024 * 512, 2);
    half_t* cqT   = (half_t*)take((size_t)NLAYER * 512 * 512, 2);
    half_t* woT   = (half_t*)take((size_t)NLAYER * 512 * 512, 2);
    half_t* coT   = (half_t*)take((size_t)NLAYER * 512 * 512, 2);
    half_t* w1T   = (half_t*)take((size_t)NLAYER * D_DIM * F_DIM, 2);
    half_t* w2T   = (half_t*)take((size_t)NLAYER * D_DIM * F_DIM, 2);
    half_t* hh    = (half_t*)take((size_t)T_DIM * D_DIM, 2);
    half_t* qb    = (half_t*)take((size_t)T_DIM * D_DIM, 2);
    half_t* kb    = (half_t*)take((size_t)S_DIM * D_DIM, 2);
    half_t* vb    = (half_t*)take((size_t)S_DIM * D_DIM, 2);
    half_t* vTp   = (half_t*)take((size_t)S_DIM * D_DIM, 2);
    half_t* mid   = (half_t*)take((size_t)T_DIM * F_DIM, 2);
    half_t* enc16 = (half_t*)take((size_t)S_DIM * D_DIM, 2);
    half_t* kbC   = (half_t*)take((size_t)NLAYER * S_DIM * D_DIM, 2);
    half_t* vC    = (half_t*)take((size_t)NLAYER * S_DIM * D_DIM, 2);
    half_t* vTCp  = (half_t*)take((size_t)NLAYER * S_DIM * D_DIM, 2);
    float* xbuf   = (float*)take((size_t)T_DIM * D_DIM, 4);
    half_t* logit16 = (half_t*)take((size_t)T_DIM * S_DIM, 2);
    half_t* p16   = (half_t*)take((size_t)T_DIM * 2048, 2);
    float* pbuf   = (float*)take((size_t)T_DIM * 2048, 4);
    float2* rowstat = (float2*)take((size_t)T_DIM, 8);
    u32* crossb = (u32*)take((size_t)T_DIM * (S_DIM / 32), 4);
    u32* selfb  = (u32*)take((size_t)T_DIM * (S_DIM / 32), 4);

    const dim3 B(256), B512(512);
    const float qscale = 0.04419417382415922f; // 1/sqrt(512), folded into Wq/Cq

    // ---- one-time prep ----
    const int SQ = 512 * 512, FZ = 512 * 2048;
    transpose_cast8<<<dim3(16, 16, 32), B, 0, stream>>>(
        Wq, Wk, Wv, Wo, Cq, Ck, Cv, Co,
        wqkvT, wqkvT + SQ, wqkvT + 2 * SQ, woT, cqT, ckvT, ckvT + SQ, coT, qscale);
    transpose_cast<<<dim3(64,16,4), B, 0, stream>>>(W1p, w1T, 512, 2048, 1.f, FZ, FZ);
    transpose_cast<<<dim3(16,64,4), B, 0, stream>>>(W2p, w2T, 2048, 512, 1.f, FZ, FZ);
    cast_f16<<<dim3((S_DIM * D_DIM / 8) / 256), B, 0, stream>>>(encp, enc16);
    pack_masks<<<dim3(T_DIM), B, 0, stream>>>(cmp, idsp, crossb, selfb);
    gemm_nt<64, 7><<<dim3(2048), B512, 0, stream>>>(enc16, 512, ckvT, 512,
        4096, 512, 64, nullptr, kbC, vC, 0);
    gemm_fold<<<dim3(256, 1, NLAYER), B512, 0, stream>>>(coT, vC, vTCp,
        SQ, (long)KVS, (long)KVS);

    for (int l = 0; l < NLAYER; ++l) {
        // ---- head: residual fold of prev W2 + norm ----
        if (l == 0)
            norm_rows<0><<<T_DIM / 4, B, 0, stream>>>(x0p, hh, nullptr, nullptr, nullptr);
        else
            norm_red<0><<<T_DIM / 4, B, 0, stream>>>(xbuf, pbuf, xbuf, hh, nullptr, nullptr, nullptr);

        // ---- self attention ----
        gemm_nt<64, 5><<<dim3(768), B512, 0, stream>>>(hh, 512, wqkvT + (size_t)l * 1536 * 512, 512,
            1536, 512, 24, qb, kb, vb, 0);
        gemm_fold<<<dim3(256, 1, 1), B512, 0, stream>>>(woT + (size_t)l * SQ, vb, vTp, 0, 0, 0);
        gemm_logits<<<dim3(1024), B, 0, stream>>>(qb, kb, selfb, logit16);
        row_stats<<<dim3(T_DIM), B, 0, stream>>>(logit16, rowstat);
        gemm_pv<<<dim3(512), B, 0, stream>>>(logit16, vTp, rowstat, p16);
        attn_tail<<<dim3(T_DIM / 4), B, 0, stream>>>((l == 0) ? x0p : xbuf, p16, xbuf, hh);

        // ---- cross attention ----
        gemm_nt<64, 2><<<dim3(256), B512, 0, stream>>>(hh, 512, cqT + (size_t)l * SQ, 512,
            512, 512, 8, qb, nullptr, nullptr, 512);
        gemm_logits<<<dim3(1024), B, 0, stream>>>(qb, kbC + (size_t)l * KVS, crossb, logit16);
        row_stats<<<dim3(T_DIM), B, 0, stream>>>(logit16, rowstat);
        gemm_pv<<<dim3(512), B, 0, stream>>>(logit16, vTCp + (size_t)l * KVS, rowstat, p16);
        attn_tail<<<dim3(T_DIM / 4), B, 0, stream>>>(xbuf, p16, xbuf, hh);

        // ---- FFN ----
        gemm97<4><<<dim3(512), B, 0, stream>>>(hh, 512, w1T + (size_t)l * FZ, 512,
            512, 16, mid, nullptr, 2048);
        gemm97<0, 4, 0><<<dim3(512), B, 0, stream>>>(mid, 2048, w2T + (size_t)l * FZ, 2048,
            2048, 4, nullptr, pbuf, 2048);
    }

    norm_red<1><<<T_DIM / 4, B, 0, stream>>>(xbuf, pbuf, xbuf, nullptr, outp, alphap, gammap);
}

// Round 15
// 1195.152 us; speedup vs baseline: 1.0271x; 1.0193x over previous
//
#include <hip/hip_runtime.h>
#include <math.h>

typedef _Float16 half_t;
typedef unsigned int u32;
typedef unsigned short u16;
typedef float f32x4 __attribute__((ext_vector_type(4)));
typedef _Float16 f16x8 __attribute__((ext_vector_type(8)));
typedef _Float16 f16x4 __attribute__((ext_vector_type(4)));

#define T_DIM 4096
#define S_DIM 4096
#define D_DIM 512
#define F_DIM 2048
#define NLAYER 4
#define KVS ((size_t)4096 * 512)

__device__ __forceinline__ void gload16(const void* g, void* l) {
    __builtin_amdgcn_global_load_lds(
        (const __attribute__((address_space(1))) u32*)g,
        (__attribute__((address_space(3))) u32*)l, 16, 0, 0);
}

template<int N> __device__ __forceinline__ void wait_vm() {
    if constexpr (N == 0) asm volatile("s_waitcnt vmcnt(0)" ::: "memory");
    else if constexpr (N == 3) asm volatile("s_waitcnt vmcnt(3)" ::: "memory");
    else if constexpr (N == 4) asm volatile("s_waitcnt vmcnt(4)" ::: "memory");
    else if constexpr (N == 6) asm volatile("s_waitcnt vmcnt(6)" ::: "memory");
    else if constexpr (N == 8) asm volatile("s_waitcnt vmcnt(8)" ::: "memory");
}
__device__ __forceinline__ void wait_lgkm0() {
    asm volatile("s_waitcnt lgkmcnt(0)" ::: "memory");
}

// ---------------------------------------------------------------------------
// Workhorse: 512 thr, BM=128, BK=64, wave tile 32xBN/2.
// EPI: 2 fp16 [M,N] (ldd) | 5 QKV split row-major | 7 batched cross-KV.
// ---------------------------------------------------------------------------
template<int BN, int EPI>
__global__ __launch_bounds__(512)
void gemm_nt(const half_t* __restrict__ A, int lda,
             const half_t* __restrict__ B, int ldb,
             int N, int K, int gx,
             half_t* __restrict__ D1, half_t* __restrict__ D2,
             half_t* __restrict__ D3, int ldd)
{
    constexpr int BM = 128, BK = 64;
    constexpr int NF = BN / 32;
    constexpr int LPT = 2 + BN / 64;
    constexpr int NSLOT = (BN == 64) ? 3 : 2;
    __shared__ half_t As[NSLOT][BM * BK];
    __shared__ half_t Bs[NSLOT][BN * BK];

    const int tid  = threadIdx.x;
    const int wave = tid >> 6;
    const int lane = tid & 63;

    const int nb  = gridDim.x;
    const int bid = blockIdx.x;
    const int nid = (bid & 7) * (nb >> 3) + (bid >> 3);
    const int bx  = nid % gx;
    const int by  = nid / gx;
    const int bm = by * BM, bn = bx * BN;

    const int wm = (wave >> 1) * 32;
    const int wn = (wave & 1) * (BN / 2);
    const int kq = lane >> 4;
    const int rr = lane & 15;
    const int scol = (((lane & 7) ^ (lane >> 3)) << 3);

    f32x4 acc[2][NF];
#pragma unroll
    for (int m = 0; m < 2; ++m)
#pragma unroll
        for (int n = 0; n < NF; ++n)
            acc[m][n] = f32x4{0.f, 0.f, 0.f, 0.f};

    auto stage = [&](int buf, int k0) {
#pragma unroll
        for (int c = 0; c < 2; ++c) {
            const int row = wave * 16 + c * 8 + (lane >> 3);
            gload16(A + (size_t)(bm + row) * lda + k0 + scol,
                    (char*)&As[buf][0] + (wave * 2 + c) * 1024 + lane * 16);
        }
        if constexpr (BN == 64) {
            const int row = wave * 8 + (lane >> 3);
            gload16(B + (size_t)(bn + row) * ldb + k0 + scol,
                    (char*)&Bs[buf][0] + wave * 1024 + lane * 16);
        } else {
#pragma unroll
            for (int c = 0; c < 2; ++c) {
                const int row = wave * 16 + c * 8 + (lane >> 3);
                gload16(B + (size_t)(bn + row) * ldb + k0 + scol,
                        (char*)&Bs[buf][0] + (wave * 2 + c) * 1024 + lane * 16);
            }
        }
    };

    const int nt = K / BK;
    stage(0, 0);
    if constexpr (NSLOT == 3) stage(1, BK);
    int cur = 0, pf = NSLOT - 1;
    for (int t = 0; t < nt; ++t) {
        if (t + 1 < nt) wait_vm<(NSLOT - 2) * LPT>(); else wait_vm<0>();
        __builtin_amdgcn_s_barrier();
        if (t + NSLOT - 1 < nt) stage(pf, (t + NSLOT - 1) * BK);
#pragma unroll
        for (int ks = 0; ks < 2; ++ks) {
            f16x8 af[2], bf[NF];
#pragma unroll
            for (int m = 0; m < 2; ++m) {
                const int r = wm + m * 16 + rr;
                af[m] = *(const f16x8*)&As[cur][r * BK + (((ks * 4 + kq) ^ (r & 7)) << 3)];
            }
#pragma unroll
            for (int n = 0; n < NF; ++n) {
                const int r = wn + n * 16 + rr;
                bf[n] = *(const f16x8*)&Bs[cur][r * BK + (((ks * 4 + kq) ^ (r & 7)) << 3)];
            }
#pragma unroll
            for (int m = 0; m < 2; ++m)
#pragma unroll
                for (int n = 0; n < NF; ++n)
                    acc[m][n] = __builtin_amdgcn_mfma_f32_16x16x32_f16(af[m], bf[n], acc[m][n], 0, 0, 0);
        }
        cur = (cur + 1 == NSLOT) ? 0 : cur + 1;
        pf  = (pf  + 1 == NSLOT) ? 0 : pf  + 1;
    }

    const int r0 = bm + wm + (lane >> 4) * 4;
#pragma unroll
    for (int m = 0; m < 2; ++m)
#pragma unroll
        for (int n = 0; n < NF; ++n) {
            const int c = bn + wn + n * 16 + rr;
            if (EPI == 2) {
#pragma unroll
                for (int i = 0; i < 4; ++i)
                    D1[(size_t)(r0 + m * 16 + i) * ldd + c] = (half_t)acc[m][n][i];
            } else if (EPI == 5) {
                half_t* Dst = (bn < 512) ? D1 : (bn < 1024) ? D2 : D3;
                const int sub = c & 511;
#pragma unroll
                for (int i = 0; i < 4; ++i)
                    Dst[(size_t)(r0 + m * 16 + i) * 512 + sub] = (half_t)acc[m][n][i];
            } else { // EPI == 7 batched cross-KV (row-major K and v)
                const int l = c >> 10;
                const int sub = c & 1023;
                half_t* Dst = (sub < 512) ? (D2 + l * KVS) : (D3 + l * KVS);
                const int d = sub & 511;
#pragma unroll
                for (int i = 0; i < 4; ++i)
                    Dst[(size_t)(r0 + m * 16 + i) * 512 + d] = (half_t)acc[m][n][i];
            }
        }
}

// ---------------------------------------------------------------------------
// V-fold GEMM (z-batched): Out[z][d',s] = sum_d Wt[z][d',d] * V[z][s,d].
// ---------------------------------------------------------------------------
__global__ __launch_bounds__(512)
void gemm_fold(const half_t* __restrict__ Wt, const half_t* __restrict__ V,
               half_t* __restrict__ Out, int zSA, long zSB, long zSD)
{
    constexpr int BM = 128, BK = 64, BN = 64, NSLOT = 3, LPT = 3;
    __shared__ half_t As[NSLOT][BM * BK];
    __shared__ half_t Bs[NSLOT][BN * BK];

    const half_t* A = Wt + (size_t)blockIdx.z * zSA;
    const half_t* B = V  + (size_t)blockIdx.z * zSB;
    half_t* D = Out + (size_t)blockIdx.z * zSD;

    const int tid  = threadIdx.x;
    const int wave = tid >> 6;
    const int lane = tid & 63;

    const int nb  = gridDim.x;   // 256
    const int bid = blockIdx.x;
    const int nid = (bid & 7) * (nb >> 3) + (bid >> 3);
    const int bx = nid & 63, by = nid >> 6;
    const int bm = by * BM, bn = bx * BN;

    const int wm = (wave >> 1) * 32;
    const int wn = (wave & 1) * 32;
    const int kq = lane >> 4;
    const int rr = lane & 15;
    const int scol = (((lane & 7) ^ (lane >> 3)) << 3);

    f32x4 acc[2][2];
#pragma unroll
    for (int m = 0; m < 2; ++m)
#pragma unroll
        for (int n = 0; n < 2; ++n)
            acc[m][n] = f32x4{0.f, 0.f, 0.f, 0.f};

    auto stage = [&](int buf, int k0) {
#pragma unroll
        for (int c = 0; c < 2; ++c) {
            const int row = wave * 16 + c * 8 + (lane >> 3);
            gload16(A + (size_t)(bm + row) * 512 + k0 + scol,
                    (char*)&As[buf][0] + (wave * 2 + c) * 1024 + lane * 16);
        }
        const int row = wave * 8 + (lane >> 3);
        gload16(B + (size_t)(bn + row) * 512 + k0 + scol,
                (char*)&Bs[buf][0] + wave * 1024 + lane * 16);
    };

    const int nt = 512 / BK;   // 8
    stage(0, 0);
    stage(1, BK);
    int cur = 0, pf = 2;
    for (int t = 0; t < nt; ++t) {
        if (t + 1 < nt) wait_vm<LPT>(); else wait_vm<0>();
        __builtin_amdgcn_s_barrier();
        if (t + 2 < nt) stage(pf, (t + 2) * BK);
#pragma unroll
        for (int ks = 0; ks < 2; ++ks) {
            f16x8 af[2], bf[2];
#pragma unroll
            for (int m = 0; m < 2; ++m) {
                const int r = wm + m * 16 + rr;
                af[m] = *(const f16x8*)&As[cur][r * BK + (((ks * 4 + kq) ^ (r & 7)) << 3)];
            }
#pragma unroll
            for (int n = 0; n < 2; ++n) {
                const int r = wn + n * 16 + rr;
                bf[n] = *(const f16x8*)&Bs[cur][r * BK + (((ks * 4 + kq) ^ (r & 7)) << 3)];
            }
#pragma unroll
            for (int m = 0; m < 2; ++m)
#pragma unroll
                for (int n = 0; n < 2; ++n)
                    acc[m][n] = __builtin_amdgcn_mfma_f32_16x16x32_f16(af[m], bf[n], acc[m][n], 0, 0, 0);
        }
        cur = (cur + 1 == NSLOT) ? 0 : cur + 1;
        pf  = (pf  + 1 == NSLOT) ? 0 : pf  + 1;
    }

    const int r0 = bm + wm + (lane >> 4) * 4;
#pragma unroll
    for (int m = 0; m < 2; ++m)
#pragma unroll
        for (int n = 0; n < 2; ++n) {
            const int c = bn + wn + n * 16 + rr;
#pragma unroll
            for (int i = 0; i < 4; ++i)
                D[(size_t)(r0 + m * 16 + i) * 4096 + c] = (half_t)acc[m][n][i];
        }
}

// ---------------------------------------------------------------------------
// m97 geometry: W1 (EPI 4), W2 split-K fp32, and UNMASKED logits (EPI 2,
// the round-8 known-good path: VGPR 68, ~22us at grid 1024).
// ---------------------------------------------------------------------------
template<int EPI, int SPLITK = 1, int P16 = 1>
__global__ __launch_bounds__(256)
void gemm97(const half_t* __restrict__ A, int lda,
            const half_t* __restrict__ B, int ldb,
            int K, int gx, half_t* __restrict__ D,
            float* __restrict__ Fout, int ldd)
{
    constexpr int BK = 32, NSLOT = 3, LPT = 4;
    __shared__ half_t As[NSLOT][128 * BK];
    __shared__ half_t Bs[NSLOT][128 * BK];

    const int tid  = threadIdx.x;
    const int wave = tid >> 6;
    const int lane = tid & 63;

    const int nb  = gridDim.x;
    const int bid = blockIdx.x;
    const int nid = (bid & 7) * (nb >> 3) + (bid >> 3);
    const int gy  = nb / (gx * SPLITK);
    const int bx  = nid % gx;
    const int tmp = nid / gx;
    const int by  = tmp % gy;
    const int kz  = tmp / gy;
    const int bm = by * 128, bn = bx * 128;

    const int Keff = K / SPLITK;
    A += (size_t)kz * Keff;
    B += (size_t)kz * Keff;

    const int wm = (wave >> 1) * 64;
    const int wn = (wave & 1) * 64;
    const int kq = lane >> 4;
    const int rr = lane & 15;
    const int srow = lane >> 2;
    const int scol = (((lane & 3) ^ ((lane >> 3) & 3)) << 3);
    const int kqa  = kq ^ ((rr >> 1) & 3);

    const half_t* Abase = A + (size_t)(bm + wave * 16 + srow) * lda + scol;
    const half_t* Bbase = B + (size_t)(bn + wave * 16 + srow) * ldb + scol;

    f32x4 acc[4][4];
#pragma unroll
    for (int m = 0; m < 4; ++m)
#pragma unroll
        for (int n = 0; n < 4; ++n)
            acc[m][n] = f32x4{0.f, 0.f, 0.f, 0.f};

    auto stage = [&](int buf, int k0) {
#pragma unroll
        for (int c = 0; c < 2; ++c)
            gload16(Abase + (size_t)c * 64 * lda + k0,
                    (char*)&As[buf][0] + c * 4096 + wave * 1024 + lane * 16);
#pragma unroll
        for (int c = 0; c < 2; ++c)
            gload16(Bbase + (size_t)c * 64 * ldb + k0,
                    (char*)&Bs[buf][0] + c * 4096 + wave * 1024 + lane * 16);
    };

    const int nt = Keff / BK;
    stage(0, 0);
    stage(1, BK);
    int cur = 0, pf = 2;
    for (int t = 0; t < nt; ++t) {
        if (t + 1 < nt) wait_vm<LPT>(); else wait_vm<0>();
        __builtin_amdgcn_s_barrier();
        if (t + 2 < nt) stage(pf, (t + 2) * BK);
        f16x8 af[4], bf[4];
#pragma unroll
        for (int m = 0; m < 4; ++m)
            af[m] = *(const f16x8*)&As[cur][(wm + m * 16 + rr) * BK + kqa * 8];
#pragma unroll
        for (int n = 0; n < 4; ++n)
            bf[n] = *(const f16x8*)&Bs[cur][(wn + n * 16 + rr) * BK + kqa * 8];
#pragma unroll
        for (int m = 0; m < 4; ++m)
#pragma unroll
            for (int n = 0; n < 4; ++n)
                acc[m][n] = __builtin_amdgcn_mfma_f32_16x16x32_f16(af[m], bf[n], acc[m][n], 0, 0, 0);
        cur = (cur == 2) ? 0 : cur + 1;
        pf  = (pf  == 2) ? 0 : pf + 1;
    }

    const int r0 = bm + wm + (lane >> 4) * 4;
    const int soff = kz * gx * 128;
#pragma unroll
    for (int m = 0; m < 4; ++m)
#pragma unroll
        for (int n = 0; n < 4; ++n) {
            const int c = bn + wn + n * 16 + rr;
#pragma unroll
            for (int i = 0; i < 4; ++i) {
                float v = acc[m][n][i];
                const size_t r = r0 + m * 16 + i;
                if constexpr (SPLITK > 1) {
                    if constexpr (P16) D[r * ldd + soff + c] = (half_t)v;
                    else               Fout[r * ldd + soff + c] = v;
                } else {
                    if (EPI == 4) v = fmaxf(v, 0.f);
                    D[r * ldd + c] = (half_t)v;
                }
            }
        }
}

// ---------------------------------------------------------------------------
// row_stats: per-row {M, 1/S} from RAW fp16 z + mask bits (memory-bound;
// mask applied here for free). One block per row.
// ---------------------------------------------------------------------------
__global__ __launch_bounds__(256)
void row_stats(const half_t* __restrict__ logits, const u32* __restrict__ bits,
               float2* __restrict__ rowstat)
{
    const int t = blockIdx.x;
    const half_t* row = logits + (size_t)t * S_DIM;
    const u32* bw = bits + (size_t)t * (S_DIM / 32);
    __shared__ float red[8];
    const int tid = threadIdx.x, wave = tid >> 6, lane = tid & 63;
    const int s0 = tid * 16;
    f16x8 h0 = *(const f16x8*)&row[s0];
    f16x8 h1 = *(const f16x8*)&row[s0 + 8];
    const u32 w = bw[tid >> 1] >> ((tid & 1) * 16);   // 16 mask bits
    float z[16];
    float lmax = -3.0e38f;
#pragma unroll
    for (int q = 0; q < 16; ++q) {
        const float v = (float)((q < 8) ? h0[q & 7] : h1[q & 7]);
        z[q] = ((w >> q) & 1u) ? v : -1e9f;
        lmax = fmaxf(lmax, z[q]);
    }
#pragma unroll
    for (int off = 32; off; off >>= 1) lmax = fmaxf(lmax, __shfl_xor(lmax, off));
    if (lane == 0) red[wave] = lmax;
    __syncthreads();
    const float mx = fmaxf(fmaxf(red[0], red[1]), fmaxf(red[2], red[3]));
    float lsum = 0.f;
#pragma unroll
    for (int q = 0; q < 16; ++q)
        lsum += (z[q] > -1e8f) ? __expf(z[q] - mx) : 0.f;
#pragma unroll
    for (int off = 32; off; off >>= 1) lsum += __shfl_xor(lsum, off);
    if (lane == 0) red[4 + wave] = lsum;
    __syncthreads();
    if (tid == 0)
        rowstat[t] = float2{mx, 1.f / (red[4] + red[5] + red[6] + red[7])};
}

// ---------------------------------------------------------------------------
// PV GEMM, on-the-fly P = bit ? exp(z - M)*inv : 0 from RAW z.
// loadA also fetches 2 mask words -> 6 vm ops per stage group (wait_vm<6>).
// ---------------------------------------------------------------------------
__global__ __launch_bounds__(256)
void gemm_pv(const half_t* __restrict__ A, const half_t* __restrict__ B,
             const u32* __restrict__ bits, const float2* __restrict__ rowstat,
             half_t* __restrict__ D)
{
    constexpr int BK = 32, NSLOT = 3, Keff = 1024, nt = 32;
    __shared__ half_t As[NSLOT][128 * BK];
    __shared__ half_t Bs[NSLOT][128 * BK];

    const int tid = threadIdx.x, wave = tid >> 6, lane = tid & 63;
    const int nb = gridDim.x, bid = blockIdx.x;
    const int nid = (bid & 7) * (nb >> 3) + (bid >> 3);
    const int bx = nid & 3;
    const int tmp = nid >> 2;
    const int by = tmp & 31, kz = tmp >> 5;
    const int bm = by * 128, bn = bx * 128;

    const int wm = (wave >> 1) * 64, wn = (wave & 1) * 64;
    const int kq = lane >> 4, rr = lane & 15, srow = lane >> 2;
    const int scol = (((lane & 3) ^ ((lane >> 3) & 3)) << 3);
    const int kqa = kq ^ ((rr >> 1) & 3);

    const int arow = bm + wave * 16 + srow;
    const half_t* Abase = A + (size_t)arow * 4096 + kz * Keff + scol;
    const half_t* Bbase = B + (size_t)(bn + wave * 16 + srow) * 4096 + kz * Keff + scol;
    const u32* Wbase0 = bits + (size_t)arow * 128 + (kz * Keff >> 5);
    const u32* Wbase1 = bits + (size_t)(arow + 64) * 128 + (kz * Keff >> 5);

    const float2 rs0 = rowstat[arow];
    const float2 rs1 = rowstat[arow + 64];
    asm volatile("s_waitcnt vmcnt(0)" ::: "memory");
    const float M0 = rs0.x, I0 = rs0.y, M1 = rs1.x, I1 = rs1.y;

    f32x4 acc[4][4];
#pragma unroll
    for (int m = 0; m < 4; ++m)
#pragma unroll
        for (int n = 0; n < 4; ++n)
            acc[m][n] = f32x4{0.f, 0.f, 0.f, 0.f};

    auto loadA = [&](int k0, f16x8& a0, f16x8& a1, u32& w0, u32& w1) {
        a0 = *(const f16x8*)(Abase + k0);
        a1 = *(const f16x8*)(Abase + (size_t)64 * 4096 + k0);
        w0 = Wbase0[k0 >> 5];
        w1 = Wbase1[k0 >> 5];
    };
    auto gloadB = [&](int buf, int k0) {
        gload16(Bbase + k0, (char*)&Bs[buf][0] + wave * 1024 + lane * 16);
        gload16(Bbase + (size_t)64 * 4096 + k0,
                (char*)&Bs[buf][0] + 4096 + wave * 1024 + lane * 16);
    };
    auto writeA = [&](int buf, const f16x8& a0, const f16x8& a1, u32 w0, u32 w1) {
        f16x8 p0, p1;
#pragma unroll
        for (int e = 0; e < 8; ++e) {
            const float e0 = __expf((float)a0[e] - M0) * I0;
            const float e1 = __expf((float)a1[e] - M1) * I1;
            p0[e] = (half_t)(((w0 >> (scol + e)) & 1u) ? e0 : 0.f);
            p1[e] = (half_t)(((w1 >> (scol + e)) & 1u) ? e1 : 0.f);
        }
        *(f16x8*)((char*)&As[buf][0] + wave * 1024 + lane * 16) = p0;
        *(f16x8*)((char*)&As[buf][0] + 4096 + wave * 1024 + lane * 16) = p1;
    };
    auto compute = [&](int s) {
        f16x8 af[4], bf[4];
#pragma unroll
        for (int m = 0; m < 4; ++m)
            af[m] = *(const f16x8*)&As[s][(wm + m * 16 + rr) * BK + kqa * 8];
#pragma unroll
        for (int n = 0; n < 4; ++n)
            bf[n] = *(const f16x8*)&Bs[s][(wn + n * 16 + rr) * BK + kqa * 8];
#pragma unroll
        for (int m = 0; m < 4; ++m)
#pragma unroll
            for (int n = 0; n < 4; ++n)
                acc[m][n] = __builtin_amdgcn_mfma_f32_16x16x32_f16(af[m], bf[n], acc[m][n], 0, 0, 0);
    };

    f16x8 a0A, a1A, a0B, a1B;
    u32 w0A, w1A, w0B, w1B;
    loadA(0, a0A, a1A, w0A, w1A);  gloadB(0, 0);
    loadA(BK, a0B, a1B, w0B, w1B); gloadB(1, BK);
    wait_vm<6>();
    writeA(0, a0A, a1A, w0A, w1A);
    wait_lgkm0();
    __builtin_amdgcn_s_barrier();

    int cur = 0, pf = 2;
    for (int t = 0; t < nt; t += 2) {
        {
            const bool hasPF = (t + 2 < nt);
            if (hasPF) { loadA((t + 2) * BK, a0A, a1A, w0A, w1A); gloadB(pf, (t + 2) * BK); }
            compute(cur);
            if (t + 1 < nt) {
                if (hasPF) wait_vm<6>(); else wait_vm<0>();
                writeA((cur + 1 == NSLOT) ? 0 : cur + 1, a0B, a1B, w0B, w1B);
                wait_lgkm0();
            }
            __builtin_amdgcn_s_barrier();
            cur = (cur + 1 == NSLOT) ? 0 : cur + 1;
            pf  = (pf  + 1 == NSLOT) ? 0 : pf + 1;
        }
        {
            const int u = t + 1;
            const bool hasPF = (u + 2 < nt);
            if (hasPF) { loadA((u + 2) * BK, a0B, a1B, w0B, w1B); gloadB(pf, (u + 2) * BK); }
            compute(cur);
            if (u + 1 < nt) {
                if (hasPF) wait_vm<6>(); else wait_vm<0>();
                writeA((cur + 1 == NSLOT) ? 0 : cur + 1, a0A, a1A, w0A, w1A);
                wait_lgkm0();
            }
            __builtin_amdgcn_s_barrier();
            cur = (cur + 1 == NSLOT) ? 0 : cur + 1;
            pf  = (pf  + 1 == NSLOT) ? 0 : pf + 1;
        }
    }

    const int r0 = bm + wm + (lane >> 4) * 4;
    const int soff = kz * 512;
#pragma unroll
    for (int m = 0; m < 4; ++m)
#pragma unroll
        for (int n = 0; n < 4; ++n) {
            const int c = bn + wn + n * 16 + rr;
#pragma unroll
            for (int i = 0; i < 4; ++i)
                D[(size_t)(r0 + m * 16 + i) * 2048 + soff + c] = (half_t)acc[m][n][i];
        }
}

// ---------------------------------------------------------------------------
// attn_tail: xbuf = xin + sum of 4 fp16 PV slices; hh = LayerNorm(xbuf).
// ---------------------------------------------------------------------------
__global__ __launch_bounds__(256)
void attn_tail(const float* __restrict__ xin, const half_t* __restrict__ P,
               float* __restrict__ xbuf, half_t* __restrict__ hh)
{
    const int row  = blockIdx.x * 4 + (threadIdx.x >> 6);
    const int lane = threadIdx.x & 63;
    const int d0 = lane * 8;
    float v[8];
    {
        const float* xr = xin + (size_t)row * D_DIM + d0;
        float4 a = *(const float4*)xr;
        float4 b = *(const float4*)(xr + 4);
        v[0]=a.x; v[1]=a.y; v[2]=a.z; v[3]=a.w; v[4]=b.x; v[5]=b.y; v[6]=b.z; v[7]=b.w;
    }
    const half_t* pr = P + (size_t)row * 2048 + d0;
#pragma unroll
    for (int j = 0; j < 4; ++j) {
        f16x8 pv = *(const f16x8*)(pr + j * 512);
#pragma unroll
        for (int e = 0; e < 8; ++e) v[e] += (float)pv[e];
    }
    float* xo = xbuf + (size_t)row * D_DIM + d0;
    *(float4*)xo       = float4{v[0], v[1], v[2], v[3]};
    *(float4*)(xo + 4) = float4{v[4], v[5], v[6], v[7]};

    float s = 0.f;
#pragma unroll
    for (int j = 0; j < 8; ++j) s += v[j];
#pragma unroll
    for (int off = 32; off; off >>= 1) s += __shfl_xor(s, off);
    const float mean = s * (1.f / 512.f);
    float ss = 0.f;
#pragma unroll
    for (int j = 0; j < 8; ++j) { float d = v[j] - mean; ss += d * d; }
#pragma unroll
    for (int off = 32; off; off >>= 1) ss += __shfl_xor(ss, off);
    const float inv = 1.f / (sqrtf(ss * (1.f / 511.f)) + 1e-6f);
    f16x8 hv;
#pragma unroll
    for (int j = 0; j < 8; ++j) hv[j] = (half_t)((v[j] - mean) * inv);
    *(f16x8*)&hh[(size_t)row * D_DIM + d0] = hv;
}

// ---------------------------------------------------------------------------
// norm_red: x = xin + sum of 4 fp32 W2 partial slices [4096][2048].
// ---------------------------------------------------------------------------
template<int FINAL>
__global__ __launch_bounds__(256)
void norm_red(const float* __restrict__ xin, const float* __restrict__ P,
              float* __restrict__ xbuf, half_t* __restrict__ hh,
              float* __restrict__ outF, const float* __restrict__ alphaP,
              const float* __restrict__ gammaP)
{
    const int row  = blockIdx.x * 4 + (threadIdx.x >> 6);
    const int lane = threadIdx.x & 63;
    const int d0 = lane * 8;
    const float* xr = xin + (size_t)row * D_DIM + d0;
    float v[8];
    {
        float4 a = *(const float4*)xr;
        float4 b = *(const float4*)(xr + 4);
        v[0]=a.x; v[1]=a.y; v[2]=a.z; v[3]=a.w; v[4]=b.x; v[5]=b.y; v[6]=b.z; v[7]=b.w;
    }
    const float* pr = P + (size_t)row * 2048 + d0;
#pragma unroll
    for (int j = 0; j < 4; ++j) {
        float4 a = *(const float4*)(pr + j * 512);
        float4 b = *(const float4*)(pr + j * 512 + 4);
        v[0]+=a.x; v[1]+=a.y; v[2]+=a.z; v[3]+=a.w; v[4]+=b.x; v[5]+=b.y; v[6]+=b.z; v[7]+=b.w;
    }
    if (!FINAL) {
        float* xo = xbuf + (size_t)row * D_DIM + d0;
        *(float4*)xo       = float4{v[0], v[1], v[2], v[3]};
        *(float4*)(xo + 4) = float4{v[4], v[5], v[6], v[7]};
    }
    float s = 0.f;
#pragma unroll
    for (int j = 0; j < 8; ++j) s += v[j];
#pragma unroll
    for (int off = 32; off; off >>= 1) s += __shfl_xor(s, off);
    const float mean = s * (1.f / 512.f);
    float ss = 0.f;
#pragma unroll
    for (int j = 0; j < 8; ++j) { float d = v[j] - mean; ss += d * d; }
#pragma unroll
    for (int off = 32; off; off >>= 1) ss += __shfl_xor(ss, off);
    const float inv = 1.f / (sqrtf(ss * (1.f / 511.f)) + 1e-6f);
    if (FINAL) {
        const float alp = alphaP[0], gam = gammaP[0];
        float o[8];
#pragma unroll
        for (int j = 0; j < 8; ++j) o[j] = alp * ((v[j] - mean) * inv) + gam;
        float* op = outF + (size_t)row * D_DIM + d0;
        *(float4*)op       = float4{o[0], o[1], o[2], o[3]};
        *(float4*)(op + 4) = float4{o[4], o[5], o[6], o[7]};
    } else {
        f16x8 hv;
#pragma unroll
        for (int j = 0; j < 8; ++j) hv[j] = (half_t)((v[j] - mean) * inv);
        *(f16x8*)&hh[(size_t)row * D_DIM + d0] = hv;
    }
}

template<int FINAL>
__global__ __launch_bounds__(256)
void norm_rows(const float* __restrict__ x, half_t* __restrict__ hh,
               float* __restrict__ outF, const float* __restrict__ alphaP,
               const float* __restrict__ gammaP)
{
    const int row  = blockIdx.x * 4 + (threadIdx.x >> 6);
    const int lane = threadIdx.x & 63;
    const float* xr = x + (size_t)row * D_DIM + lane * 8;
    float4 a = *(const float4*)xr;
    float4 b = *(const float4*)(xr + 4);
    float v[8] = {a.x, a.y, a.z, a.w, b.x, b.y, b.z, b.w};
    float s = 0.f;
#pragma unroll
    for (int j = 0; j < 8; ++j) s += v[j];
#pragma unroll
    for (int off = 32; off; off >>= 1) s += __shfl_xor(s, off);
    const float mean = s * (1.f / 512.f);
    float ss = 0.f;
#pragma unroll
    for (int j = 0; j < 8; ++j) { float d = v[j] - mean; ss += d * d; }
#pragma unroll
    for (int off = 32; off; off >>= 1) ss += __shfl_xor(ss, off);
    const float inv = 1.f / (sqrtf(ss * (1.f / 511.f)) + 1e-6f);
    if (FINAL) {
        const float alp = alphaP[0], gam = gammaP[0];
        float o[8];
#pragma unroll
        for (int j = 0; j < 8; ++j) o[j] = alp * ((v[j] - mean) * inv) + gam;
        float* op = outF + (size_t)row * D_DIM + lane * 8;
        *(float4*)op       = float4{o[0], o[1], o[2], o[3]};
        *(float4*)(op + 4) = float4{o[4], o[5], o[6], o[7]};
    } else {
        f16x8 hv;
#pragma unroll
        for (int j = 0; j < 8; ++j) hv[j] = (half_t)((v[j] - mean) * inv);
        *(f16x8*)&hh[(size_t)row * D_DIM + lane * 8] = hv;
    }
}

__global__ __launch_bounds__(256)
void cast_f16(const float* __restrict__ in, half_t* __restrict__ out)
{
    size_t i = ((size_t)blockIdx.x * 256 + threadIdx.x) * 8;
    float4 a = *(const float4*)&in[i];
    float4 b = *(const float4*)&in[i + 4];
    float v[8] = {a.x, a.y, a.z, a.w, b.x, b.y, b.z, b.w};
    f16x8 o;
#pragma unroll
    for (int j = 0; j < 8; ++j) o[j] = (half_t)v[j];
    *(f16x8*)&out[i] = o;
}

// batched square-weight transpose: z = t*4 + layer; 8 weights in one launch
__global__ __launch_bounds__(256)
void transpose_cast8(const float* __restrict__ i0, const float* __restrict__ i1,
                     const float* __restrict__ i2, const float* __restrict__ i3,
                     const float* __restrict__ i4, const float* __restrict__ i5,
                     const float* __restrict__ i6, const float* __restrict__ i7,
                     half_t* __restrict__ o0, half_t* __restrict__ o1,
                     half_t* __restrict__ o2, half_t* __restrict__ o3,
                     half_t* __restrict__ o4, half_t* __restrict__ o5,
                     half_t* __restrict__ o6, half_t* __restrict__ o7,
                     float qscale)
{
    const int SQ = 512 * 512, QKVZ = 1536 * 512, KVZ = 1024 * 512;
    const int z = blockIdx.z, t = z >> 2, l = z & 3;
    const float* in; half_t* out; float sc = 1.f; int outZ;
    switch (t) {
        case 0: in = i0; out = o0; sc = qscale; outZ = QKVZ; break;
        case 1: in = i1; out = o1; outZ = QKVZ; break;
        case 2: in = i2; out = o2; outZ = QKVZ; break;
        case 3: in = i3; out = o3; outZ = SQ; break;
        case 4: in = i4; out = o4; sc = qscale; outZ = SQ; break;
        case 5: in = i5; out = o5; outZ = KVZ; break;
        case 6: in = i6; out = o6; outZ = KVZ; break;
        default: in = i7; out = o7; outZ = SQ; break;
    }
    in  += (size_t)l * SQ;
    out += (size_t)l * outZ;
    __shared__ float tile[32][33];
    const int tx = threadIdx.x & 31, ty = threadIdx.x >> 5;
    const int r0 = blockIdx.y * 32, c0 = blockIdx.x * 32;
#pragma unroll
    for (int i = 0; i < 4; ++i)
        tile[ty + i * 8][tx] = in[(size_t)(r0 + ty + i * 8) * 512 + c0 + tx];
    __syncthreads();
#pragma unroll
    for (int i = 0; i < 4; ++i)
        out[(size_t)(c0 + ty + i * 8) * 512 + r0 + tx] = (half_t)(tile[tx][ty + i * 8] * sc);
}

__global__ __launch_bounds__(256)
void transpose_cast(const float* __restrict__ in, half_t* __restrict__ out,
                    int R, int C, float scale, int inZ, int outZ)
{
    in  += (size_t)blockIdx.z * inZ;
    out += (size_t)blockIdx.z * outZ;
    __shared__ float tile[32][33];
    const int tx = threadIdx.x & 31, ty = threadIdx.x >> 5;
    const int r0 = blockIdx.y * 32, c0 = blockIdx.x * 32;
#pragma unroll
    for (int i = 0; i < 4; ++i)
        tile[ty + i * 8][tx] = in[(size_t)(r0 + ty + i * 8) * C + c0 + tx];
    __syncthreads();
#pragma unroll
    for (int i = 0; i < 4; ++i)
        out[(size_t)(c0 + ty + i * 8) * R + r0 + tx] = (half_t)(tile[tx][ty + i * 8] * scale);
}

__global__ __launch_bounds__(256)
void pack_masks(const float* __restrict__ cm, const int* __restrict__ ids,
                u32* __restrict__ crossb, u32* __restrict__ selfb)
{
    const int t = blockIdx.x;
    const float* row = cm + (size_t)t * S_DIM;
    __shared__ u32 cb[S_DIM / 32];
    __shared__ u16 sh16[256];
    const int tid = threadIdx.x;
    u32 bits = 0;
#pragma unroll
    for (int q = 0; q < 4; ++q) {
        float4 v = *(const float4*)&row[tid * 16 + q * 4];
        bits |= (v.x > 0.5f ? 1u : 0u) << (q * 4 + 0);
        bits |= (v.y > 0.5f ? 1u : 0u) << (q * 4 + 1);
        bits |= (v.z > 0.5f ? 1u : 0u) << (q * 4 + 2);
        bits |= (v.w > 0.5f ? 1u : 0u) << (q * 4 + 3);
    }
    ((u16*)cb)[tid] = (u16)bits;
    __syncthreads();
    u32 sb = 0;
#pragma unroll
    for (int q = 0; q < 4; ++q) {
        int4 id4 = *(const int4*)&ids[tid * 16 + q * 4];
        sb |= ((cb[id4.x >> 5] >> (id4.x & 31)) & 1u) << (q * 4 + 0);
        sb |= ((cb[id4.y >> 5] >> (id4.y & 31)) & 1u) << (q * 4 + 1);
        sb |= ((cb[id4.z >> 5] >> (id4.z & 31)) & 1u) << (q * 4 + 2);
        sb |= ((cb[id4.w >> 5] >> (id4.w & 31)) & 1u) << (q * 4 + 3);
    }
    sh16[tid] = (u16)sb;
    __syncthreads();
    if (tid < 128) {
        crossb[(size_t)t * 128 + tid] = cb[tid];
        selfb[(size_t)t * 128 + tid]  = (u32)sh16[2 * tid] | ((u32)sh16[2 * tid + 1] << 16);
    }
}

// ---------------------------------------------------------------------------
extern "C" void kernel_launch(void* const* d_in, const int* in_sizes, int n_in,
                              void* d_out, int out_size, void* d_ws, size_t ws_size,
                              hipStream_t stream)
{
    (void)in_sizes; (void)n_in; (void)out_size; (void)ws_size;

    const float* x0p  = (const float*)d_in[0];
    const float* encp = (const float*)d_in[1];
    const float* cmp  = (const float*)d_in[2];
    const float* Wq = (const float*)d_in[3], *Wk = (const float*)d_in[4];
    const float* Wv = (const float*)d_in[5], *Wo = (const float*)d_in[6];
    const float* Cq = (const float*)d_in[7], *Ck = (const float*)d_in[8];
    const float* Cv = (const float*)d_in[9], *Co = (const float*)d_in[10];
    const float* W1p = (const float*)d_in[11];
    const float* W2p = (const float*)d_in[12];
    const float* alphap = (const float*)d_in[13];
    const float* gammap = (const float*)d_in[14];
    const int*   idsp   = (const int*)d_in[15];
    float* outp = (float*)d_out;

    char* wp = (char*)d_ws;
    auto take = [&](size_t nelem, int esz) -> void* {
        void* p = (void*)wp;
        wp += (nelem * (size_t)esz + 255) & ~(size_t)255;
        return p;
    };
    half_t* wqkvT = (half_t*)take((size_t)NLAYER * 1536 * 512, 2);
    half_t* ckvT  = (half_t*)take((size_t)NLAYER * 1024 * 512, 2);
    half_t* cqT   = (half_t*)take((size_t)NLAYER * 512 * 512, 2);
    half_t* woT   = (half_t*)take((size_t)NLAYER * 512 * 512, 2);
    half_t* coT   = (half_t*)take((size_t)NLAYER * 512 * 512, 2);
    half_t* w1T   = (half_t*)take((size_t)NLAYER * D_DIM * F_DIM, 2);
    half_t* w2T   = (half_t*)take((size_t)NLAYER * D_DIM * F_DIM, 2);
    half_t* hh    = (half_t*)take((size_t)T_DIM * D_DIM, 2);
    half_t* qb    = (half_t*)take((size_t)T_DIM * D_DIM, 2);
    half_t* kb    = (half_t*)take((size_t)S_DIM * D_DIM, 2);
    half_t* vb    = (half_t*)take((size_t)S_DIM * D_DIM, 2);
    half_t* vTp   = (half_t*)take((size_t)S_DIM * D_DIM, 2);
    half_t* mid   = (half_t*)take((size_t)T_DIM * F_DIM, 2);
    half_t* enc16 = (half_t*)take((size_t)S_DIM * D_DIM, 2);
    half_t* kbC   = (half_t*)take((size_t)NLAYER * S_DIM * D_DIM, 2);
    half_t* vC    = (half_t*)take((size_t)NLAYER * S_DIM * D_DIM, 2);
    half_t* vTCp  = (half_t*)take((size_t)NLAYER * S_DIM * D_DIM, 2);
    float* xbuf   = (float*)take((size_t)T_DIM * D_DIM, 4);
    half_t* logit16 = (half_t*)take((size_t)T_DIM * S_DIM, 2);
    half_t* p16   = (half_t*)take((size_t)T_DIM * 2048, 2);
    float* pbuf   = (float*)take((size_t)T_DIM * 2048, 4);
    float2* rowstat = (float2*)take((size_t)T_DIM, 8);
    u32* crossb = (u32*)take((size_t)T_DIM * (S_DIM / 32), 4);
    u32* selfb  = (u32*)take((size_t)T_DIM * (S_DIM / 32), 4);

    const dim3 B(256), B512(512);
    const float qscale = 0.04419417382415922f; // 1/sqrt(512), folded into Wq/Cq

    // ---- one-time prep ----
    const int SQ = 512 * 512, FZ = 512 * 2048;
    transpose_cast8<<<dim3(16, 16, 32), B, 0, stream>>>(
        Wq, Wk, Wv, Wo, Cq, Ck, Cv, Co,
        wqkvT, wqkvT + SQ, wqkvT + 2 * SQ, woT, cqT, ckvT, ckvT + SQ, coT, qscale);
    transpose_cast<<<dim3(64,16,4), B, 0, stream>>>(W1p, w1T, 512, 2048, 1.f, FZ, FZ);
    transpose_cast<<<dim3(16,64,4), B, 0, stream>>>(W2p, w2T, 2048, 512, 1.f, FZ, FZ);
    cast_f16<<<dim3((S_DIM * D_DIM / 8) / 256), B, 0, stream>>>(encp, enc16);
    pack_masks<<<dim3(T_DIM), B, 0, stream>>>(cmp, idsp, crossb, selfb);
    gemm_nt<64, 7><<<dim3(2048), B512, 0, stream>>>(enc16, 512, ckvT, 512,
        4096, 512, 64, nullptr, kbC, vC, 0);
    gemm_fold<<<dim3(256, 1, NLAYER), B512, 0, stream>>>(coT, vC, vTCp,
        SQ, (long)KVS, (long)KVS);

    for (int l = 0; l < NLAYER; ++l) {
        // ---- head: residual fold of prev W2 + norm ----
        if (l == 0)
            norm_rows<0><<<T_DIM / 4, B, 0, stream>>>(x0p, hh, nullptr, nullptr, nullptr);
        else
            norm_red<0><<<T_DIM / 4, B, 0, stream>>>(xbuf, pbuf, xbuf, hh, nullptr, nullptr, nullptr);

        // ---- self attention ----
        gemm_nt<64, 5><<<dim3(768), B512, 0, stream>>>(hh, 512, wqkvT + (size_t)l * 1536 * 512, 512,
            1536, 512, 24, qb, kb, vb, 0);
        gemm_fold<<<dim3(256, 1, 1), B512, 0, stream>>>(woT + (size_t)l * SQ, vb, vTp, 0, 0, 0);
        gemm97<2><<<dim3(1024), B, 0, stream>>>(qb, 512, kb, 512,
            512, 32, logit16, nullptr, 4096);
        row_stats<<<dim3(T_DIM), B, 0, stream>>>(logit16, selfb, rowstat);
        gemm_pv<<<dim3(512), B, 0, stream>>>(logit16, vTp, selfb, rowstat, p16);
        attn_tail<<<dim3(T_DIM / 4), B, 0, stream>>>((l == 0) ? x0p : xbuf, p16, xbuf, hh);

        // ---- cross attention ----
        gemm_nt<64, 2><<<dim3(256), B512, 0, stream>>>(hh, 512, cqT + (size_t)l * SQ, 512,
            512, 512, 8, qb, nullptr, nullptr, 512);
        gemm97<2><<<dim3(1024), B, 0, stream>>>(qb, 512, kbC + (size_t)l * KVS, 512,
            512, 32, logit16, nullptr, 4096);
        row_stats<<<dim3(T_DIM), B, 0, stream>>>(logit16, crossb, rowstat);
        gemm_pv<<<dim3(512), B, 0, stream>>>(logit16, vTCp + (size_t)l * KVS, crossb, rowstat, p16);
        attn_tail<<<dim3(T_DIM / 4), B, 0, stream>>>(xbuf, p16, xbuf, hh);

        // ---- FFN ----
        gemm97<4><<<dim3(512), B, 0, stream>>>(hh, 512, w1T + (size_t)l * FZ, 512,
            512, 16, mid, nullptr, 2048);
        gemm97<0, 4, 0><<<dim3(512), B, 0, stream>>>(mid, 2048, w2T + (size_t)l * FZ, 2048,
            2048, 4, nullptr, pbuf, 2048);
    }

    norm_red<1><<<T_DIM / 4, B, 0, stream>>>(xbuf, pbuf, xbuf, nullptr, outp, alphap, gammap);
}

// Round 16
// 1076.746 us; speedup vs baseline: 1.1401x; 1.1100x over previous
//
#include <hip/hip_runtime.h>
#include <math.h>

typedef _Float16 half_t;
typedef unsigned int u32;
typedef unsigned short u16;
typedef float f32x4 __attribute__((ext_vector_type(4)));
typedef _Float16 f16x8 __attribute__((ext_vector_type(8)));
typedef _Float16 f16x4 __attribute__((ext_vector_type(4)));

#define T_DIM 4096
#define S_DIM 4096
#define D_DIM 512
#define F_DIM 2048
#define NLAYER 4
#define KVS ((size_t)4096 * 512)

__device__ __forceinline__ void gload16(const void* g, void* l) {
    __builtin_amdgcn_global_load_lds(
        (const __attribute__((address_space(1))) u32*)g,
        (__attribute__((address_space(3))) u32*)l, 16, 0, 0);
}

template<int N> __device__ __forceinline__ void wait_vm() {
    if constexpr (N == 0) asm volatile("s_waitcnt vmcnt(0)" ::: "memory");
    else if constexpr (N == 3) asm volatile("s_waitcnt vmcnt(3)" ::: "memory");
    else if constexpr (N == 4) asm volatile("s_waitcnt vmcnt(4)" ::: "memory");
    else if constexpr (N == 6) asm volatile("s_waitcnt vmcnt(6)" ::: "memory");
    else if constexpr (N == 8) asm volatile("s_waitcnt vmcnt(8)" ::: "memory");
}

// ---------------------------------------------------------------------------
// Workhorse: 512 thr, BM=128, BK=64, wave tile 32xBN/2 (round-9 proven).
// EPI: 1 f32 Cin+acc | 2 fp16 [M,N] | 5 QKV split (q,k row-major; vT ldd)
//      7 batched cross-KV (K row-major; vT transposed, per-layer KVS).
// ---------------------------------------------------------------------------
template<int BN, int EPI>
__global__ __launch_bounds__(512)
void gemm_nt(const half_t* __restrict__ A, int lda,
             const half_t* __restrict__ B, int ldb,
             int N, int K, int gx,
             const float* __restrict__ Cin, float* __restrict__ Cout,
             half_t* __restrict__ D1, half_t* __restrict__ D2,
             half_t* __restrict__ D3, int ldd)
{
    constexpr int BM = 128, BK = 64;
    constexpr int NF = BN / 32;
    constexpr int LPT = 2 + BN / 64;
    constexpr int NSLOT = (BN == 64) ? 3 : 2;
    __shared__ half_t As[NSLOT][BM * BK];
    __shared__ half_t Bs[NSLOT][BN * BK];

    const int tid  = threadIdx.x;
    const int wave = tid >> 6;
    const int lane = tid & 63;

    const int nb  = gridDim.x;
    const int bid = blockIdx.x;
    const int nid = (bid & 7) * (nb >> 3) + (bid >> 3);
    const int bx  = nid % gx;
    const int by  = nid / gx;
    const int bm = by * BM, bn = bx * BN;

    const int wm = (wave >> 1) * 32;
    const int wn = (wave & 1) * (BN / 2);
    const int kq = lane >> 4;
    const int rr = lane & 15;
    const int scol = (((lane & 7) ^ (lane >> 3)) << 3);

    f32x4 acc[2][NF];
#pragma unroll
    for (int m = 0; m < 2; ++m)
#pragma unroll
        for (int n = 0; n < NF; ++n)
            acc[m][n] = f32x4{0.f, 0.f, 0.f, 0.f};

    auto stage = [&](int buf, int k0) {
#pragma unroll
        for (int c = 0; c < 2; ++c) {
            const int row = wave * 16 + c * 8 + (lane >> 3);
            gload16(A + (size_t)(bm + row) * lda + k0 + scol,
                    (char*)&As[buf][0] + (wave * 2 + c) * 1024 + lane * 16);
        }
        if constexpr (BN == 64) {
            const int row = wave * 8 + (lane >> 3);
            gload16(B + (size_t)(bn + row) * ldb + k0 + scol,
                    (char*)&Bs[buf][0] + wave * 1024 + lane * 16);
        } else {
#pragma unroll
            for (int c = 0; c < 2; ++c) {
                const int row = wave * 16 + c * 8 + (lane >> 3);
                gload16(B + (size_t)(bn + row) * ldb + k0 + scol,
                        (char*)&Bs[buf][0] + (wave * 2 + c) * 1024 + lane * 16);
            }
        }
    };

    const int nt = K / BK;
    stage(0, 0);
    if constexpr (NSLOT == 3) stage(1, BK);
    int cur = 0, pf = NSLOT - 1;
    for (int t = 0; t < nt; ++t) {
        if (t + 1 < nt) wait_vm<(NSLOT - 2) * LPT>(); else wait_vm<0>();
        __builtin_amdgcn_s_barrier();
        if (t + NSLOT - 1 < nt) stage(pf, (t + NSLOT - 1) * BK);
#pragma unroll
        for (int ks = 0; ks < 2; ++ks) {
            f16x8 af[2], bf[NF];
#pragma unroll
            for (int m = 0; m < 2; ++m) {
                const int r = wm + m * 16 + rr;
                af[m] = *(const f16x8*)&As[cur][r * BK + (((ks * 4 + kq) ^ (r & 7)) << 3)];
            }
#pragma unroll
            for (int n = 0; n < NF; ++n) {
                const int r = wn + n * 16 + rr;
                bf[n] = *(const f16x8*)&Bs[cur][r * BK + (((ks * 4 + kq) ^ (r & 7)) << 3)];
            }
#pragma unroll
            for (int m = 0; m < 2; ++m)
#pragma unroll
                for (int n = 0; n < NF; ++n)
                    acc[m][n] = __builtin_amdgcn_mfma_f32_16x16x32_f16(af[m], bf[n], acc[m][n], 0, 0, 0);
        }
        cur = (cur + 1 == NSLOT) ? 0 : cur + 1;
        pf  = (pf  + 1 == NSLOT) ? 0 : pf  + 1;
    }

    const int r0 = bm + wm + (lane >> 4) * 4;
#pragma unroll
    for (int m = 0; m < 2; ++m)
#pragma unroll
        for (int n = 0; n < NF; ++n) {
            const int c = bn + wn + n * 16 + rr;
            if (EPI == 1) {
#pragma unroll
                for (int i = 0; i < 4; ++i) {
                    const int r = r0 + m * 16 + i;
                    Cout[(size_t)r * N + c] = Cin[(size_t)r * N + c] + acc[m][n][i];
                }
            } else if (EPI == 2) {
#pragma unroll
                for (int i = 0; i < 4; ++i)
                    D1[(size_t)(r0 + m * 16 + i) * ldd + c] = (half_t)acc[m][n][i];
            } else if (EPI == 5) {
                if (bn < 512) {
#pragma unroll
                    for (int i = 0; i < 4; ++i)
                        D1[(size_t)(r0 + m * 16 + i) * 512 + c] = (half_t)acc[m][n][i];
                } else if (bn < 1024) {
#pragma unroll
                    for (int i = 0; i < 4; ++i)
                        D2[(size_t)(r0 + m * 16 + i) * 512 + (c - 512)] = (half_t)acc[m][n][i];
                } else {
                    f16x4 hv;
#pragma unroll
                    for (int i = 0; i < 4; ++i) hv[i] = (half_t)acc[m][n][i];
                    *(f16x4*)&D3[(size_t)(c - 1024) * ldd + r0 + m * 16] = hv;
                }
            } else { // EPI == 7 batched cross-KV
                const int l = c >> 10;
                const int sub = c & 1023;
                if (sub < 512) {
#pragma unroll
                    for (int i = 0; i < 4; ++i)
                        D2[l * KVS + (size_t)(r0 + m * 16 + i) * 512 + sub] = (half_t)acc[m][n][i];
                } else {
                    f16x4 hv;
#pragma unroll
                    for (int i = 0; i < 4; ++i) hv[i] = (half_t)acc[m][n][i];
                    *(f16x4*)&D3[l * KVS + (size_t)(sub - 512) * ldd + r0 + m * 16] = hv;
                }
            }
        }
}

// ---------------------------------------------------------------------------
// m97 geometry: 256 thr / 4 waves, BM=BN=128, BK=32, 64x64 wave tile,
// 3-slot ring, vmcnt(4). SPLITK>1: fp16/fp32 partial slices at col soff.
// SPLITK==1: EPI 2 = fp16 store, 4 = relu fp16 store.
// ---------------------------------------------------------------------------
template<int EPI, int SPLITK = 1, int P16 = 1>
__global__ __launch_bounds__(256)
void gemm97(const half_t* __restrict__ A, int lda,
            const half_t* __restrict__ B, int ldb,
            int K, int gx, half_t* __restrict__ D,
            float* __restrict__ Fout, int ldd)
{
    constexpr int BK = 32, NSLOT = 3, LPT = 4;
    __shared__ half_t As[NSLOT][128 * BK];
    __shared__ half_t Bs[NSLOT][128 * BK];

    const int tid  = threadIdx.x;
    const int wave = tid >> 6;
    const int lane = tid & 63;

    const int nb  = gridDim.x;
    const int bid = blockIdx.x;
    const int nid = (bid & 7) * (nb >> 3) + (bid >> 3);
    const int gy  = nb / (gx * SPLITK);
    const int bx  = nid % gx;
    const int tmp = nid / gx;
    const int by  = tmp % gy;
    const int kz  = tmp / gy;
    const int bm = by * 128, bn = bx * 128;

    const int Keff = K / SPLITK;
    A += (size_t)kz * Keff;
    B += (size_t)kz * Keff;

    const int wm = (wave >> 1) * 64;
    const int wn = (wave & 1) * 64;
    const int kq = lane >> 4;
    const int rr = lane & 15;
    const int srow = lane >> 2;
    const int scol = (((lane & 3) ^ ((lane >> 3) & 3)) << 3);
    const int kqa  = kq ^ ((rr >> 1) & 3);

    const half_t* Abase = A + (size_t)(bm + wave * 16 + srow) * lda + scol;
    const half_t* Bbase = B + (size_t)(bn + wave * 16 + srow) * ldb + scol;

    f32x4 acc[4][4];
#pragma unroll
    for (int m = 0; m < 4; ++m)
#pragma unroll
        for (int n = 0; n < 4; ++n)
            acc[m][n] = f32x4{0.f, 0.f, 0.f, 0.f};

    auto stage = [&](int buf, int k0) {
#pragma unroll
        for (int c = 0; c < 2; ++c)
            gload16(Abase + (size_t)c * 64 * lda + k0,
                    (char*)&As[buf][0] + c * 4096 + wave * 1024 + lane * 16);
#pragma unroll
        for (int c = 0; c < 2; ++c)
            gload16(Bbase + (size_t)c * 64 * ldb + k0,
                    (char*)&Bs[buf][0] + c * 4096 + wave * 1024 + lane * 16);
    };

    const int nt = Keff / BK;
    stage(0, 0);
    stage(1, BK);
    int cur = 0, pf = 2;
    for (int t = 0; t < nt; ++t) {
        if (t + 1 < nt) wait_vm<LPT>(); else wait_vm<0>();
        __builtin_amdgcn_s_barrier();
        if (t + 2 < nt) stage(pf, (t + 2) * BK);
        f16x8 af[4], bf[4];
#pragma unroll
        for (int m = 0; m < 4; ++m)
            af[m] = *(const f16x8*)&As[cur][(wm + m * 16 + rr) * BK + kqa * 8];
#pragma unroll
        for (int n = 0; n < 4; ++n)
            bf[n] = *(const f16x8*)&Bs[cur][(wn + n * 16 + rr) * BK + kqa * 8];
#pragma unroll
        for (int m = 0; m < 4; ++m)
#pragma unroll
            for (int n = 0; n < 4; ++n)
                acc[m][n] = __builtin_amdgcn_mfma_f32_16x16x32_f16(af[m], bf[n], acc[m][n], 0, 0, 0);
        cur = (cur == 2) ? 0 : cur + 1;
        pf  = (pf  == 2) ? 0 : pf + 1;
    }

    const int r0 = bm + wm + (lane >> 4) * 4;
    const int soff = kz * gx * 128;
#pragma unroll
    for (int m = 0; m < 4; ++m)
#pragma unroll
        for (int n = 0; n < 4; ++n) {
            const int c = bn + wn + n * 16 + rr;
#pragma unroll
            for (int i = 0; i < 4; ++i) {
                float v = acc[m][n][i];
                const size_t r = r0 + m * 16 + i;
                if constexpr (SPLITK > 1) {
                    if constexpr (P16) D[r * ldd + soff + c] = (half_t)v;
                    else               Fout[r * ldd + soff + c] = v;
                } else {
                    if (EPI == 4) v = fmaxf(v, 0.f);
                    D[r * ldd + c] = (half_t)v;
                }
            }
        }
}

// ---------------------------------------------------------------------------
// Sum 4 fp16 partial slices [4096][4*512] -> fp16 [4096][512].
// ---------------------------------------------------------------------------
__global__ __launch_bounds__(256)
void reduce_p16(const half_t* __restrict__ P, half_t* __restrict__ ao)
{
    const size_t q = ((size_t)blockIdx.x * 256 + threadIdx.x) * 8;
    const size_t r = q >> 9;
    const int d = (int)(q & 511);
    const half_t* row = P + r * 2048 + d;
    float s[8] = {0.f};
#pragma unroll
    for (int j = 0; j < 4; ++j) {
        f16x8 v = *(const f16x8*)(row + j * 512);
#pragma unroll
        for (int e = 0; e < 8; ++e) s[e] += (float)v[e];
    }
    f16x8 o;
#pragma unroll
    for (int e = 0; e < 8; ++e) o[e] = (half_t)s[e];
    *(f16x8*)&ao[q] = o;
}

// ---------------------------------------------------------------------------
// norm_red: x = xin + sum of 4 fp32 W2 partial slices [4096][2048].
// FINAL=0 -> xbuf + hh fp16; FINAL=1 -> out = alpha*norm + gamma.
// ---------------------------------------------------------------------------
template<int FINAL>
__global__ __launch_bounds__(256)
void norm_red(const float* __restrict__ xin, const float* __restrict__ P,
              float* __restrict__ xbuf, half_t* __restrict__ hh,
              float* __restrict__ outF, const float* __restrict__ alphaP,
              const float* __restrict__ gammaP)
{
    const int row  = blockIdx.x * 4 + (threadIdx.x >> 6);
    const int lane = threadIdx.x & 63;
    const int d0 = lane * 8;
    const float* xr = xin + (size_t)row * D_DIM + d0;
    float v[8];
    {
        float4 a = *(const float4*)xr;
        float4 b = *(const float4*)(xr + 4);
        v[0]=a.x; v[1]=a.y; v[2]=a.z; v[3]=a.w; v[4]=b.x; v[5]=b.y; v[6]=b.z; v[7]=b.w;
    }
    const float* pr = P + (size_t)row * 2048 + d0;
#pragma unroll
    for (int j = 0; j < 4; ++j) {
        float4 a = *(const float4*)(pr + j * 512);
        float4 b = *(const float4*)(pr + j * 512 + 4);
        v[0]+=a.x; v[1]+=a.y; v[2]+=a.z; v[3]+=a.w; v[4]+=b.x; v[5]+=b.y; v[6]+=b.z; v[7]+=b.w;
    }
    if (!FINAL) {
        float* xo = xbuf + (size_t)row * D_DIM + d0;
        *(float4*)xo       = float4{v[0], v[1], v[2], v[3]};
        *(float4*)(xo + 4) = float4{v[4], v[5], v[6], v[7]};
    }
    float s = 0.f;
#pragma unroll
    for (int j = 0; j < 8; ++j) s += v[j];
#pragma unroll
    for (int off = 32; off; off >>= 1) s += __shfl_xor(s, off);
    const float mean = s * (1.f / 512.f);
    float ss = 0.f;
#pragma unroll
    for (int j = 0; j < 8; ++j) { float d = v[j] - mean; ss += d * d; }
#pragma unroll
    for (int off = 32; off; off >>= 1) ss += __shfl_xor(ss, off);
    const float inv = 1.f / (sqrtf(ss * (1.f / 511.f)) + 1e-6f);
    if (FINAL) {
        const float alp = alphaP[0], gam = gammaP[0];
        float o[8];
#pragma unroll
        for (int j = 0; j < 8; ++j) o[j] = alp * ((v[j] - mean) * inv) + gam;
        float* op = outF + (size_t)row * D_DIM + d0;
        *(float4*)op       = float4{o[0], o[1], o[2], o[3]};
        *(float4*)(op + 4) = float4{o[4], o[5], o[6], o[7]};
    } else {
        f16x8 hv;
#pragma unroll
        for (int j = 0; j < 8; ++j) hv[j] = (half_t)((v[j] - mean) * inv);
        *(f16x8*)&hh[(size_t)row * D_DIM + d0] = hv;
    }
}

// ---------------------------------------------------------------------------
// Plain row LayerNorm (ddof=1) -> hh fp16 (or final out).
// ---------------------------------------------------------------------------
template<int FINAL>
__global__ __launch_bounds__(256)
void norm_rows(const float* __restrict__ x, half_t* __restrict__ hh,
               float* __restrict__ outF, const float* __restrict__ alphaP,
               const float* __restrict__ gammaP)
{
    const int row  = blockIdx.x * 4 + (threadIdx.x >> 6);
    const int lane = threadIdx.x & 63;
    const float* xr = x + (size_t)row * D_DIM + lane * 8;
    float4 a = *(const float4*)xr;
    float4 b = *(const float4*)(xr + 4);
    float v[8] = {a.x, a.y, a.z, a.w, b.x, b.y, b.z, b.w};
    float s = 0.f;
#pragma unroll
    for (int j = 0; j < 8; ++j) s += v[j];
#pragma unroll
    for (int off = 32; off; off >>= 1) s += __shfl_xor(s, off);
    const float mean = s * (1.f / 512.f);
    float ss = 0.f;
#pragma unroll
    for (int j = 0; j < 8; ++j) { float d = v[j] - mean; ss += d * d; }
#pragma unroll
    for (int off = 32; off; off >>= 1) ss += __shfl_xor(ss, off);
    const float inv = 1.f / (sqrtf(ss * (1.f / 511.f)) + 1e-6f);
    if (FINAL) {
        const float alp = alphaP[0], gam = gammaP[0];
        float o[8];
#pragma unroll
        for (int j = 0; j < 8; ++j) o[j] = alp * ((v[j] - mean) * inv) + gam;
        float* op = outF + (size_t)row * D_DIM + lane * 8;
        *(float4*)op       = float4{o[0], o[1], o[2], o[3]};
        *(float4*)(op + 4) = float4{o[4], o[5], o[6], o[7]};
    } else {
        f16x8 hv;
#pragma unroll
        for (int j = 0; j < 8; ++j) hv[j] = (half_t)((v[j] - mean) * inv);
        *(f16x8*)&hh[(size_t)row * D_DIM + lane * 8] = hv;
    }
}

__global__ __launch_bounds__(256)
void cast_f16(const float* __restrict__ in, half_t* __restrict__ out)
{
    size_t i = ((size_t)blockIdx.x * 256 + threadIdx.x) * 8;
    float4 a = *(const float4*)&in[i];
    float4 b = *(const float4*)&in[i + 4];
    float v[8] = {a.x, a.y, a.z, a.w, b.x, b.y, b.z, b.w};
    f16x8 o;
#pragma unroll
    for (int j = 0; j < 8; ++j) o[j] = (half_t)v[j];
    *(f16x8*)&out[i] = o;
}

// batched square-weight transpose: z = t*4 + layer; 8 weights in one launch
__global__ __launch_bounds__(256)
void transpose_cast8(const float* __restrict__ i0, const float* __restrict__ i1,
                     const float* __restrict__ i2, const float* __restrict__ i3,
                     const float* __restrict__ i4, const float* __restrict__ i5,
                     const float* __restrict__ i6, const float* __restrict__ i7,
                     half_t* __restrict__ o0, half_t* __restrict__ o1,
                     half_t* __restrict__ o2, half_t* __restrict__ o3,
                     half_t* __restrict__ o4, half_t* __restrict__ o5,
                     half_t* __restrict__ o6, half_t* __restrict__ o7,
                     float qscale)
{
    const int SQ = 512 * 512, QKVZ = 1536 * 512, KVZ = 1024 * 512;
    const int z = blockIdx.z, t = z >> 2, l = z & 3;
    const float* in; half_t* out; float sc = 1.f; int outZ;
    switch (t) {
        case 0: in = i0; out = o0; sc = qscale; outZ = QKVZ; break;
        case 1: in = i1; out = o1; outZ = QKVZ; break;
        case 2: in = i2; out = o2; outZ = QKVZ; break;
        case 3: in = i3; out = o3; outZ = SQ; break;
        case 4: in = i4; out = o4; sc = qscale; outZ = SQ; break;
        case 5: in = i5; out = o5; outZ = KVZ; break;
        case 6: in = i6; out = o6; outZ = KVZ; break;
        default: in = i7; out = o7; outZ = SQ; break;
    }
    in  += (size_t)l * SQ;
    out += (size_t)l * outZ;
    __shared__ float tile[32][33];
    const int tx = threadIdx.x & 31, ty = threadIdx.x >> 5;
    const int r0 = blockIdx.y * 32, c0 = blockIdx.x * 32;
#pragma unroll
    for (int i = 0; i < 4; ++i)
        tile[ty + i * 8][tx] = in[(size_t)(r0 + ty + i * 8) * 512 + c0 + tx];
    __syncthreads();
#pragma unroll
    for (int i = 0; i < 4; ++i)
        out[(size_t)(c0 + ty + i * 8) * 512 + r0 + tx] = (half_t)(tile[tx][ty + i * 8] * sc);
}

__global__ __launch_bounds__(256)
void transpose_cast(const float* __restrict__ in, half_t* __restrict__ out,
                    int R, int C, float scale, int inZ, int outZ)
{
    in  += (size_t)blockIdx.z * inZ;
    out += (size_t)blockIdx.z * outZ;
    __shared__ float tile[32][33];
    const int tx = threadIdx.x & 31, ty = threadIdx.x >> 5;
    const int r0 = blockIdx.y * 32, c0 = blockIdx.x * 32;
#pragma unroll
    for (int i = 0; i < 4; ++i)
        tile[ty + i * 8][tx] = in[(size_t)(r0 + ty + i * 8) * C + c0 + tx];
    __syncthreads();
#pragma unroll
    for (int i = 0; i < 4; ++i)
        out[(size_t)(c0 + ty + i * 8) * R + r0 + tx] = (half_t)(tile[tx][ty + i * 8] * scale);
}

__global__ __launch_bounds__(256)
void pack_masks(const float* __restrict__ cm, const int* __restrict__ ids,
                u32* __restrict__ crossb, u32* __restrict__ selfb)
{
    const int t = blockIdx.x;
    const float* row = cm + (size_t)t * S_DIM;
    __shared__ u32 cb[S_DIM / 32];
    __shared__ u16 sh16[256];
    const int tid = threadIdx.x;
    u32 bits = 0;
#pragma unroll
    for (int q = 0; q < 4; ++q) {
        float4 v = *(const float4*)&row[tid * 16 + q * 4];
        bits |= (v.x > 0.5f ? 1u : 0u) << (q * 4 + 0);
        bits |= (v.y > 0.5f ? 1u : 0u) << (q * 4 + 1);
        bits |= (v.z > 0.5f ? 1u : 0u) << (q * 4 + 2);
        bits |= (v.w > 0.5f ? 1u : 0u) << (q * 4 + 3);
    }
    ((u16*)cb)[tid] = (u16)bits;
    __syncthreads();
    u32 sb = 0;
#pragma unroll
    for (int q = 0; q < 4; ++q) {
        int4 id4 = *(const int4*)&ids[tid * 16 + q * 4];
        sb |= ((cb[id4.x >> 5] >> (id4.x & 31)) & 1u) << (q * 4 + 0);
        sb |= ((cb[id4.y >> 5] >> (id4.y & 31)) & 1u) << (q * 4 + 1);
        sb |= ((cb[id4.z >> 5] >> (id4.z & 31)) & 1u) << (q * 4 + 2);
        sb |= ((cb[id4.w >> 5] >> (id4.w & 31)) & 1u) << (q * 4 + 3);
    }
    sh16[tid] = (u16)sb;
    __syncthreads();
    if (tid < 128) {
        crossb[(size_t)t * 128 + tid] = cb[tid];
        selfb[(size_t)t * 128 + tid]  = (u32)sh16[2 * tid] | ((u32)sh16[2 * tid + 1] << 16);
    }
}

// ---------------------------------------------------------------------------
// Row softmax over S=4096, fp16 logits in, fp16 P out (in place), mask bits.
// ---------------------------------------------------------------------------
__global__ __launch_bounds__(256)
void softmax_rows16(half_t* __restrict__ logits, const u32* __restrict__ bits)
{
    const int t = blockIdx.x;
    half_t* row = logits + (size_t)t * S_DIM;
    const u32* bw = bits + (size_t)t * (S_DIM / 32);
    __shared__ float red[8];
    const int tid = threadIdx.x, wave = tid >> 6, lane = tid & 63;
    const int s0 = tid * 16;
    f16x8 h0 = *(const f16x8*)&row[s0];
    f16x8 h1 = *(const f16x8*)&row[s0 + 8];
    const u32 w = bw[tid >> 1] >> ((tid & 1) * 16);
    float z[16];
    float lmax = -3.0e38f;
#pragma unroll
    for (int q = 0; q < 16; ++q) {
        const float v = (float)((q < 8) ? h0[q & 7] : h1[q & 7]);
        z[q] = v + (((w >> q) & 1u) ? 0.f : -1e9f);
        lmax = fmaxf(lmax, z[q]);
    }
#pragma unroll
    for (int off = 32; off; off >>= 1) lmax = fmaxf(lmax, __shfl_xor(lmax, off));
    if (lane == 0) red[wave] = lmax;
    __syncthreads();
    const float mx = fmaxf(fmaxf(red[0], red[1]), fmaxf(red[2], red[3]));
    float lsum = 0.f;
#pragma unroll
    for (int q = 0; q < 16; ++q) { z[q] = __expf(z[q] - mx); lsum += z[q]; }
#pragma unroll
    for (int off = 32; off; off >>= 1) lsum += __shfl_xor(lsum, off);
    if (lane == 0) red[4 + wave] = lsum;
    __syncthreads();
    const float inv = 1.f / (red[4] + red[5] + red[6] + red[7]);
    f16x8 o0, o1;
#pragma unroll
    for (int q = 0; q < 8; ++q) {
        o0[q] = (half_t)(z[q] * inv);
        o1[q] = (half_t)(z[q + 8] * inv);
    }
    *(f16x8*)&row[s0] = o0;
    *(f16x8*)&row[s0 + 8] = o1;
}

// ---------------------------------------------------------------------------
extern "C" void kernel_launch(void* const* d_in, const int* in_sizes, int n_in,
                              void* d_out, int out_size, void* d_ws, size_t ws_size,
                              hipStream_t stream)
{
    (void)in_sizes; (void)n_in; (void)out_size; (void)ws_size;

    const float* x0p  = (const float*)d_in[0];
    const float* encp = (const float*)d_in[1];
    const float* cmp  = (const float*)d_in[2];
    const float* Wq = (const float*)d_in[3], *Wk = (const float*)d_in[4];
    const float* Wv = (const float*)d_in[5], *Wo = (const float*)d_in[6];
    const float* Cq = (const float*)d_in[7], *Ck = (const float*)d_in[8];
    const float* Cv = (const float*)d_in[9], *Co = (const float*)d_in[10];
    const float* W1p = (const float*)d_in[11];
    const float* W2p = (const float*)d_in[12];
    const float* alphap = (const float*)d_in[13];
    const float* gammap = (const float*)d_in[14];
    const int*   idsp   = (const int*)d_in[15];
    float* outp = (float*)d_out;

    char* wp = (char*)d_ws;
    auto take = [&](size_t nelem, int esz) -> void* {
        void* p = (void*)wp;
        wp += (nelem * (size_t)esz + 255) & ~(size_t)255;
        return p;
    };
    half_t* wqkvT = (half_t*)take((size_t)NLAYER * 1536 * 512, 2);
    half_t* ckvT  = (half_t*)take((size_t)NLAYER * 1024 * 512, 2);
    half_t* cqT   = (half_t*)take((size_t)NLAYER * 512 * 512, 2);
    half_t* woT   = (half_t*)take((size_t)NLAYER * 512 * 512, 2);
    half_t* coT   = (half_t*)take((size_t)NLAYER * 512 * 512, 2);
    half_t* w1T   = (half_t*)take((size_t)NLAYER * D_DIM * F_DIM, 2);
    half_t* w2T   = (half_t*)take((size_t)NLAYER * D_DIM * F_DIM, 2);
    half_t* hh    = (half_t*)take((size_t)T_DIM * D_DIM, 2);
    half_t* qb    = (half_t*)take((size_t)T_DIM * D_DIM, 2);
    half_t* kb    = (half_t*)take((size_t)S_DIM * D_DIM, 2);
    half_t* vT    = (half_t*)take((size_t)S_DIM * D_DIM, 2);
    half_t* ao    = (half_t*)take((size_t)T_DIM * D_DIM, 2);
    half_t* mid   = (half_t*)take((size_t)T_DIM * F_DIM, 2);
    half_t* enc16 = (half_t*)take((size_t)S_DIM * D_DIM, 2);
    half_t* kbC   = (half_t*)take((size_t)NLAYER * S_DIM * D_DIM, 2);
    half_t* vTC   = (half_t*)take((size_t)NLAYER * S_DIM * D_DIM, 2);
    float* xbuf   = (float*)take((size_t)T_DIM * D_DIM, 4);
    half_t* logit16 = (half_t*)take((size_t)T_DIM * S_DIM, 2);
    half_t* p16   = (half_t*)take((size_t)T_DIM * 2048, 2);
    float* pbuf   = (float*)take((size_t)T_DIM * 2048, 4);
    u32* crossb = (u32*)take((size_t)T_DIM * (S_DIM / 32), 4);
    u32* selfb  = (u32*)take((size_t)T_DIM * (S_DIM / 32), 4);

    const dim3 B(256), B512(512);
    const float qscale = 0.04419417382415922f; // 1/sqrt(512), folded into Wq/Cq

    // ---- one-time prep ----
    const int SQ = 512 * 512, QKVZ = 1536 * 512, FZ = 512 * 2048;
    transpose_cast8<<<dim3(16, 16, 32), B, 0, stream>>>(
        Wq, Wk, Wv, Wo, Cq, Ck, Cv, Co,
        wqkvT, wqkvT + SQ, wqkvT + 2 * SQ, woT, cqT, ckvT, ckvT + SQ, coT, qscale);
    transpose_cast<<<dim3(64,16,4), B, 0, stream>>>(W1p, w1T, 512, 2048, 1.f, FZ, FZ);
    transpose_cast<<<dim3(16,64,4), B, 0, stream>>>(W2p, w2T, 2048, 512, 1.f, FZ, FZ);
    cast_f16<<<dim3((S_DIM * D_DIM / 8) / 256), B, 0, stream>>>(encp, enc16);
    pack_masks<<<dim3(T_DIM), B, 0, stream>>>(cmp, idsp, crossb, selfb);
    // batched cross-K/V for all layers: K row-major + vT transposed
    gemm_nt<64, 7><<<dim3(2048), B512, 0, stream>>>(enc16, 512, ckvT, 512,
        4096, 512, 64, nullptr, nullptr, nullptr, kbC, vTC, 4096);

    for (int l = 0; l < NLAYER; ++l) {
        const float* xin = (l == 0) ? x0p : xbuf;

        // ---- head: residual fold of prev W2 + norm ----
        if (l == 0)
            norm_rows<0><<<T_DIM / 4, B, 0, stream>>>(x0p, hh, nullptr, nullptr, nullptr);
        else
            norm_red<0><<<T_DIM / 4, B, 0, stream>>>(xbuf, pbuf, xbuf, hh, nullptr, nullptr, nullptr);

        // ---- self attention ----
        gemm_nt<64, 5><<<dim3(768), B512, 0, stream>>>(hh, 512, wqkvT + (size_t)l * QKVZ, 512,
            1536, 512, 24, nullptr, nullptr, qb, kb, vT, 4096);
        gemm97<2><<<dim3(1024), B, 0, stream>>>(qb, 512, kb, 512, 512, 32, logit16, nullptr, 4096);
        softmax_rows16<<<dim3(T_DIM), B, 0, stream>>>(logit16, selfb);
        gemm97<0, 4, 1><<<dim3(512), B, 0, stream>>>(logit16, 4096, vT, 4096,
            4096, 4, p16, nullptr, 2048);
        reduce_p16<<<dim3(1024), B, 0, stream>>>(p16, ao);
        gemm_nt<64, 1><<<dim3(256), B512, 0, stream>>>(ao, 512, woT + (size_t)l * SQ, 512,
            512, 512, 8, xin, xbuf, nullptr, nullptr, nullptr, 0);

        // ---- cross attention ----
        norm_rows<0><<<T_DIM / 4, B, 0, stream>>>(xbuf, hh, nullptr, nullptr, nullptr);
        gemm_nt<64, 2><<<dim3(256), B512, 0, stream>>>(hh, 512, cqT + (size_t)l * SQ, 512,
            512, 512, 8, nullptr, nullptr, qb, nullptr, nullptr, 512);
        gemm97<2><<<dim3(1024), B, 0, stream>>>(qb, 512, kbC + (size_t)l * KVS, 512,
            512, 32, logit16, nullptr, 4096);
        softmax_rows16<<<dim3(T_DIM), B, 0, stream>>>(logit16, crossb);
        gemm97<0, 4, 1><<<dim3(512), B, 0, stream>>>(logit16, 4096, vTC + (size_t)l * KVS, 4096,
            4096, 4, p16, nullptr, 2048);
        reduce_p16<<<dim3(1024), B, 0, stream>>>(p16, ao);
        gemm_nt<64, 1><<<dim3(256), B512, 0, stream>>>(ao, 512, coT + (size_t)l * SQ, 512,
            512, 512, 8, xbuf, xbuf, nullptr, nullptr, nullptr, 0);

        // ---- FFN ----
        norm_rows<0><<<T_DIM / 4, B, 0, stream>>>(xbuf, hh, nullptr, nullptr, nullptr);
        gemm97<4><<<dim3(512), B, 0, stream>>>(hh, 512, w1T + (size_t)l * FZ, 512,
            512, 16, mid, nullptr, 2048);
        gemm97<0, 4, 0><<<dim3(512), B, 0, stream>>>(mid, 2048, w2T + (size_t)l * FZ, 2048,
            2048, 4, nullptr, pbuf, 2048);
    }

    norm_red<1><<<T_DIM / 4, B, 0, stream>>>(xbuf, pbuf, xbuf, nullptr, outp, alphap, gammap);
}

// Round 17
// 1068.435 us; speedup vs baseline: 1.1490x; 1.0078x over previous
//
#include <hip/hip_runtime.h>
#include <math.h>

typedef _Float16 half_t;
typedef unsigned int u32;
typedef unsigned short u16;
typedef float f32x4 __attribute__((ext_vector_type(4)));
typedef _Float16 f16x8 __attribute__((ext_vector_type(8)));
typedef _Float16 f16x4 __attribute__((ext_vector_type(4)));

#define T_DIM 4096
#define S_DIM 4096
#define D_DIM 512
#define F_DIM 2048
#define NLAYER 4
#define KVS ((size_t)4096 * 512)

__device__ __forceinline__ void gload16(const void* g, void* l) {
    __builtin_amdgcn_global_load_lds(
        (const __attribute__((address_space(1))) u32*)g,
        (__attribute__((address_space(3))) u32*)l, 16, 0, 0);
}

template<int N> __device__ __forceinline__ void wait_vm() {
    if constexpr (N == 0) asm volatile("s_waitcnt vmcnt(0)" ::: "memory");
    else if constexpr (N == 3) asm volatile("s_waitcnt vmcnt(3)" ::: "memory");
    else if constexpr (N == 4) asm volatile("s_waitcnt vmcnt(4)" ::: "memory");
    else if constexpr (N == 6) asm volatile("s_waitcnt vmcnt(6)" ::: "memory");
    else if constexpr (N == 8) asm volatile("s_waitcnt vmcnt(8)" ::: "memory");
}

// ---------------------------------------------------------------------------
// Workhorse: 512 thr, BM=128, BK=64, wave tile 32xBN/2 (round-9 proven).
// EPI: 1 f32 Cin+acc | 2 fp16 [M,N].  (N=512 shapes: Cq, Wo, Co residual.)
// ---------------------------------------------------------------------------
template<int BN, int EPI>
__global__ __launch_bounds__(512)
void gemm_nt(const half_t* __restrict__ A, int lda,
             const half_t* __restrict__ B, int ldb,
             int N, int K, int gx,
             const float* __restrict__ Cin, float* __restrict__ Cout,
             half_t* __restrict__ D1, int ldd)
{
    constexpr int BM = 128, BK = 64;
    constexpr int NF = BN / 32;
    constexpr int LPT = 2 + BN / 64;
    constexpr int NSLOT = (BN == 64) ? 3 : 2;
    __shared__ half_t As[NSLOT][BM * BK];
    __shared__ half_t Bs[NSLOT][BN * BK];

    const int tid  = threadIdx.x;
    const int wave = tid >> 6;
    const int lane = tid & 63;

    const int nb  = gridDim.x;
    const int bid = blockIdx.x;
    const int nid = (bid & 7) * (nb >> 3) + (bid >> 3);
    const int bx  = nid % gx;
    const int by  = nid / gx;
    const int bm = by * BM, bn = bx * BN;

    const int wm = (wave >> 1) * 32;
    const int wn = (wave & 1) * (BN / 2);
    const int kq = lane >> 4;
    const int rr = lane & 15;
    const int scol = (((lane & 7) ^ (lane >> 3)) << 3);

    f32x4 acc[2][NF];
#pragma unroll
    for (int m = 0; m < 2; ++m)
#pragma unroll
        for (int n = 0; n < NF; ++n)
            acc[m][n] = f32x4{0.f, 0.f, 0.f, 0.f};

    auto stage = [&](int buf, int k0) {
#pragma unroll
        for (int c = 0; c < 2; ++c) {
            const int row = wave * 16 + c * 8 + (lane >> 3);
            gload16(A + (size_t)(bm + row) * lda + k0 + scol,
                    (char*)&As[buf][0] + (wave * 2 + c) * 1024 + lane * 16);
        }
        if constexpr (BN == 64) {
            const int row = wave * 8 + (lane >> 3);
            gload16(B + (size_t)(bn + row) * ldb + k0 + scol,
                    (char*)&Bs[buf][0] + wave * 1024 + lane * 16);
        } else {
#pragma unroll
            for (int c = 0; c < 2; ++c) {
                const int row = wave * 16 + c * 8 + (lane >> 3);
                gload16(B + (size_t)(bn + row) * ldb + k0 + scol,
                        (char*)&Bs[buf][0] + (wave * 2 + c) * 1024 + lane * 16);
            }
        }
    };

    const int nt = K / BK;
    stage(0, 0);
    if constexpr (NSLOT == 3) stage(1, BK);
    int cur = 0, pf = NSLOT - 1;
    for (int t = 0; t < nt; ++t) {
        if (t + 1 < nt) wait_vm<(NSLOT - 2) * LPT>(); else wait_vm<0>();
        __builtin_amdgcn_s_barrier();
        if (t + NSLOT - 1 < nt) stage(pf, (t + NSLOT - 1) * BK);
#pragma unroll
        for (int ks = 0; ks < 2; ++ks) {
            f16x8 af[2], bf[NF];
#pragma unroll
            for (int m = 0; m < 2; ++m) {
                const int r = wm + m * 16 + rr;
                af[m] = *(const f16x8*)&As[cur][r * BK + (((ks * 4 + kq) ^ (r & 7)) << 3)];
            }
#pragma unroll
            for (int n = 0; n < NF; ++n) {
                const int r = wn + n * 16 + rr;
                bf[n] = *(const f16x8*)&Bs[cur][r * BK + (((ks * 4 + kq) ^ (r & 7)) << 3)];
            }
#pragma unroll
            for (int m = 0; m < 2; ++m)
#pragma unroll
                for (int n = 0; n < NF; ++n)
                    acc[m][n] = __builtin_amdgcn_mfma_f32_16x16x32_f16(af[m], bf[n], acc[m][n], 0, 0, 0);
        }
        cur = (cur + 1 == NSLOT) ? 0 : cur + 1;
        pf  = (pf  + 1 == NSLOT) ? 0 : pf  + 1;
    }

    const int r0 = bm + wm + (lane >> 4) * 4;
#pragma unroll
    for (int m = 0; m < 2; ++m)
#pragma unroll
        for (int n = 0; n < NF; ++n) {
            const int c = bn + wn + n * 16 + rr;
            if (EPI == 1) {
#pragma unroll
                for (int i = 0; i < 4; ++i) {
                    const int r = r0 + m * 16 + i;
                    Cout[(size_t)r * N + c] = Cin[(size_t)r * N + c] + acc[m][n][i];
                }
            } else { // EPI == 2
#pragma unroll
                for (int i = 0; i < 4; ++i)
                    D1[(size_t)(r0 + m * 16 + i) * ldd + c] = (half_t)acc[m][n][i];
            }
        }
}

// ---------------------------------------------------------------------------
// m97 geometry: 256 thr / 4 waves, BM=BN=128, BK=32, 64x64 wave tile,
// 3-slot ring, vmcnt(4). Same 32-granular K accumulation order as the
// workhorse -> bit-identical results when migrating shapes between them.
// EPI (SPLITK==1): 2 fp16 store | 4 relu fp16 store |
//   5 QKV split: c<512 -> D row-major 512; c<1024 -> D2 row-major 512;
//     else vT transposed into D3 (ldd) |
//   7 batched cross-KV: l=c>>10, sub=c&1023; sub<512 -> D2+l*KVS row-major;
//     else transposed into D3+l*KVS (ldd).
// SPLITK>1: fp16/fp32 partial slices at col soff.
// ---------------------------------------------------------------------------
template<int EPI, int SPLITK = 1, int P16 = 1>
__global__ __launch_bounds__(256)
void gemm97(const half_t* __restrict__ A, int lda,
            const half_t* __restrict__ B, int ldb,
            int K, int gx, half_t* __restrict__ D,
            float* __restrict__ Fout, int ldd,
            half_t* __restrict__ D2 = nullptr, half_t* __restrict__ D3 = nullptr)
{
    constexpr int BK = 32, NSLOT = 3, LPT = 4;
    __shared__ half_t As[NSLOT][128 * BK];
    __shared__ half_t Bs[NSLOT][128 * BK];

    const int tid  = threadIdx.x;
    const int wave = tid >> 6;
    const int lane = tid & 63;

    const int nb  = gridDim.x;
    const int bid = blockIdx.x;
    const int nid = (bid & 7) * (nb >> 3) + (bid >> 3);
    const int gy  = nb / (gx * SPLITK);
    const int bx  = nid % gx;
    const int tmp = nid / gx;
    const int by  = tmp % gy;
    const int kz  = tmp / gy;
    const int bm = by * 128, bn = bx * 128;

    const int Keff = K / SPLITK;
    A += (size_t)kz * Keff;
    B += (size_t)kz * Keff;

    const int wm = (wave >> 1) * 64;
    const int wn = (wave & 1) * 64;
    const int kq = lane >> 4;
    const int rr = lane & 15;
    const int srow = lane >> 2;
    const int scol = (((lane & 3) ^ ((lane >> 3) & 3)) << 3);
    const int kqa  = kq ^ ((rr >> 1) & 3);

    const half_t* Abase = A + (size_t)(bm + wave * 16 + srow) * lda + scol;
    const half_t* Bbase = B + (size_t)(bn + wave * 16 + srow) * ldb + scol;

    f32x4 acc[4][4];
#pragma unroll
    for (int m = 0; m < 4; ++m)
#pragma unroll
        for (int n = 0; n < 4; ++n)
            acc[m][n] = f32x4{0.f, 0.f, 0.f, 0.f};

    auto stage = [&](int buf, int k0) {
#pragma unroll
        for (int c = 0; c < 2; ++c)
            gload16(Abase + (size_t)c * 64 * lda + k0,
                    (char*)&As[buf][0] + c * 4096 + wave * 1024 + lane * 16);
#pragma unroll
        for (int c = 0; c < 2; ++c)
            gload16(Bbase + (size_t)c * 64 * ldb + k0,
                    (char*)&Bs[buf][0] + c * 4096 + wave * 1024 + lane * 16);
    };

    const int nt = Keff / BK;
    stage(0, 0);
    stage(1, BK);
    int cur = 0, pf = 2;
    for (int t = 0; t < nt; ++t) {
        if (t + 1 < nt) wait_vm<LPT>(); else wait_vm<0>();
        __builtin_amdgcn_s_barrier();
        if (t + 2 < nt) stage(pf, (t + 2) * BK);
        f16x8 af[4], bf[4];
#pragma unroll
        for (int m = 0; m < 4; ++m)
            af[m] = *(const f16x8*)&As[cur][(wm + m * 16 + rr) * BK + kqa * 8];
#pragma unroll
        for (int n = 0; n < 4; ++n)
            bf[n] = *(const f16x8*)&Bs[cur][(wn + n * 16 + rr) * BK + kqa * 8];
#pragma unroll
        for (int m = 0; m < 4; ++m)
#pragma unroll
            for (int n = 0; n < 4; ++n)
                acc[m][n] = __builtin_amdgcn_mfma_f32_16x16x32_f16(af[m], bf[n], acc[m][n], 0, 0, 0);
        cur = (cur == 2) ? 0 : cur + 1;
        pf  = (pf  == 2) ? 0 : pf + 1;
    }

    const int r0 = bm + wm + (lane >> 4) * 4;
    const int soff = kz * gx * 128;
#pragma unroll
    for (int m = 0; m < 4; ++m)
#pragma unroll
        for (int n = 0; n < 4; ++n) {
            const int c = bn + wn + n * 16 + rr;
            if constexpr (SPLITK > 1) {
#pragma unroll
                for (int i = 0; i < 4; ++i) {
                    const size_t r = r0 + m * 16 + i;
                    if constexpr (P16) D[r * ldd + soff + c] = (half_t)acc[m][n][i];
                    else               Fout[r * ldd + soff + c] = acc[m][n][i];
                }
            } else if (EPI == 5) {
                // QKV split (bn uniform per block; regions 512-aligned)
                if (bn < 512) {
#pragma unroll
                    for (int i = 0; i < 4; ++i)
                        D[(size_t)(r0 + m * 16 + i) * 512 + c] = (half_t)acc[m][n][i];
                } else if (bn < 1024) {
#pragma unroll
                    for (int i = 0; i < 4; ++i)
                        D2[(size_t)(r0 + m * 16 + i) * 512 + (c - 512)] = (half_t)acc[m][n][i];
                } else {
                    f16x4 hv;
#pragma unroll
                    for (int i = 0; i < 4; ++i) hv[i] = (half_t)acc[m][n][i];
                    *(f16x4*)&D3[(size_t)(c - 1024) * ldd + r0 + m * 16] = hv;
                }
            } else if (EPI == 7) {
                const int l = c >> 10;
                const int sub = c & 1023;
                if (sub < 512) {
#pragma unroll
                    for (int i = 0; i < 4; ++i)
                        D2[l * KVS + (size_t)(r0 + m * 16 + i) * 512 + sub] = (half_t)acc[m][n][i];
                } else {
                    f16x4 hv;
#pragma unroll
                    for (int i = 0; i < 4; ++i) hv[i] = (half_t)acc[m][n][i];
                    *(f16x4*)&D3[l * KVS + (size_t)(sub - 512) * ldd + r0 + m * 16] = hv;
                }
            } else {
#pragma unroll
                for (int i = 0; i < 4; ++i) {
                    float v = acc[m][n][i];
                    if (EPI == 4) v = fmaxf(v, 0.f);
                    D[(size_t)(r0 + m * 16 + i) * ldd + c] = (half_t)v;
                }
            }
        }
}

// ---------------------------------------------------------------------------
// Sum 4 fp16 partial slices [4096][4*512] -> fp16 [4096][512].
// ---------------------------------------------------------------------------
__global__ __launch_bounds__(256)
void reduce_p16(const half_t* __restrict__ P, half_t* __restrict__ ao)
{
    const size_t q = ((size_t)blockIdx.x * 256 + threadIdx.x) * 8;
    const size_t r = q >> 9;
    const int d = (int)(q & 511);
    const half_t* row = P + r * 2048 + d;
    float s[8] = {0.f};
#pragma unroll
    for (int j = 0; j < 4; ++j) {
        f16x8 v = *(const f16x8*)(row + j * 512);
#pragma unroll
        for (int e = 0; e < 8; ++e) s[e] += (float)v[e];
    }
    f16x8 o;
#pragma unroll
    for (int e = 0; e < 8; ++e) o[e] = (half_t)s[e];
    *(f16x8*)&ao[q] = o;
}

// ---------------------------------------------------------------------------
// norm_red: x = xin + sum of 4 fp32 W2 partial slices [4096][2048].
// FINAL=0 -> xbuf + hh fp16; FINAL=1 -> out = alpha*norm + gamma.
// ---------------------------------------------------------------------------
template<int FINAL>
__global__ __launch_bounds__(256)
void norm_red(const float* __restrict__ xin, const float* __restrict__ P,
              float* __restrict__ xbuf, half_t* __restrict__ hh,
              float* __restrict__ outF, const float* __restrict__ alphaP,
              const float* __restrict__ gammaP)
{
    const int row  = blockIdx.x * 4 + (threadIdx.x >> 6);
    const int lane = threadIdx.x & 63;
    const int d0 = lane * 8;
    const float* xr = xin + (size_t)row * D_DIM + d0;
    float v[8];
    {
        float4 a = *(const float4*)xr;
        float4 b = *(const float4*)(xr + 4);
        v[0]=a.x; v[1]=a.y; v[2]=a.z; v[3]=a.w; v[4]=b.x; v[5]=b.y; v[6]=b.z; v[7]=b.w;
    }
    const float* pr = P + (size_t)row * 2048 + d0;
#pragma unroll
    for (int j = 0; j < 4; ++j) {
        float4 a = *(const float4*)(pr + j * 512);
        float4 b = *(const float4*)(pr + j * 512 + 4);
        v[0]+=a.x; v[1]+=a.y; v[2]+=a.z; v[3]+=a.w; v[4]+=b.x; v[5]+=b.y; v[6]+=b.z; v[7]+=b.w;
    }
    if (!FINAL) {
        float* xo = xbuf + (size_t)row * D_DIM + d0;
        *(float4*)xo       = float4{v[0], v[1], v[2], v[3]};
        *(float4*)(xo + 4) = float4{v[4], v[5], v[6], v[7]};
    }
    float s = 0.f;
#pragma unroll
    for (int j = 0; j < 8; ++j) s += v[j];
#pragma unroll
    for (int off = 32; off; off >>= 1) s += __shfl_xor(s, off);
    const float mean = s * (1.f / 512.f);
    float ss = 0.f;
#pragma unroll
    for (int j = 0; j < 8; ++j) { float d = v[j] - mean; ss += d * d; }
#pragma unroll
    for (int off = 32; off; off >>= 1) ss += __shfl_xor(ss, off);
    const float inv = 1.f / (sqrtf(ss * (1.f / 511.f)) + 1e-6f);
    if (FINAL) {
        const float alp = alphaP[0], gam = gammaP[0];
        float o[8];
#pragma unroll
        for (int j = 0; j < 8; ++j) o[j] = alp * ((v[j] - mean) * inv) + gam;
        float* op = outF + (size_t)row * D_DIM + d0;
        *(float4*)op       = float4{o[0], o[1], o[2], o[3]};
        *(float4*)(op + 4) = float4{o[4], o[5], o[6], o[7]};
    } else {
        f16x8 hv;
#pragma unroll
        for (int j = 0; j < 8; ++j) hv[j] = (half_t)((v[j] - mean) * inv);
        *(f16x8*)&hh[(size_t)row * D_DIM + d0] = hv;
    }
}

// ---------------------------------------------------------------------------
// Plain row LayerNorm (ddof=1) -> hh fp16 (or final out).
// ---------------------------------------------------------------------------
template<int FINAL>
__global__ __launch_bounds__(256)
void norm_rows(const float* __restrict__ x, half_t* __restrict__ hh,
               float* __restrict__ outF, const float* __restrict__ alphaP,
               const float* __restrict__ gammaP)
{
    const int row  = blockIdx.x * 4 + (threadIdx.x >> 6);
    const int lane = threadIdx.x & 63;
    const float* xr = x + (size_t)row * D_DIM + lane * 8;
    float4 a = *(const float4*)xr;
    float4 b = *(const float4*)(xr + 4);
    float v[8] = {a.x, a.y, a.z, a.w, b.x, b.y, b.z, b.w};
    float s = 0.f;
#pragma unroll
    for (int j = 0; j < 8; ++j) s += v[j];
#pragma unroll
    for (int off = 32; off; off >>= 1) s += __shfl_xor(s, off);
    const float mean = s * (1.f / 512.f);
    float ss = 0.f;
#pragma unroll
    for (int j = 0; j < 8; ++j) { float d = v[j] - mean; ss += d * d; }
#pragma unroll
    for (int off = 32; off; off >>= 1) ss += __shfl_xor(ss, off);
    const float inv = 1.f / (sqrtf(ss * (1.f / 511.f)) + 1e-6f);
    if (FINAL) {
        const float alp = alphaP[0], gam = gammaP[0];
        float o[8];
#pragma unroll
        for (int j = 0; j < 8; ++j) o[j] = alp * ((v[j] - mean) * inv) + gam;
        float* op = outF + (size_t)row * D_DIM + lane * 8;
        *(float4*)op       = float4{o[0], o[1], o[2], o[3]};
        *(float4*)(op + 4) = float4{o[4], o[5], o[6], o[7]};
    } else {
        f16x8 hv;
#pragma unroll
        for (int j = 0; j < 8; ++j) hv[j] = (half_t)((v[j] - mean) * inv);
        *(f16x8*)&hh[(size_t)row * D_DIM + lane * 8] = hv;
    }
}

__global__ __launch_bounds__(256)
void cast_f16(const float* __restrict__ in, half_t* __restrict__ out)
{
    size_t i = ((size_t)blockIdx.x * 256 + threadIdx.x) * 8;
    float4 a = *(const float4*)&in[i];
    float4 b = *(const float4*)&in[i + 4];
    float v[8] = {a.x, a.y, a.z, a.w, b.x, b.y, b.z, b.w};
    f16x8 o;
#pragma unroll
    for (int j = 0; j < 8; ++j) o[j] = (half_t)v[j];
    *(f16x8*)&out[i] = o;
}

// batched square-weight transpose: z = t*4 + layer; 8 weights in one launch
__global__ __launch_bounds__(256)
void transpose_cast8(const float* __restrict__ i0, const float* __restrict__ i1,
                     const float* __restrict__ i2, const float* __restrict__ i3,
                     const float* __restrict__ i4, const float* __restrict__ i5,
                     const float* __restrict__ i6, const float* __restrict__ i7,
                     half_t* __restrict__ o0, half_t* __restrict__ o1,
                     half_t* __restrict__ o2, half_t* __restrict__ o3,
                     half_t* __restrict__ o4, half_t* __restrict__ o5,
                     half_t* __restrict__ o6, half_t* __restrict__ o7,
                     float qscale)
{
    const int SQ = 512 * 512, QKVZ = 1536 * 512, KVZ = 1024 * 512;
    const int z = blockIdx.z, t = z >> 2, l = z & 3;
    const float* in; half_t* out; float sc = 1.f; int outZ;
    switch (t) {
        case 0: in = i0; out = o0; sc = qscale; outZ = QKVZ; break;
        case 1: in = i1; out = o1; outZ = QKVZ; break;
        case 2: in = i2; out = o2; outZ = QKVZ; break;
        case 3: in = i3; out = o3; outZ = SQ; break;
        case 4: in = i4; out = o4; sc = qscale; outZ = SQ; break;
        case 5: in = i5; out = o5; outZ = KVZ; break;
        case 6: in = i6; out = o6; outZ = KVZ; break;
        default: in = i7; out = o7; outZ = SQ; break;
    }
    in  += (size_t)l * SQ;
    out += (size_t)l * outZ;
    __shared__ float tile[32][33];
    const int tx = threadIdx.x & 31, ty = threadIdx.x >> 5;
    const int r0 = blockIdx.y * 32, c0 = blockIdx.x * 32;
#pragma unroll
    for (int i = 0; i < 4; ++i)
        tile[ty + i * 8][tx] = in[(size_t)(r0 + ty + i * 8) * 512 + c0 + tx];
    __syncthreads();
#pragma unroll
    for (int i = 0; i < 4; ++i)
        out[(size_t)(c0 + ty + i * 8) * 512 + r0 + tx] = (half_t)(tile[tx][ty + i * 8] * sc);
}

__global__ __launch_bounds__(256)
void transpose_cast(const float* __restrict__ in, half_t* __restrict__ out,
                    int R, int C, float scale, int inZ, int outZ)
{
    in  += (size_t)blockIdx.z * inZ;
    out += (size_t)blockIdx.z * outZ;
    __shared__ float tile[32][33];
    const int tx = threadIdx.x & 31, ty = threadIdx.x >> 5;
    const int r0 = blockIdx.y * 32, c0 = blockIdx.x * 32;
#pragma unroll
    for (int i = 0; i < 4; ++i)
        tile[ty + i * 8][tx] = in[(size_t)(r0 + ty + i * 8) * C + c0 + tx];
    __syncthreads();
#pragma unroll
    for (int i = 0; i < 4; ++i)
        out[(size_t)(c0 + ty + i * 8) * R + r0 + tx] = (half_t)(tile[tx][ty + i * 8] * scale);
}

__global__ __launch_bounds__(256)
void pack_masks(const float* __restrict__ cm, const int* __restrict__ ids,
                u32* __restrict__ crossb, u32* __restrict__ selfb)
{
    const int t = blockIdx.x;
    const float* row = cm + (size_t)t * S_DIM;
    __shared__ u32 cb[S_DIM / 32];
    __shared__ u16 sh16[256];
    const int tid = threadIdx.x;
    u32 bits = 0;
#pragma unroll
    for (int q = 0; q < 4; ++q) {
        float4 v = *(const float4*)&row[tid * 16 + q * 4];
        bits |= (v.x > 0.5f ? 1u : 0u) << (q * 4 + 0);
        bits |= (v.y > 0.5f ? 1u : 0u) << (q * 4 + 1);
        bits |= (v.z > 0.5f ? 1u : 0u) << (q * 4 + 2);
        bits |= (v.w > 0.5f ? 1u : 0u) << (q * 4 + 3);
    }
    ((u16*)cb)[tid] = (u16)bits;
    __syncthreads();
    u32 sb = 0;
#pragma unroll
    for (int q = 0; q < 4; ++q) {
        int4 id4 = *(const int4*)&ids[tid * 16 + q * 4];
        sb |= ((cb[id4.x >> 5] >> (id4.x & 31)) & 1u) << (q * 4 + 0);
        sb |= ((cb[id4.y >> 5] >> (id4.y & 31)) & 1u) << (q * 4 + 1);
        sb |= ((cb[id4.z >> 5] >> (id4.z & 31)) & 1u) << (q * 4 + 2);
        sb |= ((cb[id4.w >> 5] >> (id4.w & 31)) & 1u) << (q * 4 + 3);
    }
    sh16[tid] = (u16)sb;
    __syncthreads();
    if (tid < 128) {
        crossb[(size_t)t * 128 + tid] = cb[tid];
        selfb[(size_t)t * 128 + tid]  = (u32)sh16[2 * tid] | ((u32)sh16[2 * tid + 1] << 16);
    }
}

// ---------------------------------------------------------------------------
// Row softmax over S=4096, fp16 logits in, fp16 P out (in place), mask bits.
// ---------------------------------------------------------------------------
__global__ __launch_bounds__(256)
void softmax_rows16(half_t* __restrict__ logits, const u32* __restrict__ bits)
{
    const int t = blockIdx.x;
    half_t* row = logits + (size_t)t * S_DIM;
    const u32* bw = bits + (size_t)t * (S_DIM / 32);
    __shared__ float red[8];
    const int tid = threadIdx.x, wave = tid >> 6, lane = tid & 63;
    const int s0 = tid * 16;
    f16x8 h0 = *(const f16x8*)&row[s0];
    f16x8 h1 = *(const f16x8*)&row[s0 + 8];
    const u32 w = bw[tid >> 1] >> ((tid & 1) * 16);
    float z[16];
    float lmax = -3.0e38f;
#pragma unroll
    for (int q = 0; q < 16; ++q) {
        const float v = (float)((q < 8) ? h0[q & 7] : h1[q & 7]);
        z[q] = v + (((w >> q) & 1u) ? 0.f : -1e9f);
        lmax = fmaxf(lmax, z[q]);
    }
#pragma unroll
    for (int off = 32; off; off >>= 1) lmax = fmaxf(lmax, __shfl_xor(lmax, off));
    if (lane == 0) red[wave] = lmax;
    __syncthreads();
    const float mx = fmaxf(fmaxf(red[0], red[1]), fmaxf(red[2], red[3]));
    float lsum = 0.f;
#pragma unroll
    for (int q = 0; q < 16; ++q) { z[q] = __expf(z[q] - mx); lsum += z[q]; }
#pragma unroll
    for (int off = 32; off; off >>= 1) lsum += __shfl_xor(lsum, off);
    if (lane == 0) red[4 + wave] = lsum;
    __syncthreads();
    const float inv = 1.f / (red[4] + red[5] + red[6] + red[7]);
    f16x8 o0, o1;
#pragma unroll
    for (int q = 0; q < 8; ++q) {
        o0[q] = (half_t)(z[q] * inv);
        o1[q] = (half_t)(z[q + 8] * inv);
    }
    *(f16x8*)&row[s0] = o0;
    *(f16x8*)&row[s0 + 8] = o1;
}

// ---------------------------------------------------------------------------
extern "C" void kernel_launch(void* const* d_in, const int* in_sizes, int n_in,
                              void* d_out, int out_size, void* d_ws, size_t ws_size,
                              hipStream_t stream)
{
    (void)in_sizes; (void)n_in; (void)out_size; (void)ws_size;

    const float* x0p  = (const float*)d_in[0];
    const float* encp = (const float*)d_in[1];
    const float* cmp  = (const float*)d_in[2];
    const float* Wq = (const float*)d_in[3], *Wk = (const float*)d_in[4];
    const float* Wv = (const float*)d_in[5], *Wo = (const float*)d_in[6];
    const float* Cq = (const float*)d_in[7], *Ck = (const float*)d_in[8];
    const float* Cv = (const float*)d_in[9], *Co = (const float*)d_in[10];
    const float* W1p = (const float*)d_in[11];
    const float* W2p = (const float*)d_in[12];
    const float* alphap = (const float*)d_in[13];
    const float* gammap = (const float*)d_in[14];
    const int*   idsp   = (const int*)d_in[15];
    float* outp = (float*)d_out;

    char* wp = (char*)d_ws;
    auto take = [&](size_t nelem, int esz) -> void* {
        void* p = (void*)wp;
        wp += (nelem * (size_t)esz + 255) & ~(size_t)255;
        return p;
    };
    half_t* wqkvT = (half_t*)take((size_t)NLAYER * 1536 * 512, 2);
    half_t* ckvT  = (half_t*)take((size_t)NLAYER * 1024 * 512, 2);
    half_t* cqT   = (half_t*)take((size_t)NLAYER * 512 * 512, 2);
    half_t* woT   = (half_t*)take((size_t)NLAYER * 512 * 512, 2);
    half_t* coT   = (half_t*)take((size_t)NLAYER * 512 * 512, 2);
    half_t* w1T   = (half_t*)take((size_t)NLAYER * D_DIM * F_DIM, 2);
    half_t* w2T   = (half_t*)take((size_t)NLAYER * D_DIM * F_DIM, 2);
    half_t* hh    = (half_t*)take((size_t)T_DIM * D_DIM, 2);
    half_t* qb    = (half_t*)take((size_t)T_DIM * D_DIM, 2);
    half_t* kb    = (half_t*)take((size_t)S_DIM * D_DIM, 2);
    half_t* vT    = (half_t*)take((size_t)S_DIM * D_DIM, 2);
    half_t* ao    = (half_t*)take((size_t)T_DIM * D_DIM, 2);
    half_t* mid   = (half_t*)take((size_t)T_DIM * F_DIM, 2);
    half_t* enc16 = (half_t*)take((size_t)S_DIM * D_DIM, 2);
    half_t* kbC   = (half_t*)take((size_t)NLAYER * S_DIM * D_DIM, 2);
    half_t* vTC   = (half_t*)take((size_t)NLAYER * S_DIM * D_DIM, 2);
    float* xbuf   = (float*)take((size_t)T_DIM * D_DIM, 4);
    half_t* logit16 = (half_t*)take((size_t)T_DIM * S_DIM, 2);
    half_t* p16   = (half_t*)take((size_t)T_DIM * 2048, 2);
    float* pbuf   = (float*)take((size_t)T_DIM * 2048, 4);
    u32* crossb = (u32*)take((size_t)T_DIM * (S_DIM / 32), 4);
    u32* selfb  = (u32*)take((size_t)T_DIM * (S_DIM / 32), 4);

    const dim3 B(256), B512(512);
    const float qscale = 0.04419417382415922f; // 1/sqrt(512), folded into Wq/Cq

    // ---- one-time prep ----
    const int SQ = 512 * 512, QKVZ = 1536 * 512, FZ = 512 * 2048;
    transpose_cast8<<<dim3(16, 16, 32), B, 0, stream>>>(
        Wq, Wk, Wv, Wo, Cq, Ck, Cv, Co,
        wqkvT, wqkvT + SQ, wqkvT + 2 * SQ, woT, cqT, ckvT, ckvT + SQ, coT, qscale);
    transpose_cast<<<dim3(64,16,4), B, 0, stream>>>(W1p, w1T, 512, 2048, 1.f, FZ, FZ);
    transpose_cast<<<dim3(16,64,4), B, 0, stream>>>(W2p, w2T, 2048, 512, 1.f, FZ, FZ);
    cast_f16<<<dim3((S_DIM * D_DIM / 8) / 256), B, 0, stream>>>(encp, enc16);
    pack_masks<<<dim3(T_DIM), B, 0, stream>>>(cmp, idsp, crossb, selfb);
    // batched cross-K/V for all layers (gemm97 geometry, grid 1024)
    gemm97<7><<<dim3(1024), B, 0, stream>>>(enc16, 512, ckvT, 512,
        512, 32, nullptr, nullptr, 4096, kbC, vTC);

    for (int l = 0; l < NLAYER; ++l) {
        const float* xin = (l == 0) ? x0p : xbuf;

        // ---- head: residual fold of prev W2 + norm ----
        if (l == 0)
            norm_rows<0><<<T_DIM / 4, B, 0, stream>>>(x0p, hh, nullptr, nullptr, nullptr);
        else
            norm_red<0><<<T_DIM / 4, B, 0, stream>>>(xbuf, pbuf, xbuf, hh, nullptr, nullptr, nullptr);

        // ---- self attention ----
        gemm97<5><<<dim3(384), B, 0, stream>>>(hh, 512, wqkvT + (size_t)l * QKVZ, 512,
            512, 12, qb, nullptr, 4096, kb, vT);
        gemm97<2><<<dim3(1024), B, 0, stream>>>(qb, 512, kb, 512, 512, 32, logit16, nullptr, 4096);
        softmax_rows16<<<dim3(T_DIM), B, 0, stream>>>(logit16, selfb);
        gemm97<0, 4, 1><<<dim3(512), B, 0, stream>>>(logit16, 4096, vT, 4096,
            4096, 4, p16, nullptr, 2048);
        reduce_p16<<<dim3(1024), B, 0, stream>>>(p16, ao);
        gemm_nt<64, 1><<<dim3(256), B512, 0, stream>>>(ao, 512, woT + (size_t)l * SQ, 512,
            512, 512, 8, xin, xbuf, nullptr, 0);

        // ---- cross attention ----
        norm_rows<0><<<T_DIM / 4, B, 0, stream>>>(xbuf, hh, nullptr, nullptr, nullptr);
        gemm_nt<64, 2><<<dim3(256), B512, 0, stream>>>(hh, 512, cqT + (size_t)l * SQ, 512,
            512, 512, 8, nullptr, nullptr, qb, 512);
        gemm97<2><<<dim3(1024), B, 0, stream>>>(qb, 512, kbC + (size_t)l * KVS, 512,
            512, 32, logit16, nullptr, 4096);
        softmax_rows16<<<dim3(T_DIM), B, 0, stream>>>(logit16, crossb);
        gemm97<0, 4, 1><<<dim3(512), B, 0, stream>>>(logit16, 4096, vTC + (size_t)l * KVS, 4096,
            4096, 4, p16, nullptr, 2048);
        reduce_p16<<<dim3(1024), B, 0, stream>>>(p16, ao);
        gemm_nt<64, 1><<<dim3(256), B512, 0, stream>>>(ao, 512, coT + (size_t)l * SQ, 512,
            512, 512, 8, xbuf, xbuf, nullptr, 0);

        // ---- FFN ----
        norm_rows<0><<<T_DIM / 4, B, 0, stream>>>(xbuf, hh, nullptr, nullptr, nullptr);
        gemm97<4><<<dim3(512), B, 0, stream>>>(hh, 512, w1T + (size_t)l * FZ, 512,
            512, 16, mid, nullptr, 2048);
        gemm97<0, 4, 0><<<dim3(512), B, 0, stream>>>(mid, 2048, w2T + (size_t)l * FZ, 2048,
            2048, 4, nullptr, pbuf, 2048);
    }

    norm_red<1><<<T_DIM / 4, B, 0, stream>>>(xbuf, pbuf, xbuf, nullptr, outp, alphap, gammap);
}